// Round 5
// baseline (493.811 us; speedup 1.0000x reference)
//
#include <hip/hip_runtime.h>
#include <hip/hip_bf16.h>

// SwinTransformerEncoder on gfx950.
// H=W=64, C=256, HEADS=8 (d=32), WS=8, N=64 tok/window, NW=64, B=8, DEPTH=2, HIDDEN=1024.
// Inputs fp32 (runtime probe also supports bf16-cast). OUTPUT fp32. Residual fp32 in ws.
// R13: k_fullN epilogue de-scattered. The fragment-order epilogue (64 scalar 4B xf
//     accesses/lane at 64B stride + 2 shfl chains per row) was latency-bound: 28% HBM,
//     14% VALU, 14% Mfma. Now: acc -> LDS (union with dead staging buffers, 33-float
//     chunk stride = conflict-free re-read) -> each thread owns 32 CONSECUTIVE floats
//     of one row -> all xf/out/bufB traffic is 8x dwordx4 coalesced streams, LN reduce
//     = 3 shfl_xor in an 8-lane group. K-loop (depth-2 vmcnt prefetch), k_gemm, attn
//     unchanged.
//
// Workspace (~171 MiB of 256 MiB):
//   xf   fp32 [8*4096*256]   @ 0          (32 MiB)  residual stream
//   bufH bf16 [32768*1024]   @ 33554432   (64 MiB)  fc1 hidden
//   bufQ bf16 [32768*768]    @ 100663296  (48 MiB)  qkv
//   bufB bf16 [32768*256]    @ 150994944  (16 MiB)  LN out / attn out
//   wT   bf16 [2*786432]     @ 167772160  (3 MiB)   transposed weights
//   mode int                 @ 170917888  (4 B)     input-dtype flag (1=bf16, 0=fp32)

typedef __hip_bfloat16 bf16;
typedef unsigned short u16;
typedef unsigned int u32;
typedef short short8 __attribute__((ext_vector_type(8)));
typedef float floatx4 __attribute__((ext_vector_type(4)));

#define DEVI static __device__ __forceinline__
#define WAITCNT_VM(n) asm volatile("s_waitcnt vmcnt(" #n ")" ::: "memory")

DEVI float lo16(u32 u) { union { u32 i; float f; } x; x.i = u << 16; return x.f; }
DEVI float hi16(u32 u) { union { u32 i; float f; } x; x.i = u & 0xffff0000u; return x.f; }
DEVI float b2f(u16 u) { union { u32 i; float f; } x; x.i = ((u32)u) << 16; return x.f; }
DEVI u16 f2b(float f) {  // round-to-nearest-even
  union { float f; u32 i; } x; x.f = f;
  u32 r = x.i + 0x7fffu + ((x.i >> 16) & 1u);
  return (u16)(r >> 16);
}
DEVI float in_elem(const void* p, size_t i, int m) {
  return m ? b2f(((const u16*)p)[i]) : ((const float*)p)[i];
}
DEVI int swlab(int g) { return (g < 56) ? 0 : (g < 60 ? 1 : 2); }

// GELU via tanh form, 7 VALU ops (max abs err vs exact-erf GELU ~3e-4, << bf16 quant).
DEVI float gelu_cheap(float v) {
  const float u = v * v;
  const float t = v * __builtin_fmaf(0.1029436f, u, 2.3022090f);
  const float e = __builtin_amdgcn_exp2f(t);
  const float r = __builtin_amdgcn_rcpf(e + 1.0f);
  return __builtin_fmaf(-v, r, v);
}

DEVI void async16(const bf16* g, bf16* l) {
  __builtin_amdgcn_global_load_lds((const __attribute__((address_space(1))) u32*)g,
                                   (__attribute__((address_space(3))) u32*)l, 16, 0, 0);
}

// ---------------- dtype probe (ln1_g is all-ones) ----------------
__global__ void k_detect(const u32* __restrict__ ln1g, int* __restrict__ mode) {
  if (threadIdx.x == 0 && blockIdx.x == 0)
    *mode = (ln1g[0] == 0x3F803F80u) ? 1 : 0;
}

// ---------------- ingest + LN1(depth0): x -> xf copy, LN -> bufB windowed ----------------
__global__ __launch_bounds__(256) void k_ingest_ln(const void* __restrict__ xin,
    float* __restrict__ xf, const void* __restrict__ gamw, const void* __restrict__ betw,
    bf16* __restrict__ outp, const int* __restrict__ mode)
{
  const int m = *mode;
  const int l = threadIdx.x & 63, w = threadIdx.x >> 6;
  const int row = blockIdx.x * 4 + w;     // window-order output row
  const int t = row & 63, win = row >> 6;
  const int bb = win >> 6, wi = win & 63;
  const int gh = ((wi >> 3) << 3) + (t >> 3);
  const int gw = ((wi & 7) << 3) + (t & 7);
  const int srow = (bb << 12) + (gh << 6) + gw;   // token row (shift=0)
  const int cb = l << 2;
  float4 v;
  if (m) {
    const uint2 u = *(const uint2*)((const u16*)xin + (size_t)srow * 256 + cb);
    v = make_float4(lo16(u.x), hi16(u.x), lo16(u.y), hi16(u.y));
  } else {
    v = ((const float4*)((const float*)xin + (size_t)srow * 256))[l];
  }
  ((float4*)(xf + (size_t)srow * 256))[l] = v;    // residual copy
  float s = v.x + v.y + v.z + v.w;
#pragma unroll
  for (int off = 32; off > 0; off >>= 1) s += __shfl_xor(s, off, 64);
  const float mu = s * 0.00390625f;
  const float a = v.x - mu, b = v.y - mu, c = v.z - mu, d = v.w - mu;
  float q = a * a + b * b + c * c + d * d;
#pragma unroll
  for (int off = 32; off > 0; off >>= 1) q += __shfl_xor(q, off, 64);
  const float rs = rsqrtf(q * 0.00390625f + 1e-5f);
  const float o0 = a * rs * in_elem(gamw, cb + 0, m) + in_elem(betw, cb + 0, m);
  const float o1 = b * rs * in_elem(gamw, cb + 1, m) + in_elem(betw, cb + 1, m);
  const float o2 = c * rs * in_elem(gamw, cb + 2, m) + in_elem(betw, cb + 2, m);
  const float o3 = d * rs * in_elem(gamw, cb + 3, m) + in_elem(betw, cb + 3, m);
  const u32 p0 = (u32)f2b(o0) | ((u32)f2b(o1) << 16);
  const u32 p1 = (u32)f2b(o2) | ((u32)f2b(o3) << 16);
  *(uint2*)((u16*)outp + (size_t)row * 256 + cb) = make_uint2(p0, p1);
}

// ---------------- coalesced weight transpose: dst[c][r] = src[r][c], both depths ----------
__global__ __launch_bounds__(256) void k_transpose(
    const void* __restrict__ src, bf16* __restrict__ dst,
    const int* __restrict__ mode, int estride, int dstride, int R, int Cn) {
  __shared__ float T[32][33];
  const int m = *mode;
  const int tx = threadIdx.x & 31, ty = threadIdx.x >> 5;  // ty in 0..7
  const int bc = blockIdx.x << 5, br = blockIdx.y << 5;
  for (int d = 0; d < 2; ++d) {
    __syncthreads();
#pragma unroll
    for (int dy = 0; dy < 4; ++dy) {
      const int r = br + ty + dy * 8;
      T[ty + dy * 8][tx] = in_elem(src, (size_t)d * estride + (size_t)r * Cn + bc + tx, m);
    }
    __syncthreads();
#pragma unroll
    for (int dy = 0; dy < 4; ++dy) {
      const int c = bc + ty + dy * 8;
      ((u16*)dst)[(size_t)d * dstride + (size_t)c * R + br + tx] = f2b(T[tx][ty + dy * 8]);
    }
  }
}

// ---------------- bf16 MFMA GEMM: C[M,N] = A[M,K] @ Bt[N,K]^T + bias ----------------
// Tile 128 x 128, 4 waves (2x2), 16x16x32 MFMA; depth-2 prefetch (3 buffers, counted
// vmcnt(4) + raw s_barrier); XOR-swizzled LDS; XCD-chunked block swizzle.
// EPI: 0 = store bf16; 1 = GELU + bf16.
template <int EPI>
__global__ __launch_bounds__(256, 3) void k_gemm(
    const bf16* __restrict__ A, const bf16* __restrict__ Bt,
    const void* __restrict__ bias, bf16* __restrict__ outb,
    const int* __restrict__ mode, int boff, int K, int N)
{
  __shared__ __align__(16) bf16 As[3][128 * 32];
  __shared__ __align__(16) bf16 Bs[3][128 * 32];
  const int md = *mode;
  const int tid = threadIdx.x;
  const int l = tid & 63, wid = tid >> 6;
  const int wr = wid >> 1, wc = wid & 1;

  const int gx = gridDim.x;
  const int nwg = gx * gridDim.y;
  int fid = blockIdx.y * gx + blockIdx.x;
  if (!(nwg & 7)) fid = (fid & 7) * (nwg >> 3) + (fid >> 3);
  const int row0 = (fid / gx) * 128;
  const int col0 = (fid % gx) * 128;

  const int lrow = l >> 2;
  const int lkof = (((l & 3) ^ ((l >> 3) & 3)) * 8);    // swizzled staged k-chunk
  const int qsw  = (((l >> 4) ^ ((l >> 1) & 3)) * 8);   // swizzled read slot

  floatx4 acc[4][4];
#pragma unroll
  for (int mi = 0; mi < 4; ++mi)
#pragma unroll
    for (int ni = 0; ni < 4; ++ni)
      acc[mi][ni] = (floatx4){0.f, 0.f, 0.f, 0.f};

  auto stage = [&](int b, int kbase) {   // 4 global_load_lds per thread
    const int kk = kbase + lkof;
#pragma unroll
    for (int c = 0; c < 2; ++c) {
      const int seg = c * 4 + wid;
      async16(A + (size_t)(row0 + seg * 16 + lrow) * K + kk, &As[b][seg * 512]);
      async16(Bt + (size_t)(col0 + seg * 16 + lrow) * K + kk, &Bs[b][seg * 512]);
    }
  };

  const int nsl = K >> 5;
  stage(0, 0);
  stage(1, 32);

  for (int s = 0; s < nsl; ++s) {
    const int cur = s % 3;
    WAITCNT_VM(4);                      // slice-s loads landed (s+1's 4 may fly)
    __builtin_amdgcn_s_barrier();       // all waves: slice s resident, slice s-1 reads done
    if (s + 2 < nsl) stage((s + 2) % 3, (s + 2) * 32);  // overwrites slice s-1's buffer

    short8 af[4], bq[4];
#pragma unroll
    for (int mi = 0; mi < 4; ++mi)
      af[mi] = *(const short8*)&As[cur][(wr * 64 + mi * 16 + (l & 15)) * 32 + qsw];
#pragma unroll
    for (int ni = 0; ni < 4; ++ni)
      bq[ni] = *(const short8*)&Bs[cur][(wc * 64 + ni * 16 + (l & 15)) * 32 + qsw];
#pragma unroll
    for (int mi = 0; mi < 4; ++mi)
#pragma unroll
      for (int ni = 0; ni < 4; ++ni)
        acc[mi][ni] = __builtin_amdgcn_mfma_f32_16x16x32_bf16(af[mi], bq[ni], acc[mi][ni], 0, 0, 0);
  }

  const int cl = l & 15, rq = l >> 4;  // C/D: col=lane&15, row=(lane>>4)*4+reg
#pragma unroll
  for (int mi = 0; mi < 4; ++mi) {
#pragma unroll
    for (int ni = 0; ni < 4; ++ni) {
      const int col = col0 + wc * 64 + ni * 16 + cl;
      const float bv = in_elem(bias, (size_t)boff + col, md);
#pragma unroll
      for (int r = 0; r < 4; ++r) {
        const int row = row0 + wr * 64 + mi * 16 + rq * 4 + r;
        float v = acc[mi][ni][r] + bv;
        if (EPI == 1) v = gelu_cheap(v);
        ((u16*)outb)[(size_t)row * N + col] = f2b(v);
      }
    }
  }
}

// ---------------- full-N GEMM (N=256 in one block) + fused residual/LN epilogues -------
// 4 waves x 16 rows x 256 cols (NI=16); depth-2 prefetch (3 buffers, vmcnt(5)).
// Epilogue: acc -> LDS (chunk stride 33 floats, conflict-free re-read) -> thread owns
// (row, 32-col chunk) -> coalesced dwordx4 streams for xf/out/bufB; LN = 3 shfl_xor
// in the 8-lane row group. MODE:
//   0 = proj:  t = xf[winrev(row)]+v+bias; xf=t; bufB[tokenrow] = LN2(t)
//   1 = fc2(d0): t = xf[row]+v+bias; xf=t; bufB[winshift4(row)] = LN1d1(t)
//   2 = fc2(d1): out fp32 = xf[row] + v + bias   (final)
template <int MODE>
__global__ __launch_bounds__(256, 2) void k_fullN(
    const bf16* __restrict__ A, const bf16* __restrict__ Bt,
    const void* __restrict__ bias, const void* __restrict__ lng,
    const void* __restrict__ lnb, void* __restrict__ outp,
    float* __restrict__ xf, const int* __restrict__ mode,
    int boff, int lnoff, int K, int shift)
{
  // union: staging (3 bufs: As 3x4KB + Bs 3x16KB = 60KB) / epilogue scratch (33.8KB)
  __shared__ __align__(16) char smem[61440];
  bf16* As = (bf16*)smem;                 // [3][64*32]
  bf16* Bs = (bf16*)(smem + 12288);       // [3][256*32]
  float* EP = (float*)smem;               // [32 rows][8 chunks][33 floats]
  const int md = *mode;
  const int tid = threadIdx.x;
  const int l = tid & 63, w = tid >> 6;

  int fid = blockIdx.x;
  const int nwg = gridDim.x;
  if (!(nwg & 7)) fid = (fid & 7) * (nwg >> 3) + (fid >> 3);
  const int row0 = fid * 64;

  const int lrow = l >> 2;
  const int lkof = (((l & 3) ^ ((l >> 3) & 3)) * 8);
  const int qsw  = (((l >> 4) ^ ((l >> 1) & 3)) * 8);

  floatx4 acc[16];
#pragma unroll
  for (int ni = 0; ni < 16; ++ni) acc[ni] = (floatx4){0.f, 0.f, 0.f, 0.f};

  auto stage = [&](int b, int kbase) {   // 5 global_load_lds per thread
    const int kk = kbase + lkof;
    async16(A + (size_t)(row0 + w * 16 + lrow) * K + kk, As + b * 2048 + w * 512);
#pragma unroll
    for (int c = 0; c < 4; ++c) {
      const int seg = c * 4 + w;
      async16(Bt + (size_t)(seg * 16 + lrow) * K + kk, Bs + b * 8192 + seg * 512);
    }
  };

  const int nsl = K >> 5;
  stage(0, 0);
  stage(1, 32);

  for (int s = 0; s < nsl; ++s) {
    const int cur = s % 3;
    WAITCNT_VM(5);                      // slice-s loads landed (s+1's 5 may fly)
    __builtin_amdgcn_s_barrier();
    if (s + 2 < nsl) stage((s + 2) % 3, (s + 2) * 32);

    const short8 af = *(const short8*)&As[cur * 2048 + (w * 16 + (l & 15)) * 32 + qsw];
#pragma unroll
    for (int ni = 0; ni < 16; ++ni) {
      const short8 bq = *(const short8*)&Bs[cur * 8192 + (ni * 16 + (l & 15)) * 32 + qsw];
      acc[ni] = __builtin_amdgcn_mfma_f32_16x16x32_bf16(af, bq, acc[ni], 0, 0, 0);
    }
  }

  // ---- epilogue: fragment -> row-chunk layout via LDS, coalesced streaming ----
  const int cl = l & 15, rq = l >> 4;     // C/D: col=lane&15, row=(lane>>4)*4+reg
  const int myhalf = w >> 1;              // waves 0,1 own rows 0..31; waves 2,3 own 32..63
  const int rr = tid >> 3;                // 0..31: row-in-half this thread processes
  const int ck = tid & 7;                 // chunk 0..7 (32 cols each)
  const int colb = ck * 32;

  // per-col constants (same cols for both halves)
  float bias32[32];
#pragma unroll
  for (int i = 0; i < 32; ++i) bias32[i] = in_elem(bias, (size_t)boff + colb + i, md);
  float g32[32], b32[32];
  if (MODE != 2) {
#pragma unroll
    for (int i = 0; i < 32; ++i) {
      g32[i] = in_elem(lng, (size_t)lnoff + colb + i, md);
      b32[i] = in_elem(lnb, (size_t)lnoff + colb + i, md);
    }
  }

  for (int h = 0; h < 2; ++h) {
    __syncthreads();                      // previous LDS users done
    if (myhalf == h) {
#pragma unroll
      for (int ni = 0; ni < 16; ++ni) {
        const int chv = ni >> 1;
        const int wi_ = (ni & 1) * 16 + cl;
#pragma unroll
        for (int r = 0; r < 4; ++r) {
          const int rowh = (w & 1) * 16 + rq * 4 + r;
          EP[(rowh * 8 + chv) * 33 + wi_] = acc[ni][r];
        }
      }
    }
    __syncthreads();

    const int lrow_g = row0 + h * 32 + rr;   // A-order global row
    float av[32];
#pragma unroll
    for (int i = 0; i < 8; ++i)
      *(float4*)&av[i * 4] = *(const float4*)&EP[(rr * 8 + ck) * 33 + i * 4];

    int resrow, dstrow;
    if (MODE == 0) {
      const int t_ = lrow_g & 63, win = lrow_g >> 6;
      const int bb = win >> 6, wi2 = win & 63;
      int gh = ((wi2 >> 3) << 3) + (t_ >> 3);
      int gw = ((wi2 & 7) << 3) + (t_ & 7);
      gh = (gh + shift) & 63; gw = (gw + shift) & 63;
      resrow = (bb << 12) + (gh << 6) + gw;
      dstrow = resrow;
    } else if (MODE == 1) {
      resrow = lrow_g;
      const int bb = lrow_g >> 12, th = (lrow_g >> 6) & 63, tw = lrow_g & 63;
      const int gh = (th + 60) & 63, gw = (tw + 60) & 63;
      const int wi2 = ((gh >> 3) << 3) + (gw >> 3);
      const int tt = ((gh & 7) << 3) + (gw & 7);
      dstrow = (bb << 12) + (wi2 << 6) + tt;
    } else {
      resrow = lrow_g; dstrow = lrow_g;
    }

    const float* xr = xf + (size_t)resrow * 256 + colb;
    if (MODE == 2) {
      float* oo = (float*)outp + (size_t)lrow_g * 256 + colb;
#pragma unroll
      for (int i = 0; i < 8; ++i) {
        const float4 xv = *(const float4*)&xr[i * 4];
        float4 o;
        o.x = xv.x + av[i * 4 + 0] + bias32[i * 4 + 0];
        o.y = xv.y + av[i * 4 + 1] + bias32[i * 4 + 1];
        o.z = xv.z + av[i * 4 + 2] + bias32[i * 4 + 2];
        o.w = xv.w + av[i * 4 + 3] + bias32[i * 4 + 3];
        *(float4*)&oo[i * 4] = o;
      }
      continue;
    }

    float t32[32];
    float s = 0.f;
#pragma unroll
    for (int i = 0; i < 8; ++i) {
      const float4 xv = *(const float4*)&xr[i * 4];
      t32[i * 4 + 0] = av[i * 4 + 0] + bias32[i * 4 + 0] + xv.x;
      t32[i * 4 + 1] = av[i * 4 + 1] + bias32[i * 4 + 1] + xv.y;
      t32[i * 4 + 2] = av[i * 4 + 2] + bias32[i * 4 + 2] + xv.z;
      t32[i * 4 + 3] = av[i * 4 + 3] + bias32[i * 4 + 3] + xv.w;
    }
#pragma unroll
    for (int i = 0; i < 32; ++i) s += t32[i];
    s += __shfl_xor(s, 1, 64);
    s += __shfl_xor(s, 2, 64);
    s += __shfl_xor(s, 4, 64);
    const float mu = s * 0.00390625f;
    float q = 0.f;
#pragma unroll
    for (int i = 0; i < 32; ++i) { const float d = t32[i] - mu; q += d * d; }
    q += __shfl_xor(q, 1, 64);
    q += __shfl_xor(q, 2, 64);
    q += __shfl_xor(q, 4, 64);
    const float rs = rsqrtf(q * 0.00390625f + 1e-5f);

    float* xw = xf + (size_t)resrow * 256 + colb;
#pragma unroll
    for (int i = 0; i < 8; ++i)
      *(float4*)&xw[i * 4] = make_float4(t32[i * 4 + 0], t32[i * 4 + 1],
                                         t32[i * 4 + 2], t32[i * 4 + 3]);
    u16* ob = (u16*)outp + (size_t)dstrow * 256 + colb;
#pragma unroll
    for (int i = 0; i < 4; ++i) {
      uint4 pk;
      pk.x = (u32)f2b((t32[i * 8 + 0] - mu) * rs * g32[i * 8 + 0] + b32[i * 8 + 0]) |
             ((u32)f2b((t32[i * 8 + 1] - mu) * rs * g32[i * 8 + 1] + b32[i * 8 + 1]) << 16);
      pk.y = (u32)f2b((t32[i * 8 + 2] - mu) * rs * g32[i * 8 + 2] + b32[i * 8 + 2]) |
             ((u32)f2b((t32[i * 8 + 3] - mu) * rs * g32[i * 8 + 3] + b32[i * 8 + 3]) << 16);
      pk.z = (u32)f2b((t32[i * 8 + 4] - mu) * rs * g32[i * 8 + 4] + b32[i * 8 + 4]) |
             ((u32)f2b((t32[i * 8 + 5] - mu) * rs * g32[i * 8 + 5] + b32[i * 8 + 5]) << 16);
      pk.w = (u32)f2b((t32[i * 8 + 6] - mu) * rs * g32[i * 8 + 6] + b32[i * 8 + 6]) |
             ((u32)f2b((t32[i * 8 + 7] - mu) * rs * g32[i * 8 + 7] + b32[i * 8 + 7]) << 16);
      *(uint4*)&ob[i * 8] = pk;
    }
  }
}

// ---------------- windowed attention (MFMA; wave = window x head, 2 heads/wave) ----------------
__global__ __launch_bounds__(256, 2) void k_attn(
    const bf16* __restrict__ qkv, const void* __restrict__ rpb,
    bf16* __restrict__ outp, const int* __restrict__ mode, int eoff, int shifted)
{
  __shared__ __align__(16) u16 Pl[4][64][72];   // 36864 B
  __shared__ __align__(16) u16 Vt[4][32][72];   // 18432 B
  __shared__ float rpbs[4][228];                //  3648 B
  const int md = *mode;
  const int l = threadIdx.x & 63, w = threadIdx.x >> 6;
  const int cl = l & 15, qd = l >> 4;
  const int ko = qd * 8;
  const int win = blockIdx.x;
  const int wi = win & 63;
  const int whb = (wi >> 3) << 3, wwb = (wi & 7) << 3;
  const size_t rowbase = (size_t)win * 64 * 768;

  for (int hh = 0; hh < 2; ++hh) {
    const int h = w + hh * 4;
    for (int i = l; i < 225; i += 64)
      rpbs[w][i] = in_elem(rpb, (size_t)eoff + (size_t)i * 8 + h, md);
    {
      const u16* vrow = (const u16*)(qkv + rowbase + (size_t)l * 768 + 512 + h * 32);
#pragma unroll
      for (int n = 0; n < 32; ++n) Vt[w][n][l] = vrow[n];
    }
    short8 qf[4], kf[4];
#pragma unroll
    for (int t = 0; t < 4; ++t) {
      qf[t] = *(const short8*)(qkv + rowbase + (size_t)(t * 16 + cl) * 768 + h * 32 + ko);
      kf[t] = *(const short8*)(qkv + rowbase + (size_t)(t * 16 + cl) * 768 + 256 + h * 32 + ko);
    }
    __syncthreads();

    floatx4 S[4][4];
#pragma unroll
    for (int mi = 0; mi < 4; ++mi)
#pragma unroll
      for (int ni = 0; ni < 4; ++ni)
        S[mi][ni] = __builtin_amdgcn_mfma_f32_16x16x32_bf16(qf[mi], kf[ni], (floatx4){0.f, 0.f, 0.f, 0.f}, 0, 0, 0);

    int cty[4], ctx[4], clab[4];
#pragma unroll
    for (int ni = 0; ni < 4; ++ni) {
      const int ct = ni * 16 + cl;
      cty[ni] = ct >> 3; ctx[ni] = ct & 7;
      clab[ni] = shifted ? (swlab(whb + cty[ni]) * 3 + swlab(wwb + ctx[ni])) : 0;
    }

    float invs[4][4];
#pragma unroll
    for (int mi = 0; mi < 4; ++mi) {
#pragma unroll
      for (int r = 0; r < 4; ++r) {
        const int rt = mi * 16 + qd * 4 + r;
        const int rty = rt >> 3, rtx = rt & 7;
        const int rlab = shifted ? (swlab(whb + rty) * 3 + swlab(wwb + rtx)) : 0;
        float sv[4];
#pragma unroll
        for (int ni = 0; ni < 4; ++ni) {
          float x = S[mi][ni][r] * 0.17677669529663687f;
          x += rpbs[w][(rty - cty[ni] + 7) * 15 + (rtx - ctx[ni] + 7)];
          if (shifted && (rlab != clab[ni])) x -= 100.f;
          sv[ni] = x;
        }
        float mx = fmaxf(fmaxf(sv[0], sv[1]), fmaxf(sv[2], sv[3]));
        mx = fmaxf(mx, __shfl_xor(mx, 1, 64));
        mx = fmaxf(mx, __shfl_xor(mx, 2, 64));
        mx = fmaxf(mx, __shfl_xor(mx, 4, 64));
        mx = fmaxf(mx, __shfl_xor(mx, 8, 64));
        float sum = 0.f;
#pragma unroll
        for (int ni = 0; ni < 4; ++ni) { sv[ni] = __expf(sv[ni] - mx); sum += sv[ni]; }
        sum += __shfl_xor(sum, 1, 64);
        sum += __shfl_xor(sum, 2, 64);
        sum += __shfl_xor(sum, 4, 64);
        sum += __shfl_xor(sum, 8, 64);
        invs[mi][r] = __builtin_amdgcn_rcpf(sum);
#pragma unroll
        for (int ni = 0; ni < 4; ++ni) Pl[w][rt][ni * 16 + cl] = f2b(sv[ni]);
      }
    }
    __syncthreads();

    floatx4 O[4][2];
#pragma unroll
    for (int mi = 0; mi < 4; ++mi)
#pragma unroll
      for (int nv = 0; nv < 2; ++nv)
        O[mi][nv] = (floatx4){0.f, 0.f, 0.f, 0.f};
    short8 vf[2][2];
#pragma unroll
    for (int nv = 0; nv < 2; ++nv)
#pragma unroll
      for (int kk = 0; kk < 2; ++kk)
        vf[nv][kk] = *(const short8*)&Vt[w][nv * 16 + cl][kk * 32 + ko];
#pragma unroll
    for (int mi = 0; mi < 4; ++mi) {
      const short8 pf0 = *(const short8*)&Pl[w][mi * 16 + cl][ko];
      const short8 pf1 = *(const short8*)&Pl[w][mi * 16 + cl][32 + ko];
#pragma unroll
      for (int nv = 0; nv < 2; ++nv) {
        O[mi][nv] = __builtin_amdgcn_mfma_f32_16x16x32_bf16(pf0, vf[nv][0], O[mi][nv], 0, 0, 0);
        O[mi][nv] = __builtin_amdgcn_mfma_f32_16x16x32_bf16(pf1, vf[nv][1], O[mi][nv], 0, 0, 0);
      }
    }

#pragma unroll
    for (int mi = 0; mi < 4; ++mi)
#pragma unroll
      for (int nv = 0; nv < 2; ++nv)
#pragma unroll
        for (int r = 0; r < 4; ++r) {
          const int row = mi * 16 + qd * 4 + r;
          ((u16*)outp)[((size_t)win * 64 + row) * 256 + h * 32 + nv * 16 + cl] =
              f2b(O[mi][nv][r] * invs[mi][r]);
        }
    __syncthreads();
  }
}

// ---------------- host launcher ----------------
extern "C" void kernel_launch(void* const* d_in, const int* in_sizes, int n_in,
                              void* d_out, int out_size, void* d_ws, size_t ws_size,
                              hipStream_t stream) {
  (void)in_sizes; (void)n_in; (void)out_size; (void)ws_size;
  const void* x_in   = d_in[0];
  const void* qkv_w  = d_in[1];
  const void* qkv_b  = d_in[2];
  const void* proj_w = d_in[3];
  const void* proj_b = d_in[4];
  const void* ln1_g  = d_in[5];
  const void* ln1_b  = d_in[6];
  const void* ln2_g  = d_in[7];
  const void* ln2_b  = d_in[8];
  const void* fc1_w  = d_in[9];
  const void* fc1_b  = d_in[10];
  const void* fc2_w  = d_in[11];
  const void* fc2_b  = d_in[12];
  const void* rpb    = d_in[13];

  char* ws = (char*)d_ws;
  float* xf  = (float*)ws;                   // 32 MiB
  bf16* bufH = (bf16*)(ws + 33554432);       // 64 MiB fc1 hidden
  bf16* bufQ = (bf16*)(ws + 100663296);      // 48 MiB qkv
  bf16* bufB = (bf16*)(ws + 150994944);      // 16 MiB LN out / attn out
  bf16* wT   = (bf16*)(ws + 167772160);      // 3 MiB
  int* mode  = (int*)(ws + 170917888);       // 4 B

  k_detect<<<1, 1, 0, stream>>>((const u32*)ln1_g, mode);
  // ingest + LN1(depth0): x -> xf, LN -> bufB (windowed, shift=0)
  k_ingest_ln<<<8192, 256, 0, stream>>>(x_in, xf, ln1_g, ln1_b, bufB, mode);

  // transposed weights per depth:
  // qkvT[768][256] @0, projT[256][256] @196608, fc1T[1024][256] @262144, fc2T[256][1024] @524288
  k_transpose<<<dim3(24, 8), 256, 0, stream>>>(qkv_w,  wT,          mode, 196608, 786432, 256, 768);
  k_transpose<<<dim3(8, 8), 256, 0, stream>>>(proj_w, wT + 196608, mode, 65536, 786432, 256, 256);
  k_transpose<<<dim3(32, 8), 256, 0, stream>>>(fc1_w, wT + 262144, mode, 262144, 786432, 256, 1024);
  k_transpose<<<dim3(8, 32), 256, 0, stream>>>(fc2_w, wT + 524288, mode, 262144, 786432, 1024, 256);

  for (int i = 0; i < 2; ++i) {
    const int shift = i ? 4 : 0;
    bf16* base  = wT + (size_t)i * 786432;
    bf16* qkvT  = base;
    bf16* projT = base + 196608;
    bf16* fc1T  = base + 262144;
    bf16* fc2T  = base + 524288;

    // QKV: bufQ[32768,768] = bufB @ qkv_w + b
    k_gemm<0><<<dim3(6, 256), 256, 0, stream>>>(bufB, qkvT, qkv_b, bufQ, mode, i * 768, 256, 768);
    // windowed attention: bufQ -> bufB
    k_attn<<<512, 256, 0, stream>>>(bufQ, rpb, bufB, mode, i * 1800, i);
    // proj + window-reverse(+unshift) + residual into xf + LN2 -> bufB (token order)
    k_fullN<0><<<512, 256, 0, stream>>>(bufB, projT, proj_b, ln2_g, ln2_b, bufB, xf, mode,
                                        i * 256, i * 256, 256, shift);
    // FC1: bufH[32768,1024] = GELU(bufB @ fc1_w + b)
    k_gemm<1><<<dim3(8, 256), 256, 0, stream>>>(bufB, fc1T, fc1_b, bufH, mode, i * 1024, 256, 1024);
    // FC2 (K=1024) + residual; depth0 fuses LN1(depth1, shift=4) -> bufB windowed;
    // depth1 writes final fp32 output directly
    if (i == 0)
      k_fullN<1><<<512, 256, 0, stream>>>(bufH, fc2T, fc2_b, ln1_g, ln1_b, bufB, xf, mode,
                                          0, 256, 1024, 4);
    else
      k_fullN<2><<<512, 256, 0, stream>>>(bufH, fc2T, fc2_b, nullptr, nullptr, d_out, xf, mode,
                                          256, 0, 1024, 0);
  }
}

// Round 6
// 435.820 us; speedup vs baseline: 1.1331x; 1.1331x over previous
//
#include <hip/hip_runtime.h>
#include <hip/hip_bf16.h>

// SwinTransformerEncoder on gfx950.
// H=W=64, C=256, HEADS=8 (d=32), WS=8, N=64 tok/window, NW=64, B=8, DEPTH=2, HIDDEN=1024.
// Inputs fp32 (runtime probe also supports bf16-cast). OUTPUT fp32. Residual fp32 in ws.
// R14: (1) FIX tail race in counted-vmcnt K-loops (R13's absmax 0.104): at s=nsl-1 the
//     only outstanding loads are slice s's own, so vmcnt(N) was a no-op -> vmcnt(0) on
//     the last iteration (both k_gemm and k_fullN). (2) k_fullN epilogue v2: wave-private
//     LDS transpose (each wave owns 16 full rows; 4-row x 272-float scratch, 2 lanes/bank
//     writes = free, no barriers) -> lane-uniform row address + float4/lane = 1KB
//     coalesced xf transactions; LN = 6-step full-wave shfl tree. Only 12 extra live
//     regs (R13's 160-float version spilled: VGPR 128, fullN 60us).
//
// Workspace (~171 MiB of 256 MiB):
//   xf   fp32 [8*4096*256]   @ 0          (32 MiB)  residual stream
//   bufH bf16 [32768*1024]   @ 33554432   (64 MiB)  fc1 hidden
//   bufQ bf16 [32768*768]    @ 100663296  (48 MiB)  qkv
//   bufB bf16 [32768*256]    @ 150994944  (16 MiB)  LN out / attn out
//   wT   bf16 [2*786432]     @ 167772160  (3 MiB)   transposed weights
//   mode int                 @ 170917888  (4 B)     input-dtype flag (1=bf16, 0=fp32)

typedef __hip_bfloat16 bf16;
typedef unsigned short u16;
typedef unsigned int u32;
typedef short short8 __attribute__((ext_vector_type(8)));
typedef float floatx4 __attribute__((ext_vector_type(4)));

#define DEVI static __device__ __forceinline__
#define WAITCNT_VM(n) asm volatile("s_waitcnt vmcnt(" #n ")" ::: "memory")

DEVI float lo16(u32 u) { union { u32 i; float f; } x; x.i = u << 16; return x.f; }
DEVI float hi16(u32 u) { union { u32 i; float f; } x; x.i = u & 0xffff0000u; return x.f; }
DEVI float b2f(u16 u) { union { u32 i; float f; } x; x.i = ((u32)u) << 16; return x.f; }
DEVI u16 f2b(float f) {  // round-to-nearest-even
  union { float f; u32 i; } x; x.f = f;
  u32 r = x.i + 0x7fffu + ((x.i >> 16) & 1u);
  return (u16)(r >> 16);
}
DEVI float in_elem(const void* p, size_t i, int m) {
  return m ? b2f(((const u16*)p)[i]) : ((const float*)p)[i];
}
DEVI int swlab(int g) { return (g < 56) ? 0 : (g < 60 ? 1 : 2); }

// GELU via tanh form, 7 VALU ops (max abs err vs exact-erf GELU ~3e-4, << bf16 quant).
DEVI float gelu_cheap(float v) {
  const float u = v * v;
  const float t = v * __builtin_fmaf(0.1029436f, u, 2.3022090f);
  const float e = __builtin_amdgcn_exp2f(t);
  const float r = __builtin_amdgcn_rcpf(e + 1.0f);
  return __builtin_fmaf(-v, r, v);
}

DEVI void async16(const bf16* g, bf16* l) {
  __builtin_amdgcn_global_load_lds((const __attribute__((address_space(1))) u32*)g,
                                   (__attribute__((address_space(3))) u32*)l, 16, 0, 0);
}

// ---------------- dtype probe (ln1_g is all-ones) ----------------
__global__ void k_detect(const u32* __restrict__ ln1g, int* __restrict__ mode) {
  if (threadIdx.x == 0 && blockIdx.x == 0)
    *mode = (ln1g[0] == 0x3F803F80u) ? 1 : 0;
}

// ---------------- ingest + LN1(depth0): x -> xf copy, LN -> bufB windowed ----------------
__global__ __launch_bounds__(256) void k_ingest_ln(const void* __restrict__ xin,
    float* __restrict__ xf, const void* __restrict__ gamw, const void* __restrict__ betw,
    bf16* __restrict__ outp, const int* __restrict__ mode)
{
  const int m = *mode;
  const int l = threadIdx.x & 63, w = threadIdx.x >> 6;
  const int row = blockIdx.x * 4 + w;     // window-order output row
  const int t = row & 63, win = row >> 6;
  const int bb = win >> 6, wi = win & 63;
  const int gh = ((wi >> 3) << 3) + (t >> 3);
  const int gw = ((wi & 7) << 3) + (t & 7);
  const int srow = (bb << 12) + (gh << 6) + gw;   // token row (shift=0)
  const int cb = l << 2;
  float4 v;
  if (m) {
    const uint2 u = *(const uint2*)((const u16*)xin + (size_t)srow * 256 + cb);
    v = make_float4(lo16(u.x), hi16(u.x), lo16(u.y), hi16(u.y));
  } else {
    v = ((const float4*)((const float*)xin + (size_t)srow * 256))[l];
  }
  ((float4*)(xf + (size_t)srow * 256))[l] = v;    // residual copy
  float s = v.x + v.y + v.z + v.w;
#pragma unroll
  for (int off = 32; off > 0; off >>= 1) s += __shfl_xor(s, off, 64);
  const float mu = s * 0.00390625f;
  const float a = v.x - mu, b = v.y - mu, c = v.z - mu, d = v.w - mu;
  float q = a * a + b * b + c * c + d * d;
#pragma unroll
  for (int off = 32; off > 0; off >>= 1) q += __shfl_xor(q, off, 64);
  const float rs = rsqrtf(q * 0.00390625f + 1e-5f);
  const float o0 = a * rs * in_elem(gamw, cb + 0, m) + in_elem(betw, cb + 0, m);
  const float o1 = b * rs * in_elem(gamw, cb + 1, m) + in_elem(betw, cb + 1, m);
  const float o2 = c * rs * in_elem(gamw, cb + 2, m) + in_elem(betw, cb + 2, m);
  const float o3 = d * rs * in_elem(gamw, cb + 3, m) + in_elem(betw, cb + 3, m);
  const u32 p0 = (u32)f2b(o0) | ((u32)f2b(o1) << 16);
  const u32 p1 = (u32)f2b(o2) | ((u32)f2b(o3) << 16);
  *(uint2*)((u16*)outp + (size_t)row * 256 + cb) = make_uint2(p0, p1);
}

// ---------------- coalesced weight transpose: dst[c][r] = src[r][c], both depths ----------
__global__ __launch_bounds__(256) void k_transpose(
    const void* __restrict__ src, bf16* __restrict__ dst,
    const int* __restrict__ mode, int estride, int dstride, int R, int Cn) {
  __shared__ float T[32][33];
  const int m = *mode;
  const int tx = threadIdx.x & 31, ty = threadIdx.x >> 5;  // ty in 0..7
  const int bc = blockIdx.x << 5, br = blockIdx.y << 5;
  for (int d = 0; d < 2; ++d) {
    __syncthreads();
#pragma unroll
    for (int dy = 0; dy < 4; ++dy) {
      const int r = br + ty + dy * 8;
      T[ty + dy * 8][tx] = in_elem(src, (size_t)d * estride + (size_t)r * Cn + bc + tx, m);
    }
    __syncthreads();
#pragma unroll
    for (int dy = 0; dy < 4; ++dy) {
      const int c = bc + ty + dy * 8;
      ((u16*)dst)[(size_t)d * dstride + (size_t)c * R + br + tx] = f2b(T[tx][ty + dy * 8]);
    }
  }
}

// ---------------- bf16 MFMA GEMM: C[M,N] = A[M,K] @ Bt[N,K]^T + bias ----------------
// Tile 128 x 128, 4 waves (2x2), 16x16x32 MFMA; depth-2 prefetch (3 buffers, counted
// vmcnt(4), vmcnt(0) on last iter); XOR-swizzled LDS; XCD-chunked block swizzle.
// EPI: 0 = store bf16; 1 = GELU + bf16.
template <int EPI>
__global__ __launch_bounds__(256, 3) void k_gemm(
    const bf16* __restrict__ A, const bf16* __restrict__ Bt,
    const void* __restrict__ bias, bf16* __restrict__ outb,
    const int* __restrict__ mode, int boff, int K, int N)
{
  __shared__ __align__(16) bf16 As[3][128 * 32];
  __shared__ __align__(16) bf16 Bs[3][128 * 32];
  const int md = *mode;
  const int tid = threadIdx.x;
  const int l = tid & 63, wid = tid >> 6;
  const int wr = wid >> 1, wc = wid & 1;

  const int gx = gridDim.x;
  const int nwg = gx * gridDim.y;
  int fid = blockIdx.y * gx + blockIdx.x;
  if (!(nwg & 7)) fid = (fid & 7) * (nwg >> 3) + (fid >> 3);
  const int row0 = (fid / gx) * 128;
  const int col0 = (fid % gx) * 128;

  const int lrow = l >> 2;
  const int lkof = (((l & 3) ^ ((l >> 3) & 3)) * 8);    // swizzled staged k-chunk
  const int qsw  = (((l >> 4) ^ ((l >> 1) & 3)) * 8);   // swizzled read slot

  floatx4 acc[4][4];
#pragma unroll
  for (int mi = 0; mi < 4; ++mi)
#pragma unroll
    for (int ni = 0; ni < 4; ++ni)
      acc[mi][ni] = (floatx4){0.f, 0.f, 0.f, 0.f};

  auto stage = [&](int b, int kbase) {   // 4 global_load_lds per thread
    const int kk = kbase + lkof;
#pragma unroll
    for (int c = 0; c < 2; ++c) {
      const int seg = c * 4 + wid;
      async16(A + (size_t)(row0 + seg * 16 + lrow) * K + kk, &As[b][seg * 512]);
      async16(Bt + (size_t)(col0 + seg * 16 + lrow) * K + kk, &Bs[b][seg * 512]);
    }
  };

  const int nsl = K >> 5;
  stage(0, 0);
  stage(1, 32);

  for (int s = 0; s < nsl; ++s) {
    const int cur = s % 3;
    if (s < nsl - 1) { WAITCNT_VM(4); }  // slice-s landed; slice s+1's 4 may fly
    else            { WAITCNT_VM(0); }   // tail: only slice-s loads outstanding
    __builtin_amdgcn_s_barrier();        // slice s resident, slice s-1 reads done
    if (s + 2 < nsl) stage((s + 2) % 3, (s + 2) * 32);  // overwrites slice s-1's buffer

    short8 af[4], bq[4];
#pragma unroll
    for (int mi = 0; mi < 4; ++mi)
      af[mi] = *(const short8*)&As[cur][(wr * 64 + mi * 16 + (l & 15)) * 32 + qsw];
#pragma unroll
    for (int ni = 0; ni < 4; ++ni)
      bq[ni] = *(const short8*)&Bs[cur][(wc * 64 + ni * 16 + (l & 15)) * 32 + qsw];
#pragma unroll
    for (int mi = 0; mi < 4; ++mi)
#pragma unroll
      for (int ni = 0; ni < 4; ++ni)
        acc[mi][ni] = __builtin_amdgcn_mfma_f32_16x16x32_bf16(af[mi], bq[ni], acc[mi][ni], 0, 0, 0);
  }

  const int cl = l & 15, rq = l >> 4;  // C/D: col=lane&15, row=(lane>>4)*4+reg
#pragma unroll
  for (int mi = 0; mi < 4; ++mi) {
#pragma unroll
    for (int ni = 0; ni < 4; ++ni) {
      const int col = col0 + wc * 64 + ni * 16 + cl;
      const float bv = in_elem(bias, (size_t)boff + col, md);
#pragma unroll
      for (int r = 0; r < 4; ++r) {
        const int row = row0 + wr * 64 + mi * 16 + rq * 4 + r;
        float v = acc[mi][ni][r] + bv;
        if (EPI == 1) v = gelu_cheap(v);
        ((u16*)outb)[(size_t)row * N + col] = f2b(v);
      }
    }
  }
}

// ---------------- full-N GEMM (N=256 in one block) + fused residual/LN epilogues -------
// 4 waves x 16 rows x 256 cols (NI=16); depth-2 prefetch (3 buffers, vmcnt(5), vmcnt(0)
// tail). Epilogue: wave-private LDS transpose (wave owns 16 full rows; [4][272] scratch,
// free 2-way write banks, no barriers) -> lane-uniform row + float4/lane coalesced
// xf/out/bufB streams; LN = 6-step full-wave shfl tree. MODE:
//   0 = proj:  t = xf[winrev(row)]+v+bias; xf=t; bufB[tokenrow] = LN2(t)
//   1 = fc2(d0): t = xf[row]+v+bias; xf=t; bufB[winshift4(row)] = LN1d1(t)
//   2 = fc2(d1): out fp32 = xf[row] + v + bias   (final)
template <int MODE>
__global__ __launch_bounds__(256, 2) void k_fullN(
    const bf16* __restrict__ A, const bf16* __restrict__ Bt,
    const void* __restrict__ bias, const void* __restrict__ lng,
    const void* __restrict__ lnb, void* __restrict__ outp,
    float* __restrict__ xf, const int* __restrict__ mode,
    int boff, int lnoff, int K, int shift)
{
  // union: staging (3 bufs: As 3x4KB + Bs 3x16KB = 60KB) / epilogue scratch 17KB
  __shared__ __align__(16) char smem[61440];
  bf16* As = (bf16*)smem;                 // [3][64*32]
  bf16* Bs = (bf16*)(smem + 12288);       // [3][256*32]
  const int md = *mode;
  const int tid = threadIdx.x;
  const int l = tid & 63, w = tid >> 6;

  int fid = blockIdx.x;
  const int nwg = gridDim.x;
  if (!(nwg & 7)) fid = (fid & 7) * (nwg >> 3) + (fid >> 3);
  const int row0 = fid * 64;

  const int lrow = l >> 2;
  const int lkof = (((l & 3) ^ ((l >> 3) & 3)) * 8);
  const int qsw  = (((l >> 4) ^ ((l >> 1) & 3)) * 8);

  floatx4 acc[16];
#pragma unroll
  for (int ni = 0; ni < 16; ++ni) acc[ni] = (floatx4){0.f, 0.f, 0.f, 0.f};

  auto stage = [&](int b, int kbase) {   // 5 global_load_lds per thread
    const int kk = kbase + lkof;
    async16(A + (size_t)(row0 + w * 16 + lrow) * K + kk, As + b * 2048 + w * 512);
#pragma unroll
    for (int c = 0; c < 4; ++c) {
      const int seg = c * 4 + w;
      async16(Bt + (size_t)(seg * 16 + lrow) * K + kk, Bs + b * 8192 + seg * 512);
    }
  };

  const int nsl = K >> 5;
  stage(0, 0);
  stage(1, 32);

  for (int s = 0; s < nsl; ++s) {
    const int cur = s % 3;
    if (s < nsl - 1) { WAITCNT_VM(5); }  // slice-s landed; slice s+1's 5 may fly
    else            { WAITCNT_VM(0); }   // tail: only slice-s loads outstanding
    __builtin_amdgcn_s_barrier();
    if (s + 2 < nsl) stage((s + 2) % 3, (s + 2) * 32);

    const short8 af = *(const short8*)&As[cur * 2048 + (w * 16 + (l & 15)) * 32 + qsw];
#pragma unroll
    for (int ni = 0; ni < 16; ++ni) {
      const short8 bq = *(const short8*)&Bs[cur * 8192 + (ni * 16 + (l & 15)) * 32 + qsw];
      acc[ni] = __builtin_amdgcn_mfma_f32_16x16x32_bf16(af, bq, acc[ni], 0, 0, 0);
    }
  }

  // ---- epilogue: wave-private LDS transpose -> coalesced row streaming ----
  __syncthreads();   // all waves done with staging LDS (vmcnt/lgkm drained)

  float* EPw = (float*)smem + w * 1088;   // [4 rows][272 floats] = 4352 B per wave
  const int cl = l & 15, rq = l >> 4;     // C/D: col=lane&15, row=(lane>>4)*4+reg
  const int c4 = l * 4;                   // lane's col base in row-streaming phase

  float bias4[4], g4[4], b4[4];
#pragma unroll
  for (int i = 0; i < 4; ++i) bias4[i] = in_elem(bias, (size_t)boff + c4 + i, md);
  if (MODE != 2) {
#pragma unroll
    for (int i = 0; i < 4; ++i) {
      g4[i] = in_elem(lng, (size_t)lnoff + c4 + i, md);
      b4[i] = in_elem(lnb, (size_t)lnoff + c4 + i, md);
    }
  }

  for (int r = 0; r < 4; ++r) {
    // fragment -> wave-private LDS: row slot rq holds row_local rq*4+r.
    // banks: rq*272+ni*16+cl -> exactly 2 lanes/bank (free).
#pragma unroll
    for (int ni = 0; ni < 16; ++ni)
      EPw[rq * 272 + ni * 16 + cl] = acc[ni][r];

#pragma unroll
    for (int g = 0; g < 4; ++g) {
      const int lrow_g = row0 + w * 16 + g * 4 + r;   // lane-uniform global A-row
      const float4 av = *(const float4*)&EPw[g * 272 + c4];

      int resrow, dstrow;
      if (MODE == 0) {
        const int t_ = lrow_g & 63, win = lrow_g >> 6;
        const int bb = win >> 6, wi2 = win & 63;
        int gh = ((wi2 >> 3) << 3) + (t_ >> 3);
        int gw = ((wi2 & 7) << 3) + (t_ & 7);
        gh = (gh + shift) & 63; gw = (gw + shift) & 63;
        resrow = (bb << 12) + (gh << 6) + gw;
        dstrow = resrow;
      } else if (MODE == 1) {
        resrow = lrow_g;
        const int bb = lrow_g >> 12, th = (lrow_g >> 6) & 63, tw = lrow_g & 63;
        const int gh = (th + 60) & 63, gw = (tw + 60) & 63;
        const int wi2 = ((gh >> 3) << 3) + (gw >> 3);
        const int tt = ((gh & 7) << 3) + (gw & 7);
        dstrow = (bb << 12) + (wi2 << 6) + tt;
      } else {
        resrow = lrow_g; dstrow = lrow_g;
      }

      const float4 xv = *(const float4*)(xf + (size_t)resrow * 256 + c4);
      float t0 = av.x + bias4[0] + xv.x;
      float t1 = av.y + bias4[1] + xv.y;
      float t2 = av.z + bias4[2] + xv.z;
      float t3 = av.w + bias4[3] + xv.w;

      if (MODE == 2) {
        *(float4*)((float*)outp + (size_t)lrow_g * 256 + c4) = make_float4(t0, t1, t2, t3);
        continue;
      }

      float s = t0 + t1 + t2 + t3;
#pragma unroll
      for (int off = 32; off > 0; off >>= 1) s += __shfl_xor(s, off, 64);
      const float mu = s * 0.00390625f;
      const float d0 = t0 - mu, d1 = t1 - mu, d2 = t2 - mu, d3 = t3 - mu;
      float q = d0 * d0 + d1 * d1 + d2 * d2 + d3 * d3;
#pragma unroll
      for (int off = 32; off > 0; off >>= 1) q += __shfl_xor(q, off, 64);
      const float rs = rsqrtf(q * 0.00390625f + 1e-5f);

      *(float4*)(xf + (size_t)resrow * 256 + c4) = make_float4(t0, t1, t2, t3);
      const u32 p0 = (u32)f2b(d0 * rs * g4[0] + b4[0]) | ((u32)f2b(d1 * rs * g4[1] + b4[1]) << 16);
      const u32 p1 = (u32)f2b(d2 * rs * g4[2] + b4[2]) | ((u32)f2b(d3 * rs * g4[3] + b4[3]) << 16);
      *(uint2*)((u16*)outp + (size_t)dstrow * 256 + c4) = make_uint2(p0, p1);
    }
  }
}

// ---------------- windowed attention (MFMA; wave = window x head, 2 heads/wave) ----------------
__global__ __launch_bounds__(256, 2) void k_attn(
    const bf16* __restrict__ qkv, const void* __restrict__ rpb,
    bf16* __restrict__ outp, const int* __restrict__ mode, int eoff, int shifted)
{
  __shared__ __align__(16) u16 Pl[4][64][72];   // 36864 B
  __shared__ __align__(16) u16 Vt[4][32][72];   // 18432 B
  __shared__ float rpbs[4][228];                //  3648 B
  const int md = *mode;
  const int l = threadIdx.x & 63, w = threadIdx.x >> 6;
  const int cl = l & 15, qd = l >> 4;
  const int ko = qd * 8;
  const int win = blockIdx.x;
  const int wi = win & 63;
  const int whb = (wi >> 3) << 3, wwb = (wi & 7) << 3;
  const size_t rowbase = (size_t)win * 64 * 768;

  for (int hh = 0; hh < 2; ++hh) {
    const int h = w + hh * 4;
    for (int i = l; i < 225; i += 64)
      rpbs[w][i] = in_elem(rpb, (size_t)eoff + (size_t)i * 8 + h, md);
    {
      const u16* vrow = (const u16*)(qkv + rowbase + (size_t)l * 768 + 512 + h * 32);
#pragma unroll
      for (int n = 0; n < 32; ++n) Vt[w][n][l] = vrow[n];
    }
    short8 qf[4], kf[4];
#pragma unroll
    for (int t = 0; t < 4; ++t) {
      qf[t] = *(const short8*)(qkv + rowbase + (size_t)(t * 16 + cl) * 768 + h * 32 + ko);
      kf[t] = *(const short8*)(qkv + rowbase + (size_t)(t * 16 + cl) * 768 + 256 + h * 32 + ko);
    }
    __syncthreads();

    floatx4 S[4][4];
#pragma unroll
    for (int mi = 0; mi < 4; ++mi)
#pragma unroll
      for (int ni = 0; ni < 4; ++ni)
        S[mi][ni] = __builtin_amdgcn_mfma_f32_16x16x32_bf16(qf[mi], kf[ni], (floatx4){0.f, 0.f, 0.f, 0.f}, 0, 0, 0);

    int cty[4], ctx[4], clab[4];
#pragma unroll
    for (int ni = 0; ni < 4; ++ni) {
      const int ct = ni * 16 + cl;
      cty[ni] = ct >> 3; ctx[ni] = ct & 7;
      clab[ni] = shifted ? (swlab(whb + cty[ni]) * 3 + swlab(wwb + ctx[ni])) : 0;
    }

    float invs[4][4];
#pragma unroll
    for (int mi = 0; mi < 4; ++mi) {
#pragma unroll
      for (int r = 0; r < 4; ++r) {
        const int rt = mi * 16 + qd * 4 + r;
        const int rty = rt >> 3, rtx = rt & 7;
        const int rlab = shifted ? (swlab(whb + rty) * 3 + swlab(wwb + rtx)) : 0;
        float sv[4];
#pragma unroll
        for (int ni = 0; ni < 4; ++ni) {
          float x = S[mi][ni][r] * 0.17677669529663687f;
          x += rpbs[w][(rty - cty[ni] + 7) * 15 + (rtx - ctx[ni] + 7)];
          if (shifted && (rlab != clab[ni])) x -= 100.f;
          sv[ni] = x;
        }
        float mx = fmaxf(fmaxf(sv[0], sv[1]), fmaxf(sv[2], sv[3]));
        mx = fmaxf(mx, __shfl_xor(mx, 1, 64));
        mx = fmaxf(mx, __shfl_xor(mx, 2, 64));
        mx = fmaxf(mx, __shfl_xor(mx, 4, 64));
        mx = fmaxf(mx, __shfl_xor(mx, 8, 64));
        float sum = 0.f;
#pragma unroll
        for (int ni = 0; ni < 4; ++ni) { sv[ni] = __expf(sv[ni] - mx); sum += sv[ni]; }
        sum += __shfl_xor(sum, 1, 64);
        sum += __shfl_xor(sum, 2, 64);
        sum += __shfl_xor(sum, 4, 64);
        sum += __shfl_xor(sum, 8, 64);
        invs[mi][r] = __builtin_amdgcn_rcpf(sum);
#pragma unroll
        for (int ni = 0; ni < 4; ++ni) Pl[w][rt][ni * 16 + cl] = f2b(sv[ni]);
      }
    }
    __syncthreads();

    floatx4 O[4][2];
#pragma unroll
    for (int mi = 0; mi < 4; ++mi)
#pragma unroll
      for (int nv = 0; nv < 2; ++nv)
        O[mi][nv] = (floatx4){0.f, 0.f, 0.f, 0.f};
    short8 vf[2][2];
#pragma unroll
    for (int nv = 0; nv < 2; ++nv)
#pragma unroll
      for (int kk = 0; kk < 2; ++kk)
        vf[nv][kk] = *(const short8*)&Vt[w][nv * 16 + cl][kk * 32 + ko];
#pragma unroll
    for (int mi = 0; mi < 4; ++mi) {
      const short8 pf0 = *(const short8*)&Pl[w][mi * 16 + cl][ko];
      const short8 pf1 = *(const short8*)&Pl[w][mi * 16 + cl][32 + ko];
#pragma unroll
      for (int nv = 0; nv < 2; ++nv) {
        O[mi][nv] = __builtin_amdgcn_mfma_f32_16x16x32_bf16(pf0, vf[nv][0], O[mi][nv], 0, 0, 0);
        O[mi][nv] = __builtin_amdgcn_mfma_f32_16x16x32_bf16(pf1, vf[nv][1], O[mi][nv], 0, 0, 0);
      }
    }

#pragma unroll
    for (int mi = 0; mi < 4; ++mi)
#pragma unroll
      for (int nv = 0; nv < 2; ++nv)
#pragma unroll
        for (int r = 0; r < 4; ++r) {
          const int row = mi * 16 + qd * 4 + r;
          ((u16*)outp)[((size_t)win * 64 + row) * 256 + h * 32 + nv * 16 + cl] =
              f2b(O[mi][nv][r] * invs[mi][r]);
        }
    __syncthreads();
  }
}

// ---------------- host launcher ----------------
extern "C" void kernel_launch(void* const* d_in, const int* in_sizes, int n_in,
                              void* d_out, int out_size, void* d_ws, size_t ws_size,
                              hipStream_t stream) {
  (void)in_sizes; (void)n_in; (void)out_size; (void)ws_size;
  const void* x_in   = d_in[0];
  const void* qkv_w  = d_in[1];
  const void* qkv_b  = d_in[2];
  const void* proj_w = d_in[3];
  const void* proj_b = d_in[4];
  const void* ln1_g  = d_in[5];
  const void* ln1_b  = d_in[6];
  const void* ln2_g  = d_in[7];
  const void* ln2_b  = d_in[8];
  const void* fc1_w  = d_in[9];
  const void* fc1_b  = d_in[10];
  const void* fc2_w  = d_in[11];
  const void* fc2_b  = d_in[12];
  const void* rpb    = d_in[13];

  char* ws = (char*)d_ws;
  float* xf  = (float*)ws;                   // 32 MiB
  bf16* bufH = (bf16*)(ws + 33554432);       // 64 MiB fc1 hidden
  bf16* bufQ = (bf16*)(ws + 100663296);      // 48 MiB qkv
  bf16* bufB = (bf16*)(ws + 150994944);      // 16 MiB LN out / attn out
  bf16* wT   = (bf16*)(ws + 167772160);      // 3 MiB
  int* mode  = (int*)(ws + 170917888);       // 4 B

  k_detect<<<1, 1, 0, stream>>>((const u32*)ln1_g, mode);
  // ingest + LN1(depth0): x -> xf, LN -> bufB (windowed, shift=0)
  k_ingest_ln<<<8192, 256, 0, stream>>>(x_in, xf, ln1_g, ln1_b, bufB, mode);

  // transposed weights per depth:
  // qkvT[768][256] @0, projT[256][256] @196608, fc1T[1024][256] @262144, fc2T[256][1024] @524288
  k_transpose<<<dim3(24, 8), 256, 0, stream>>>(qkv_w,  wT,          mode, 196608, 786432, 256, 768);
  k_transpose<<<dim3(8, 8), 256, 0, stream>>>(proj_w, wT + 196608, mode, 65536, 786432, 256, 256);
  k_transpose<<<dim3(32, 8), 256, 0, stream>>>(fc1_w, wT + 262144, mode, 262144, 786432, 256, 1024);
  k_transpose<<<dim3(8, 32), 256, 0, stream>>>(fc2_w, wT + 524288, mode, 262144, 786432, 1024, 256);

  for (int i = 0; i < 2; ++i) {
    const int shift = i ? 4 : 0;
    bf16* base  = wT + (size_t)i * 786432;
    bf16* qkvT  = base;
    bf16* projT = base + 196608;
    bf16* fc1T  = base + 262144;
    bf16* fc2T  = base + 524288;

    // QKV: bufQ[32768,768] = bufB @ qkv_w + b
    k_gemm<0><<<dim3(6, 256), 256, 0, stream>>>(bufB, qkvT, qkv_b, bufQ, mode, i * 768, 256, 768);
    // windowed attention: bufQ -> bufB
    k_attn<<<512, 256, 0, stream>>>(bufQ, rpb, bufB, mode, i * 1800, i);
    // proj + window-reverse(+unshift) + residual into xf + LN2 -> bufB (token order)
    k_fullN<0><<<512, 256, 0, stream>>>(bufB, projT, proj_b, ln2_g, ln2_b, bufB, xf, mode,
                                        i * 256, i * 256, 256, shift);
    // FC1: bufH[32768,1024] = GELU(bufB @ fc1_w + b)
    k_gemm<1><<<dim3(8, 256), 256, 0, stream>>>(bufB, fc1T, fc1_b, bufH, mode, i * 1024, 256, 1024);
    // FC2 (K=1024) + residual; depth0 fuses LN1(depth1, shift=4) -> bufB windowed;
    // depth1 writes final fp32 output directly
    if (i == 0)
      k_fullN<1><<<512, 256, 0, stream>>>(bufH, fc2T, fc2_b, ln1_g, ln1_b, bufB, xf, mode,
                                          0, 256, 1024, 4);
    else
      k_fullN<2><<<512, 256, 0, stream>>>(bufH, fc2T, fc2_b, nullptr, nullptr, d_out, xf, mode,
                                          256, 0, 1024, 0);
  }
}

// Round 7
// 424.840 us; speedup vs baseline: 1.1623x; 1.0258x over previous
//
#include <hip/hip_runtime.h>
#include <hip/hip_bf16.h>

// SwinTransformerEncoder on gfx950.
// H=W=64, C=256, HEADS=8 (d=32), WS=8, N=64 tok/window, NW=64, B=8, DEPTH=2, HIDDEN=1024.
// Inputs fp32 (runtime probe also supports bf16-cast). OUTPUT fp32. Residual fp32 in ws.
// R15: k_gemm epilogue de-scattered (same trick as R14's fullN): 64 scalar u16 stores
//     in fragment order (4x32B segments/instr, ~1.5 TB/s write path, VALU 38%) ->
//     wave-private [4][72] LDS transpose per (mi,r) group -> one uint2 store per group
//     (4 rows x 128B contiguous), 16 stores/thread total. +4.5KB LDS (53KB, still
//     3 blocks/CU), no barriers (wave-private). K-loop/fullN/attn unchanged from R14.
//
// Workspace (~171 MiB of 256 MiB):
//   xf   fp32 [8*4096*256]   @ 0          (32 MiB)  residual stream
//   bufH bf16 [32768*1024]   @ 33554432   (64 MiB)  fc1 hidden
//   bufQ bf16 [32768*768]    @ 100663296  (48 MiB)  qkv
//   bufB bf16 [32768*256]    @ 150994944  (16 MiB)  LN out / attn out
//   wT   bf16 [2*786432]     @ 167772160  (3 MiB)   transposed weights
//   mode int                 @ 170917888  (4 B)     input-dtype flag (1=bf16, 0=fp32)

typedef __hip_bfloat16 bf16;
typedef unsigned short u16;
typedef unsigned int u32;
typedef short short8 __attribute__((ext_vector_type(8)));
typedef float floatx4 __attribute__((ext_vector_type(4)));

#define DEVI static __device__ __forceinline__
#define WAITCNT_VM(n) asm volatile("s_waitcnt vmcnt(" #n ")" ::: "memory")

DEVI float lo16(u32 u) { union { u32 i; float f; } x; x.i = u << 16; return x.f; }
DEVI float hi16(u32 u) { union { u32 i; float f; } x; x.i = u & 0xffff0000u; return x.f; }
DEVI float b2f(u16 u) { union { u32 i; float f; } x; x.i = ((u32)u) << 16; return x.f; }
DEVI u16 f2b(float f) {  // round-to-nearest-even
  union { float f; u32 i; } x; x.f = f;
  u32 r = x.i + 0x7fffu + ((x.i >> 16) & 1u);
  return (u16)(r >> 16);
}
DEVI float in_elem(const void* p, size_t i, int m) {
  return m ? b2f(((const u16*)p)[i]) : ((const float*)p)[i];
}
DEVI int swlab(int g) { return (g < 56) ? 0 : (g < 60 ? 1 : 2); }

// GELU via tanh form, 7 VALU ops (max abs err vs exact-erf GELU ~3e-4, << bf16 quant).
DEVI float gelu_cheap(float v) {
  const float u = v * v;
  const float t = v * __builtin_fmaf(0.1029436f, u, 2.3022090f);
  const float e = __builtin_amdgcn_exp2f(t);
  const float r = __builtin_amdgcn_rcpf(e + 1.0f);
  return __builtin_fmaf(-v, r, v);
}

DEVI void async16(const bf16* g, bf16* l) {
  __builtin_amdgcn_global_load_lds((const __attribute__((address_space(1))) u32*)g,
                                   (__attribute__((address_space(3))) u32*)l, 16, 0, 0);
}

// ---------------- dtype probe (ln1_g is all-ones) ----------------
__global__ void k_detect(const u32* __restrict__ ln1g, int* __restrict__ mode) {
  if (threadIdx.x == 0 && blockIdx.x == 0)
    *mode = (ln1g[0] == 0x3F803F80u) ? 1 : 0;
}

// ---------------- ingest + LN1(depth0): x -> xf copy, LN -> bufB windowed ----------------
__global__ __launch_bounds__(256) void k_ingest_ln(const void* __restrict__ xin,
    float* __restrict__ xf, const void* __restrict__ gamw, const void* __restrict__ betw,
    bf16* __restrict__ outp, const int* __restrict__ mode)
{
  const int m = *mode;
  const int l = threadIdx.x & 63, w = threadIdx.x >> 6;
  const int row = blockIdx.x * 4 + w;     // window-order output row
  const int t = row & 63, win = row >> 6;
  const int bb = win >> 6, wi = win & 63;
  const int gh = ((wi >> 3) << 3) + (t >> 3);
  const int gw = ((wi & 7) << 3) + (t & 7);
  const int srow = (bb << 12) + (gh << 6) + gw;   // token row (shift=0)
  const int cb = l << 2;
  float4 v;
  if (m) {
    const uint2 u = *(const uint2*)((const u16*)xin + (size_t)srow * 256 + cb);
    v = make_float4(lo16(u.x), hi16(u.x), lo16(u.y), hi16(u.y));
  } else {
    v = ((const float4*)((const float*)xin + (size_t)srow * 256))[l];
  }
  ((float4*)(xf + (size_t)srow * 256))[l] = v;    // residual copy
  float s = v.x + v.y + v.z + v.w;
#pragma unroll
  for (int off = 32; off > 0; off >>= 1) s += __shfl_xor(s, off, 64);
  const float mu = s * 0.00390625f;
  const float a = v.x - mu, b = v.y - mu, c = v.z - mu, d = v.w - mu;
  float q = a * a + b * b + c * c + d * d;
#pragma unroll
  for (int off = 32; off > 0; off >>= 1) q += __shfl_xor(q, off, 64);
  const float rs = rsqrtf(q * 0.00390625f + 1e-5f);
  const float o0 = a * rs * in_elem(gamw, cb + 0, m) + in_elem(betw, cb + 0, m);
  const float o1 = b * rs * in_elem(gamw, cb + 1, m) + in_elem(betw, cb + 1, m);
  const float o2 = c * rs * in_elem(gamw, cb + 2, m) + in_elem(betw, cb + 2, m);
  const float o3 = d * rs * in_elem(gamw, cb + 3, m) + in_elem(betw, cb + 3, m);
  const u32 p0 = (u32)f2b(o0) | ((u32)f2b(o1) << 16);
  const u32 p1 = (u32)f2b(o2) | ((u32)f2b(o3) << 16);
  *(uint2*)((u16*)outp + (size_t)row * 256 + cb) = make_uint2(p0, p1);
}

// ---------------- coalesced weight transpose: dst[c][r] = src[r][c], both depths ----------
__global__ __launch_bounds__(256) void k_transpose(
    const void* __restrict__ src, bf16* __restrict__ dst,
    const int* __restrict__ mode, int estride, int dstride, int R, int Cn) {
  __shared__ float T[32][33];
  const int m = *mode;
  const int tx = threadIdx.x & 31, ty = threadIdx.x >> 5;  // ty in 0..7
  const int bc = blockIdx.x << 5, br = blockIdx.y << 5;
  for (int d = 0; d < 2; ++d) {
    __syncthreads();
#pragma unroll
    for (int dy = 0; dy < 4; ++dy) {
      const int r = br + ty + dy * 8;
      T[ty + dy * 8][tx] = in_elem(src, (size_t)d * estride + (size_t)r * Cn + bc + tx, m);
    }
    __syncthreads();
#pragma unroll
    for (int dy = 0; dy < 4; ++dy) {
      const int c = bc + ty + dy * 8;
      ((u16*)dst)[(size_t)d * dstride + (size_t)c * R + br + tx] = f2b(T[tx][ty + dy * 8]);
    }
  }
}

// ---------------- bf16 MFMA GEMM: C[M,N] = A[M,K] @ Bt[N,K]^T + bias ----------------
// Tile 128 x 128, 4 waves (2x2), 16x16x32 MFMA; depth-2 prefetch (3 buffers, counted
// vmcnt(4), vmcnt(0) on last iter); XOR-swizzled LDS; XCD-chunked block swizzle.
// Epilogue: wave-private [4][72] LDS transpose per (mi,r) -> uint2 coalesced stores
// (4 rows x 128B per instruction; 16 stores/thread vs 64 scalar).
// EPI: 0 = store bf16; 1 = GELU + bf16.
template <int EPI>
__global__ __launch_bounds__(256, 3) void k_gemm(
    const bf16* __restrict__ A, const bf16* __restrict__ Bt,
    const void* __restrict__ bias, bf16* __restrict__ outb,
    const int* __restrict__ mode, int boff, int K, int N)
{
  __shared__ __align__(16) bf16 As[3][128 * 32];
  __shared__ __align__(16) bf16 Bs[3][128 * 32];
  __shared__ __align__(16) float EPs[4][4][72];   // wave-private transpose scratch
  const int md = *mode;
  const int tid = threadIdx.x;
  const int l = tid & 63, wid = tid >> 6;
  const int wr = wid >> 1, wc = wid & 1;

  const int gx = gridDim.x;
  const int nwg = gx * gridDim.y;
  int fid = blockIdx.y * gx + blockIdx.x;
  if (!(nwg & 7)) fid = (fid & 7) * (nwg >> 3) + (fid >> 3);
  const int row0 = (fid / gx) * 128;
  const int col0 = (fid % gx) * 128;

  const int lrow = l >> 2;
  const int lkof = (((l & 3) ^ ((l >> 3) & 3)) * 8);    // swizzled staged k-chunk
  const int qsw  = (((l >> 4) ^ ((l >> 1) & 3)) * 8);   // swizzled read slot

  floatx4 acc[4][4];
#pragma unroll
  for (int mi = 0; mi < 4; ++mi)
#pragma unroll
    for (int ni = 0; ni < 4; ++ni)
      acc[mi][ni] = (floatx4){0.f, 0.f, 0.f, 0.f};

  auto stage = [&](int b, int kbase) {   // 4 global_load_lds per thread
    const int kk = kbase + lkof;
#pragma unroll
    for (int c = 0; c < 2; ++c) {
      const int seg = c * 4 + wid;
      async16(A + (size_t)(row0 + seg * 16 + lrow) * K + kk, &As[b][seg * 512]);
      async16(Bt + (size_t)(col0 + seg * 16 + lrow) * K + kk, &Bs[b][seg * 512]);
    }
  };

  const int nsl = K >> 5;
  stage(0, 0);
  stage(1, 32);

  for (int s = 0; s < nsl; ++s) {
    const int cur = s % 3;
    if (s < nsl - 1) { WAITCNT_VM(4); }  // slice-s landed; slice s+1's 4 may fly
    else            { WAITCNT_VM(0); }   // tail: only slice-s loads outstanding
    __builtin_amdgcn_s_barrier();        // slice s resident, slice s-1 reads done
    if (s + 2 < nsl) stage((s + 2) % 3, (s + 2) * 32);  // overwrites slice s-1's buffer

    short8 af[4], bq[4];
#pragma unroll
    for (int mi = 0; mi < 4; ++mi)
      af[mi] = *(const short8*)&As[cur][(wr * 64 + mi * 16 + (l & 15)) * 32 + qsw];
#pragma unroll
    for (int ni = 0; ni < 4; ++ni)
      bq[ni] = *(const short8*)&Bs[cur][(wc * 64 + ni * 16 + (l & 15)) * 32 + qsw];
#pragma unroll
    for (int mi = 0; mi < 4; ++mi)
#pragma unroll
      for (int ni = 0; ni < 4; ++ni)
        acc[mi][ni] = __builtin_amdgcn_mfma_f32_16x16x32_bf16(af[mi], bq[ni], acc[mi][ni], 0, 0, 0);
  }

  // ---- epilogue: wave-private LDS transpose -> coalesced uint2 stores ----
  float* EPw = &EPs[wid][0][0];
  const int cl = l & 15, rq = l >> 4;   // fragment: col=lane&15, row=(lane>>4)*4+reg
  const int colb = wc * 64 + cl * 4;    // read-phase col base within 128-tile
  float bias4[4];
#pragma unroll
  for (int i = 0; i < 4; ++i) bias4[i] = in_elem(bias, (size_t)boff + col0 + colb + i, md);

#pragma unroll
  for (int mi = 0; mi < 4; ++mi) {
#pragma unroll
    for (int r = 0; r < 4; ++r) {
      // write: banks rq*8 + ni*16 + cl -> 2 lanes/bank (free)
#pragma unroll
      for (int ni = 0; ni < 4; ++ni)
        EPw[rq * 72 + ni * 16 + cl] = acc[mi][ni][r];
      // read: lane -> row slot l>>4, 4 consecutive cols (l&15)*4
      const float4 av = *(const float4*)&EPw[rq * 72 + cl * 4];
      float v0 = av.x + bias4[0], v1 = av.y + bias4[1];
      float v2 = av.z + bias4[2], v3 = av.w + bias4[3];
      if (EPI == 1) {
        v0 = gelu_cheap(v0); v1 = gelu_cheap(v1);
        v2 = gelu_cheap(v2); v3 = gelu_cheap(v3);
      }
      const int row = row0 + wr * 64 + mi * 16 + rq * 4 + r;
      const u32 p0 = (u32)f2b(v0) | ((u32)f2b(v1) << 16);
      const u32 p1 = (u32)f2b(v2) | ((u32)f2b(v3) << 16);
      *(uint2*)((u16*)outb + (size_t)row * N + col0 + colb) = make_uint2(p0, p1);
    }
  }
}

// ---------------- full-N GEMM (N=256 in one block) + fused residual/LN epilogues -------
// 4 waves x 16 rows x 256 cols (NI=16); depth-2 prefetch (3 buffers, vmcnt(5), vmcnt(0)
// tail). Epilogue: wave-private LDS transpose (wave owns 16 full rows; [4][272] scratch,
// free 2-way write banks, no barriers) -> lane-uniform row + float4/lane coalesced
// xf/out/bufB streams; LN = 6-step full-wave shfl tree. MODE:
//   0 = proj:  t = xf[winrev(row)]+v+bias; xf=t; bufB[tokenrow] = LN2(t)
//   1 = fc2(d0): t = xf[row]+v+bias; xf=t; bufB[winshift4(row)] = LN1d1(t)
//   2 = fc2(d1): out fp32 = xf[row] + v + bias   (final)
template <int MODE>
__global__ __launch_bounds__(256, 2) void k_fullN(
    const bf16* __restrict__ A, const bf16* __restrict__ Bt,
    const void* __restrict__ bias, const void* __restrict__ lng,
    const void* __restrict__ lnb, void* __restrict__ outp,
    float* __restrict__ xf, const int* __restrict__ mode,
    int boff, int lnoff, int K, int shift)
{
  // union: staging (3 bufs: As 3x4KB + Bs 3x16KB = 60KB) / epilogue scratch 17KB
  __shared__ __align__(16) char smem[61440];
  bf16* As = (bf16*)smem;                 // [3][64*32]
  bf16* Bs = (bf16*)(smem + 12288);       // [3][256*32]
  const int md = *mode;
  const int tid = threadIdx.x;
  const int l = tid & 63, w = tid >> 6;

  int fid = blockIdx.x;
  const int nwg = gridDim.x;
  if (!(nwg & 7)) fid = (fid & 7) * (nwg >> 3) + (fid >> 3);
  const int row0 = fid * 64;

  const int lrow = l >> 2;
  const int lkof = (((l & 3) ^ ((l >> 3) & 3)) * 8);
  const int qsw  = (((l >> 4) ^ ((l >> 1) & 3)) * 8);

  floatx4 acc[16];
#pragma unroll
  for (int ni = 0; ni < 16; ++ni) acc[ni] = (floatx4){0.f, 0.f, 0.f, 0.f};

  auto stage = [&](int b, int kbase) {   // 5 global_load_lds per thread
    const int kk = kbase + lkof;
    async16(A + (size_t)(row0 + w * 16 + lrow) * K + kk, As + b * 2048 + w * 512);
#pragma unroll
    for (int c = 0; c < 4; ++c) {
      const int seg = c * 4 + w;
      async16(Bt + (size_t)(seg * 16 + lrow) * K + kk, Bs + b * 8192 + seg * 512);
    }
  };

  const int nsl = K >> 5;
  stage(0, 0);
  stage(1, 32);

  for (int s = 0; s < nsl; ++s) {
    const int cur = s % 3;
    if (s < nsl - 1) { WAITCNT_VM(5); }  // slice-s landed; slice s+1's 5 may fly
    else            { WAITCNT_VM(0); }   // tail: only slice-s loads outstanding
    __builtin_amdgcn_s_barrier();
    if (s + 2 < nsl) stage((s + 2) % 3, (s + 2) * 32);

    const short8 af = *(const short8*)&As[cur * 2048 + (w * 16 + (l & 15)) * 32 + qsw];
#pragma unroll
    for (int ni = 0; ni < 16; ++ni) {
      const short8 bq = *(const short8*)&Bs[cur * 8192 + (ni * 16 + (l & 15)) * 32 + qsw];
      acc[ni] = __builtin_amdgcn_mfma_f32_16x16x32_bf16(af, bq, acc[ni], 0, 0, 0);
    }
  }

  // ---- epilogue: wave-private LDS transpose -> coalesced row streaming ----
  __syncthreads();   // all waves done with staging LDS (vmcnt/lgkm drained)

  float* EPw = (float*)smem + w * 1088;   // [4 rows][272 floats] = 4352 B per wave
  const int cl = l & 15, rq = l >> 4;     // C/D: col=lane&15, row=(lane>>4)*4+reg
  const int c4 = l * 4;                   // lane's col base in row-streaming phase

  float bias4[4], g4[4], b4[4];
#pragma unroll
  for (int i = 0; i < 4; ++i) bias4[i] = in_elem(bias, (size_t)boff + c4 + i, md);
  if (MODE != 2) {
#pragma unroll
    for (int i = 0; i < 4; ++i) {
      g4[i] = in_elem(lng, (size_t)lnoff + c4 + i, md);
      b4[i] = in_elem(lnb, (size_t)lnoff + c4 + i, md);
    }
  }

  for (int r = 0; r < 4; ++r) {
    // fragment -> wave-private LDS: row slot rq holds row_local rq*4+r.
    // banks: rq*272+ni*16+cl -> exactly 2 lanes/bank (free).
#pragma unroll
    for (int ni = 0; ni < 16; ++ni)
      EPw[rq * 272 + ni * 16 + cl] = acc[ni][r];

#pragma unroll
    for (int g = 0; g < 4; ++g) {
      const int lrow_g = row0 + w * 16 + g * 4 + r;   // lane-uniform global A-row
      const float4 av = *(const float4*)&EPw[g * 272 + c4];

      int resrow, dstrow;
      if (MODE == 0) {
        const int t_ = lrow_g & 63, win = lrow_g >> 6;
        const int bb = win >> 6, wi2 = win & 63;
        int gh = ((wi2 >> 3) << 3) + (t_ >> 3);
        int gw = ((wi2 & 7) << 3) + (t_ & 7);
        gh = (gh + shift) & 63; gw = (gw + shift) & 63;
        resrow = (bb << 12) + (gh << 6) + gw;
        dstrow = resrow;
      } else if (MODE == 1) {
        resrow = lrow_g;
        const int bb = lrow_g >> 12, th = (lrow_g >> 6) & 63, tw = lrow_g & 63;
        const int gh = (th + 60) & 63, gw = (tw + 60) & 63;
        const int wi2 = ((gh >> 3) << 3) + (gw >> 3);
        const int tt = ((gh & 7) << 3) + (gw & 7);
        dstrow = (bb << 12) + (wi2 << 6) + tt;
      } else {
        resrow = lrow_g; dstrow = lrow_g;
      }

      const float4 xv = *(const float4*)(xf + (size_t)resrow * 256 + c4);
      float t0 = av.x + bias4[0] + xv.x;
      float t1 = av.y + bias4[1] + xv.y;
      float t2 = av.z + bias4[2] + xv.z;
      float t3 = av.w + bias4[3] + xv.w;

      if (MODE == 2) {
        *(float4*)((float*)outp + (size_t)lrow_g * 256 + c4) = make_float4(t0, t1, t2, t3);
        continue;
      }

      float s = t0 + t1 + t2 + t3;
#pragma unroll
      for (int off = 32; off > 0; off >>= 1) s += __shfl_xor(s, off, 64);
      const float mu = s * 0.00390625f;
      const float d0 = t0 - mu, d1 = t1 - mu, d2 = t2 - mu, d3 = t3 - mu;
      float q = d0 * d0 + d1 * d1 + d2 * d2 + d3 * d3;
#pragma unroll
      for (int off = 32; off > 0; off >>= 1) q += __shfl_xor(q, off, 64);
      const float rs = rsqrtf(q * 0.00390625f + 1e-5f);

      *(float4*)(xf + (size_t)resrow * 256 + c4) = make_float4(t0, t1, t2, t3);
      const u32 p0 = (u32)f2b(d0 * rs * g4[0] + b4[0]) | ((u32)f2b(d1 * rs * g4[1] + b4[1]) << 16);
      const u32 p1 = (u32)f2b(d2 * rs * g4[2] + b4[2]) | ((u32)f2b(d3 * rs * g4[3] + b4[3]) << 16);
      *(uint2*)((u16*)outp + (size_t)dstrow * 256 + c4) = make_uint2(p0, p1);
    }
  }
}

// ---------------- windowed attention (MFMA; wave = window x head, 2 heads/wave) ----------------
__global__ __launch_bounds__(256, 2) void k_attn(
    const bf16* __restrict__ qkv, const void* __restrict__ rpb,
    bf16* __restrict__ outp, const int* __restrict__ mode, int eoff, int shifted)
{
  __shared__ __align__(16) u16 Pl[4][64][72];   // 36864 B
  __shared__ __align__(16) u16 Vt[4][32][72];   // 18432 B
  __shared__ float rpbs[4][228];                //  3648 B
  const int md = *mode;
  const int l = threadIdx.x & 63, w = threadIdx.x >> 6;
  const int cl = l & 15, qd = l >> 4;
  const int ko = qd * 8;
  const int win = blockIdx.x;
  const int wi = win & 63;
  const int whb = (wi >> 3) << 3, wwb = (wi & 7) << 3;
  const size_t rowbase = (size_t)win * 64 * 768;

  for (int hh = 0; hh < 2; ++hh) {
    const int h = w + hh * 4;
    for (int i = l; i < 225; i += 64)
      rpbs[w][i] = in_elem(rpb, (size_t)eoff + (size_t)i * 8 + h, md);
    {
      const u16* vrow = (const u16*)(qkv + rowbase + (size_t)l * 768 + 512 + h * 32);
#pragma unroll
      for (int n = 0; n < 32; ++n) Vt[w][n][l] = vrow[n];
    }
    short8 qf[4], kf[4];
#pragma unroll
    for (int t = 0; t < 4; ++t) {
      qf[t] = *(const short8*)(qkv + rowbase + (size_t)(t * 16 + cl) * 768 + h * 32 + ko);
      kf[t] = *(const short8*)(qkv + rowbase + (size_t)(t * 16 + cl) * 768 + 256 + h * 32 + ko);
    }
    __syncthreads();

    floatx4 S[4][4];
#pragma unroll
    for (int mi = 0; mi < 4; ++mi)
#pragma unroll
      for (int ni = 0; ni < 4; ++ni)
        S[mi][ni] = __builtin_amdgcn_mfma_f32_16x16x32_bf16(qf[mi], kf[ni], (floatx4){0.f, 0.f, 0.f, 0.f}, 0, 0, 0);

    int cty[4], ctx[4], clab[4];
#pragma unroll
    for (int ni = 0; ni < 4; ++ni) {
      const int ct = ni * 16 + cl;
      cty[ni] = ct >> 3; ctx[ni] = ct & 7;
      clab[ni] = shifted ? (swlab(whb + cty[ni]) * 3 + swlab(wwb + ctx[ni])) : 0;
    }

    float invs[4][4];
#pragma unroll
    for (int mi = 0; mi < 4; ++mi) {
#pragma unroll
      for (int r = 0; r < 4; ++r) {
        const int rt = mi * 16 + qd * 4 + r;
        const int rty = rt >> 3, rtx = rt & 7;
        const int rlab = shifted ? (swlab(whb + rty) * 3 + swlab(wwb + rtx)) : 0;
        float sv[4];
#pragma unroll
        for (int ni = 0; ni < 4; ++ni) {
          float x = S[mi][ni][r] * 0.17677669529663687f;
          x += rpbs[w][(rty - cty[ni] + 7) * 15 + (rtx - ctx[ni] + 7)];
          if (shifted && (rlab != clab[ni])) x -= 100.f;
          sv[ni] = x;
        }
        float mx = fmaxf(fmaxf(sv[0], sv[1]), fmaxf(sv[2], sv[3]));
        mx = fmaxf(mx, __shfl_xor(mx, 1, 64));
        mx = fmaxf(mx, __shfl_xor(mx, 2, 64));
        mx = fmaxf(mx, __shfl_xor(mx, 4, 64));
        mx = fmaxf(mx, __shfl_xor(mx, 8, 64));
        float sum = 0.f;
#pragma unroll
        for (int ni = 0; ni < 4; ++ni) { sv[ni] = __expf(sv[ni] - mx); sum += sv[ni]; }
        sum += __shfl_xor(sum, 1, 64);
        sum += __shfl_xor(sum, 2, 64);
        sum += __shfl_xor(sum, 4, 64);
        sum += __shfl_xor(sum, 8, 64);
        invs[mi][r] = __builtin_amdgcn_rcpf(sum);
#pragma unroll
        for (int ni = 0; ni < 4; ++ni) Pl[w][rt][ni * 16 + cl] = f2b(sv[ni]);
      }
    }
    __syncthreads();

    floatx4 O[4][2];
#pragma unroll
    for (int mi = 0; mi < 4; ++mi)
#pragma unroll
      for (int nv = 0; nv < 2; ++nv)
        O[mi][nv] = (floatx4){0.f, 0.f, 0.f, 0.f};
    short8 vf[2][2];
#pragma unroll
    for (int nv = 0; nv < 2; ++nv)
#pragma unroll
      for (int kk = 0; kk < 2; ++kk)
        vf[nv][kk] = *(const short8*)&Vt[w][nv * 16 + cl][kk * 32 + ko];
#pragma unroll
    for (int mi = 0; mi < 4; ++mi) {
      const short8 pf0 = *(const short8*)&Pl[w][mi * 16 + cl][ko];
      const short8 pf1 = *(const short8*)&Pl[w][mi * 16 + cl][32 + ko];
#pragma unroll
      for (int nv = 0; nv < 2; ++nv) {
        O[mi][nv] = __builtin_amdgcn_mfma_f32_16x16x32_bf16(pf0, vf[nv][0], O[mi][nv], 0, 0, 0);
        O[mi][nv] = __builtin_amdgcn_mfma_f32_16x16x32_bf16(pf1, vf[nv][1], O[mi][nv], 0, 0, 0);
      }
    }

#pragma unroll
    for (int mi = 0; mi < 4; ++mi)
#pragma unroll
      for (int nv = 0; nv < 2; ++nv)
#pragma unroll
        for (int r = 0; r < 4; ++r) {
          const int row = mi * 16 + qd * 4 + r;
          ((u16*)outp)[((size_t)win * 64 + row) * 256 + h * 32 + nv * 16 + cl] =
              f2b(O[mi][nv][r] * invs[mi][r]);
        }
    __syncthreads();
  }
}

// ---------------- host launcher ----------------
extern "C" void kernel_launch(void* const* d_in, const int* in_sizes, int n_in,
                              void* d_out, int out_size, void* d_ws, size_t ws_size,
                              hipStream_t stream) {
  (void)in_sizes; (void)n_in; (void)out_size; (void)ws_size;
  const void* x_in   = d_in[0];
  const void* qkv_w  = d_in[1];
  const void* qkv_b  = d_in[2];
  const void* proj_w = d_in[3];
  const void* proj_b = d_in[4];
  const void* ln1_g  = d_in[5];
  const void* ln1_b  = d_in[6];
  const void* ln2_g  = d_in[7];
  const void* ln2_b  = d_in[8];
  const void* fc1_w  = d_in[9];
  const void* fc1_b  = d_in[10];
  const void* fc2_w  = d_in[11];
  const void* fc2_b  = d_in[12];
  const void* rpb    = d_in[13];

  char* ws = (char*)d_ws;
  float* xf  = (float*)ws;                   // 32 MiB
  bf16* bufH = (bf16*)(ws + 33554432);       // 64 MiB fc1 hidden
  bf16* bufQ = (bf16*)(ws + 100663296);      // 48 MiB qkv
  bf16* bufB = (bf16*)(ws + 150994944);      // 16 MiB LN out / attn out
  bf16* wT   = (bf16*)(ws + 167772160);      // 3 MiB
  int* mode  = (int*)(ws + 170917888);       // 4 B

  k_detect<<<1, 1, 0, stream>>>((const u32*)ln1_g, mode);
  // ingest + LN1(depth0): x -> xf, LN -> bufB (windowed, shift=0)
  k_ingest_ln<<<8192, 256, 0, stream>>>(x_in, xf, ln1_g, ln1_b, bufB, mode);

  // transposed weights per depth:
  // qkvT[768][256] @0, projT[256][256] @196608, fc1T[1024][256] @262144, fc2T[256][1024] @524288
  k_transpose<<<dim3(24, 8), 256, 0, stream>>>(qkv_w,  wT,          mode, 196608, 786432, 256, 768);
  k_transpose<<<dim3(8, 8), 256, 0, stream>>>(proj_w, wT + 196608, mode, 65536, 786432, 256, 256);
  k_transpose<<<dim3(32, 8), 256, 0, stream>>>(fc1_w, wT + 262144, mode, 262144, 786432, 256, 1024);
  k_transpose<<<dim3(8, 32), 256, 0, stream>>>(fc2_w, wT + 524288, mode, 262144, 786432, 1024, 256);

  for (int i = 0; i < 2; ++i) {
    const int shift = i ? 4 : 0;
    bf16* base  = wT + (size_t)i * 786432;
    bf16* qkvT  = base;
    bf16* projT = base + 196608;
    bf16* fc1T  = base + 262144;
    bf16* fc2T  = base + 524288;

    // QKV: bufQ[32768,768] = bufB @ qkv_w + b
    k_gemm<0><<<dim3(6, 256), 256, 0, stream>>>(bufB, qkvT, qkv_b, bufQ, mode, i * 768, 256, 768);
    // windowed attention: bufQ -> bufB
    k_attn<<<512, 256, 0, stream>>>(bufQ, rpb, bufB, mode, i * 1800, i);
    // proj + window-reverse(+unshift) + residual into xf + LN2 -> bufB (token order)
    k_fullN<0><<<512, 256, 0, stream>>>(bufB, projT, proj_b, ln2_g, ln2_b, bufB, xf, mode,
                                        i * 256, i * 256, 256, shift);
    // FC1: bufH[32768,1024] = GELU(bufB @ fc1_w + b)
    k_gemm<1><<<dim3(8, 256), 256, 0, stream>>>(bufB, fc1T, fc1_b, bufH, mode, i * 1024, 256, 1024);
    // FC2 (K=1024) + residual; depth0 fuses LN1(depth1, shift=4) -> bufB windowed;
    // depth1 writes final fp32 output directly
    if (i == 0)
      k_fullN<1><<<512, 256, 0, stream>>>(bufH, fc2T, fc2_b, ln1_g, ln1_b, bufB, xf, mode,
                                          0, 256, 1024, 4);
    else
      k_fullN<2><<<512, 256, 0, stream>>>(bufH, fc2T, fc2_b, nullptr, nullptr, d_out, xf, mode,
                                          256, 0, 1024, 0);
  }
}

// Round 9
// 421.229 us; speedup vs baseline: 1.1723x; 1.0086x over previous
//
#include <hip/hip_runtime.h>
#include <hip/hip_bf16.h>

// SwinTransformerEncoder on gfx950.
// H=W=64, C=256, HEADS=8 (d=32), WS=8, N=64 tok/window, NW=64, B=8, DEPTH=2, HIDDEN=1024.
// Inputs fp32 (runtime probe also supports bf16-cast). OUTPUT fp32. Residual fp32 in ws.
// R17 = R16 resubmit (R16 bench died to a container/acquisition flake; kernel audit
// found no hang/fault path: uniform barriers, all LDS/global indices in bounds,
// 80KB static LDS legal on gfx950).
// R16: (1) FC1+FC2 fused into k_mlp: block owns 64 token rows; A panel staged once
//     (32KB, 8 swizzled slices); 8 hidden-chunks of 128: FC1 (4 BK=64 phases) ->
//     GELU -> bf16 H tile in LDS (wave-private rows, A-fragment swizzle) -> FC2
//     partials into persistent acc2[16]; W1/W2 double-buffered (16KB slices, 2-phase
//     __syncthreads pipeline; weights L2-resident). Kills the 128MB bufH round-trip
//     (~40us/depth) + one dispatch/depth. 80KB LDS, 2 blocks/CU. (2) Buffer chain
//     reworked (attn->bufB, proj LN2->bufQ, mlp->bufB/d_out): removes fullN<0>'s
//     latent read/write-bufB cross-block race; bufH dropped entirely.
//
// Workspace (~100 MiB of 256 MiB):
//   xf   fp32 [8*4096*256]   @ 0          (32 MiB)  residual stream
//   bufQ bf16 [32768*768]    @ 100663296  (48 MiB)  qkv / LN2 out
//   bufB bf16 [32768*256]    @ 150994944  (16 MiB)  LN out / attn out
//   wT   bf16 [2*786432]     @ 167772160  (3 MiB)   transposed weights
//   mode int                 @ 170917888  (4 B)     input-dtype flag (1=bf16, 0=fp32)

typedef __hip_bfloat16 bf16;
typedef unsigned short u16;
typedef unsigned int u32;
typedef short short8 __attribute__((ext_vector_type(8)));
typedef float floatx4 __attribute__((ext_vector_type(4)));

#define DEVI static __device__ __forceinline__
#define WAITCNT_VM(n) asm volatile("s_waitcnt vmcnt(" #n ")" ::: "memory")

DEVI float lo16(u32 u) { union { u32 i; float f; } x; x.i = u << 16; return x.f; }
DEVI float hi16(u32 u) { union { u32 i; float f; } x; x.i = u & 0xffff0000u; return x.f; }
DEVI float b2f(u16 u) { union { u32 i; float f; } x; x.i = ((u32)u) << 16; return x.f; }
DEVI u16 f2b(float f) {  // round-to-nearest-even
  union { float f; u32 i; } x; x.f = f;
  u32 r = x.i + 0x7fffu + ((x.i >> 16) & 1u);
  return (u16)(r >> 16);
}
DEVI float in_elem(const void* p, size_t i, int m) {
  return m ? b2f(((const u16*)p)[i]) : ((const float*)p)[i];
}
DEVI int swlab(int g) { return (g < 56) ? 0 : (g < 60 ? 1 : 2); }

// GELU via tanh form, 7 VALU ops (max abs err vs exact-erf GELU ~3e-4, << bf16 quant).
DEVI float gelu_cheap(float v) {
  const float u = v * v;
  const float t = v * __builtin_fmaf(0.1029436f, u, 2.3022090f);
  const float e = __builtin_amdgcn_exp2f(t);
  const float r = __builtin_amdgcn_rcpf(e + 1.0f);
  return __builtin_fmaf(-v, r, v);
}

DEVI void async16(const bf16* g, bf16* l) {
  __builtin_amdgcn_global_load_lds((const __attribute__((address_space(1))) u32*)g,
                                   (__attribute__((address_space(3))) u32*)l, 16, 0, 0);
}

// ---------------- dtype probe (ln1_g is all-ones) ----------------
__global__ void k_detect(const u32* __restrict__ ln1g, int* __restrict__ mode) {
  if (threadIdx.x == 0 && blockIdx.x == 0)
    *mode = (ln1g[0] == 0x3F803F80u) ? 1 : 0;
}

// ---------------- ingest + LN1(depth0): x -> xf copy, LN -> bufB windowed ----------------
__global__ __launch_bounds__(256) void k_ingest_ln(const void* __restrict__ xin,
    float* __restrict__ xf, const void* __restrict__ gamw, const void* __restrict__ betw,
    bf16* __restrict__ outp, const int* __restrict__ mode)
{
  const int m = *mode;
  const int l = threadIdx.x & 63, w = threadIdx.x >> 6;
  const int row = blockIdx.x * 4 + w;     // window-order output row
  const int t = row & 63, win = row >> 6;
  const int bb = win >> 6, wi = win & 63;
  const int gh = ((wi >> 3) << 3) + (t >> 3);
  const int gw = ((wi & 7) << 3) + (t & 7);
  const int srow = (bb << 12) + (gh << 6) + gw;   // token row (shift=0)
  const int cb = l << 2;
  float4 v;
  if (m) {
    const uint2 u = *(const uint2*)((const u16*)xin + (size_t)srow * 256 + cb);
    v = make_float4(lo16(u.x), hi16(u.x), lo16(u.y), hi16(u.y));
  } else {
    v = ((const float4*)((const float*)xin + (size_t)srow * 256))[l];
  }
  ((float4*)(xf + (size_t)srow * 256))[l] = v;    // residual copy
  float s = v.x + v.y + v.z + v.w;
#pragma unroll
  for (int off = 32; off > 0; off >>= 1) s += __shfl_xor(s, off, 64);
  const float mu = s * 0.00390625f;
  const float a = v.x - mu, b = v.y - mu, c = v.z - mu, d = v.w - mu;
  float q = a * a + b * b + c * c + d * d;
#pragma unroll
  for (int off = 32; off > 0; off >>= 1) q += __shfl_xor(q, off, 64);
  const float rs = rsqrtf(q * 0.00390625f + 1e-5f);
  const float o0 = a * rs * in_elem(gamw, cb + 0, m) + in_elem(betw, cb + 0, m);
  const float o1 = b * rs * in_elem(gamw, cb + 1, m) + in_elem(betw, cb + 1, m);
  const float o2 = c * rs * in_elem(gamw, cb + 2, m) + in_elem(betw, cb + 2, m);
  const float o3 = d * rs * in_elem(gamw, cb + 3, m) + in_elem(betw, cb + 3, m);
  const u32 p0 = (u32)f2b(o0) | ((u32)f2b(o1) << 16);
  const u32 p1 = (u32)f2b(o2) | ((u32)f2b(o3) << 16);
  *(uint2*)((u16*)outp + (size_t)row * 256 + cb) = make_uint2(p0, p1);
}

// ---------------- coalesced weight transpose: dst[c][r] = src[r][c], both depths ----------
__global__ __launch_bounds__(256) void k_transpose(
    const void* __restrict__ src, bf16* __restrict__ dst,
    const int* __restrict__ mode, int estride, int dstride, int R, int Cn) {
  __shared__ float T[32][33];
  const int m = *mode;
  const int tx = threadIdx.x & 31, ty = threadIdx.x >> 5;  // ty in 0..7
  const int bc = blockIdx.x << 5, br = blockIdx.y << 5;
  for (int d = 0; d < 2; ++d) {
    __syncthreads();
#pragma unroll
    for (int dy = 0; dy < 4; ++dy) {
      const int r = br + ty + dy * 8;
      T[ty + dy * 8][tx] = in_elem(src, (size_t)d * estride + (size_t)r * Cn + bc + tx, m);
    }
    __syncthreads();
#pragma unroll
    for (int dy = 0; dy < 4; ++dy) {
      const int c = bc + ty + dy * 8;
      ((u16*)dst)[(size_t)d * dstride + (size_t)c * R + br + tx] = f2b(T[tx][ty + dy * 8]);
    }
  }
}

// ---------------- bf16 MFMA GEMM: C[M,N] = A[M,K] @ Bt[N,K]^T + bias ----------------
// Tile 128 x 128, 4 waves (2x2), 16x16x32 MFMA; depth-2 prefetch (3 buffers, counted
// vmcnt(4), vmcnt(0) on last iter); XOR-swizzled LDS; XCD-chunked block swizzle.
// Epilogue: wave-private [4][72] LDS transpose -> uint2 coalesced stores.
template <int EPI>
__global__ __launch_bounds__(256, 3) void k_gemm(
    const bf16* __restrict__ A, const bf16* __restrict__ Bt,
    const void* __restrict__ bias, bf16* __restrict__ outb,
    const int* __restrict__ mode, int boff, int K, int N)
{
  __shared__ __align__(16) bf16 As[3][128 * 32];
  __shared__ __align__(16) bf16 Bs[3][128 * 32];
  __shared__ __align__(16) float EPs[4][4][72];   // wave-private transpose scratch
  const int md = *mode;
  const int tid = threadIdx.x;
  const int l = tid & 63, wid = tid >> 6;
  const int wr = wid >> 1, wc = wid & 1;

  const int gx = gridDim.x;
  const int nwg = gx * gridDim.y;
  int fid = blockIdx.y * gx + blockIdx.x;
  if (!(nwg & 7)) fid = (fid & 7) * (nwg >> 3) + (fid >> 3);
  const int row0 = (fid / gx) * 128;
  const int col0 = (fid % gx) * 128;

  const int lrow = l >> 2;
  const int lkof = (((l & 3) ^ ((l >> 3) & 3)) * 8);    // swizzled staged k-chunk
  const int qsw  = (((l >> 4) ^ ((l >> 1) & 3)) * 8);   // swizzled read slot

  floatx4 acc[4][4];
#pragma unroll
  for (int mi = 0; mi < 4; ++mi)
#pragma unroll
    for (int ni = 0; ni < 4; ++ni)
      acc[mi][ni] = (floatx4){0.f, 0.f, 0.f, 0.f};

  auto stage = [&](int b, int kbase) {   // 4 global_load_lds per thread
    const int kk = kbase + lkof;
#pragma unroll
    for (int c = 0; c < 2; ++c) {
      const int seg = c * 4 + wid;
      async16(A + (size_t)(row0 + seg * 16 + lrow) * K + kk, &As[b][seg * 512]);
      async16(Bt + (size_t)(col0 + seg * 16 + lrow) * K + kk, &Bs[b][seg * 512]);
    }
  };

  const int nsl = K >> 5;
  stage(0, 0);
  stage(1, 32);

  for (int s = 0; s < nsl; ++s) {
    const int cur = s % 3;
    if (s < nsl - 1) { WAITCNT_VM(4); }  // slice-s landed; slice s+1's 4 may fly
    else            { WAITCNT_VM(0); }   // tail: only slice-s loads outstanding
    __builtin_amdgcn_s_barrier();        // slice s resident, slice s-1 reads done
    if (s + 2 < nsl) stage((s + 2) % 3, (s + 2) * 32);  // overwrites slice s-1's buffer

    short8 af[4], bq[4];
#pragma unroll
    for (int mi = 0; mi < 4; ++mi)
      af[mi] = *(const short8*)&As[cur][(wr * 64 + mi * 16 + (l & 15)) * 32 + qsw];
#pragma unroll
    for (int ni = 0; ni < 4; ++ni)
      bq[ni] = *(const short8*)&Bs[cur][(wc * 64 + ni * 16 + (l & 15)) * 32 + qsw];
#pragma unroll
    for (int mi = 0; mi < 4; ++mi)
#pragma unroll
      for (int ni = 0; ni < 4; ++ni)
        acc[mi][ni] = __builtin_amdgcn_mfma_f32_16x16x32_bf16(af[mi], bq[ni], acc[mi][ni], 0, 0, 0);
  }

  // ---- epilogue: wave-private LDS transpose -> coalesced uint2 stores ----
  float* EPw = &EPs[wid][0][0];
  const int cl = l & 15, rq = l >> 4;   // fragment: col=lane&15, row=(lane>>4)*4+reg
  const int colb = wc * 64 + cl * 4;    // read-phase col base within 128-tile
  float bias4[4];
#pragma unroll
  for (int i = 0; i < 4; ++i) bias4[i] = in_elem(bias, (size_t)boff + col0 + colb + i, md);

#pragma unroll
  for (int mi = 0; mi < 4; ++mi) {
#pragma unroll
    for (int r = 0; r < 4; ++r) {
#pragma unroll
      for (int ni = 0; ni < 4; ++ni)
        EPw[rq * 72 + ni * 16 + cl] = acc[mi][ni][r];
      const float4 av = *(const float4*)&EPw[rq * 72 + cl * 4];
      float v0 = av.x + bias4[0], v1 = av.y + bias4[1];
      float v2 = av.z + bias4[2], v3 = av.w + bias4[3];
      if (EPI == 1) {
        v0 = gelu_cheap(v0); v1 = gelu_cheap(v1);
        v2 = gelu_cheap(v2); v3 = gelu_cheap(v3);
      }
      const int row = row0 + wr * 64 + mi * 16 + rq * 4 + r;
      const u32 p0 = (u32)f2b(v0) | ((u32)f2b(v1) << 16);
      const u32 p1 = (u32)f2b(v2) | ((u32)f2b(v3) << 16);
      *(uint2*)((u16*)outb + (size_t)row * N + col0 + colb) = make_uint2(p0, p1);
    }
  }
}

// ---------------- full-N GEMM (N=256) + fused residual/LN epilogue (proj only now) ----
// MODE 0 = proj: t = xf[winrev(row)]+v+bias; xf=t; outp[tokenrow] = LN2(t)
template <int MODE>
__global__ __launch_bounds__(256, 2) void k_fullN(
    const bf16* __restrict__ A, const bf16* __restrict__ Bt,
    const void* __restrict__ bias, const void* __restrict__ lng,
    const void* __restrict__ lnb, void* __restrict__ outp,
    float* __restrict__ xf, const int* __restrict__ mode,
    int boff, int lnoff, int K, int shift)
{
  __shared__ __align__(16) char smem[61440];
  bf16* As = (bf16*)smem;                 // [3][64*32]
  bf16* Bs = (bf16*)(smem + 12288);       // [3][256*32]
  const int md = *mode;
  const int tid = threadIdx.x;
  const int l = tid & 63, w = tid >> 6;

  int fid = blockIdx.x;
  const int nwg = gridDim.x;
  if (!(nwg & 7)) fid = (fid & 7) * (nwg >> 3) + (fid >> 3);
  const int row0 = fid * 64;

  const int lrow = l >> 2;
  const int lkof = (((l & 3) ^ ((l >> 3) & 3)) * 8);
  const int qsw  = (((l >> 4) ^ ((l >> 1) & 3)) * 8);

  floatx4 acc[16];
#pragma unroll
  for (int ni = 0; ni < 16; ++ni) acc[ni] = (floatx4){0.f, 0.f, 0.f, 0.f};

  auto stage = [&](int b, int kbase) {   // 5 global_load_lds per thread
    const int kk = kbase + lkof;
    async16(A + (size_t)(row0 + w * 16 + lrow) * K + kk, As + b * 2048 + w * 512);
#pragma unroll
    for (int c = 0; c < 4; ++c) {
      const int seg = c * 4 + w;
      async16(Bt + (size_t)(seg * 16 + lrow) * K + kk, Bs + b * 8192 + seg * 512);
    }
  };

  const int nsl = K >> 5;
  stage(0, 0);
  stage(1, 32);

  for (int s = 0; s < nsl; ++s) {
    const int cur = s % 3;
    if (s < nsl - 1) { WAITCNT_VM(5); }
    else            { WAITCNT_VM(0); }   // tail: only slice-s loads outstanding
    __builtin_amdgcn_s_barrier();
    if (s + 2 < nsl) stage((s + 2) % 3, (s + 2) * 32);

    const short8 af = *(const short8*)&As[cur * 2048 + (w * 16 + (l & 15)) * 32 + qsw];
#pragma unroll
    for (int ni = 0; ni < 16; ++ni) {
      const short8 bq = *(const short8*)&Bs[cur * 8192 + (ni * 16 + (l & 15)) * 32 + qsw];
      acc[ni] = __builtin_amdgcn_mfma_f32_16x16x32_bf16(af, bq, acc[ni], 0, 0, 0);
    }
  }

  // ---- epilogue: wave-private LDS transpose -> coalesced row streaming ----
  __syncthreads();

  float* EPw = (float*)smem + w * 1088;   // [4 rows][272 floats]
  const int cl = l & 15, rq = l >> 4;
  const int c4 = l * 4;

  float bias4[4], g4[4], b4[4];
#pragma unroll
  for (int i = 0; i < 4; ++i) bias4[i] = in_elem(bias, (size_t)boff + c4 + i, md);
#pragma unroll
  for (int i = 0; i < 4; ++i) {
    g4[i] = in_elem(lng, (size_t)lnoff + c4 + i, md);
    b4[i] = in_elem(lnb, (size_t)lnoff + c4 + i, md);
  }

  for (int r = 0; r < 4; ++r) {
#pragma unroll
    for (int ni = 0; ni < 16; ++ni)
      EPw[rq * 272 + ni * 16 + cl] = acc[ni][r];

#pragma unroll
    for (int g = 0; g < 4; ++g) {
      const int lrow_g = row0 + w * 16 + g * 4 + r;
      const float4 av = *(const float4*)&EPw[g * 272 + c4];

      const int t_ = lrow_g & 63, win = lrow_g >> 6;
      const int bb = win >> 6, wi2 = win & 63;
      int gh = ((wi2 >> 3) << 3) + (t_ >> 3);
      int gw = ((wi2 & 7) << 3) + (t_ & 7);
      gh = (gh + shift) & 63; gw = (gw + shift) & 63;
      const int resrow = (bb << 12) + (gh << 6) + gw;
      const int dstrow = resrow;

      const float4 xv = *(const float4*)(xf + (size_t)resrow * 256 + c4);
      float t0 = av.x + bias4[0] + xv.x;
      float t1 = av.y + bias4[1] + xv.y;
      float t2 = av.z + bias4[2] + xv.z;
      float t3 = av.w + bias4[3] + xv.w;

      float s = t0 + t1 + t2 + t3;
#pragma unroll
      for (int off = 32; off > 0; off >>= 1) s += __shfl_xor(s, off, 64);
      const float mu = s * 0.00390625f;
      const float d0 = t0 - mu, d1 = t1 - mu, d2 = t2 - mu, d3 = t3 - mu;
      float q = d0 * d0 + d1 * d1 + d2 * d2 + d3 * d3;
#pragma unroll
      for (int off = 32; off > 0; off >>= 1) q += __shfl_xor(q, off, 64);
      const float rs = rsqrtf(q * 0.00390625f + 1e-5f);

      *(float4*)(xf + (size_t)resrow * 256 + c4) = make_float4(t0, t1, t2, t3);
      const u32 p0 = (u32)f2b(d0 * rs * g4[0] + b4[0]) | ((u32)f2b(d1 * rs * g4[1] + b4[1]) << 16);
      const u32 p1 = (u32)f2b(d2 * rs * g4[2] + b4[2]) | ((u32)f2b(d3 * rs * g4[3] + b4[3]) << 16);
      *(uint2*)((u16*)outp + (size_t)dstrow * 256 + c4) = make_uint2(p0, p1);
    }
  }
}

// ---------------- fused MLP: out = FC2(GELU(FC1(A))) + residual (+LN1d1) ----------------
// Block = 64 token rows, 4 waves (wave owns rows w*16..+15 throughout). A panel (64x256)
// staged once (8 swizzled 32-k slices, 32KB). 8 hidden-chunks of 128: FC1 = 4 phases of
// BK=64 -> bias+GELU -> bf16 H tile (16KB, A-fragment swizzle, wave-private rows) ->
// FC2 = 4 phases of 32-hk into persistent acc2[16]. W1/W2 16KB slices double-buffered
// (2-phase __syncthreads pipeline; weights L2-resident). 8 barriers/chunk.
// MODE 1 = fc2(d0): t = xf[row]+v+b2; xf=t; outp[winshift4(row)] = LN1d1(t) (bf16)
// MODE 2 = fc2(d1): outp fp32 = xf[row] + v + b2  (final)
template <int MODE>
__global__ __launch_bounds__(256) void k_mlp(
    const bf16* __restrict__ A, const bf16* __restrict__ W1t, const bf16* __restrict__ W2t,
    const void* __restrict__ b1, const void* __restrict__ b2,
    const void* __restrict__ lng, const void* __restrict__ lnb,
    void* __restrict__ outp, float* __restrict__ xf, const int* __restrict__ mode,
    int b1off, int b2off, int lnoff)
{
  __shared__ __align__(16) char smem[81920];          // 80 KB -> 2 blocks/CU
  bf16* Al = (bf16*)smem;                             // [8][64*32]  32 KB (A slices)
  bf16* Wl = (bf16*)(smem + 32768);                   // [2][8192]   32 KB (W dbuf)
  u16*  Hl = (u16*)(smem + 65536);                    // [4][64*32]  16 KB (hidden chunk)
  const int md = *mode;
  const int tid = threadIdx.x;
  const int l = tid & 63, w = tid >> 6;
  int fid = blockIdx.x;
  const int nwg = gridDim.x;
  if (!(nwg & 7)) fid = (fid & 7) * (nwg >> 3) + (fid >> 3);
  const int row0 = fid * 64;

  const int lr4 = l >> 2;                             // staging row within 16-row seg
  const int lkof = (((l & 3) ^ ((l >> 3) & 3)) * 8);  // pre-swizzled global k-chunk
  const int qsw  = (((l >> 4) ^ ((l >> 1) & 3)) * 8); // swizzled LDS read slot
  const int cl = l & 15, rq = l >> 4;

  floatx4 acc2[16];
#pragma unroll
  for (int ni = 0; ni < 16; ++ni) acc2[ni] = (floatx4){0.f, 0.f, 0.f, 0.f};

  // W1 pair-stage: slices s, s+1 of chunk c (each 128 Hrows x 32 k) -> buf halves
  auto stageW1 = [&](int c, int s, int b) {           // 4 loads/thread
#pragma unroll
    for (int cc = 0; cc < 2; ++cc) {
      const int seg = w * 2 + cc;
      const size_t gr = (size_t)(c * 128 + seg * 16 + lr4) * 256;
      async16(W1t + gr + s * 32 + lkof,       Wl + b * 8192 + seg * 512);
      async16(W1t + gr + (s + 1) * 32 + lkof, Wl + b * 8192 + 4096 + seg * 512);
    }
  };
  // W2 stage: slice q of chunk c (256 out-rows x 32 hk) -> full buf
  auto stageW2 = [&](int c, int q, int b) {           // 4 loads/thread
#pragma unroll
    for (int cc = 0; cc < 4; ++cc) {
      const int seg = w * 4 + cc;
      async16(W2t + (size_t)(seg * 16 + lr4) * 1024 + c * 128 + q * 32 + lkof,
              Wl + b * 8192 + seg * 512);
    }
  };

  // prologue: A panel (8 slices) + W1 chunk0 slices 0,1 -> buf 0
#pragma unroll
  for (int s = 0; s < 8; ++s)
    async16(A + (size_t)(row0 + w * 16 + lr4) * 256 + s * 32 + lkof, Al + s * 2048 + w * 512);
  stageW1(0, 0, 0);

  int buf = 0;
  for (int c = 0; c < 8; ++c) {
    floatx4 acc1[8];
#pragma unroll
    for (int ni = 0; ni < 8; ++ni) acc1[ni] = (floatx4){0.f, 0.f, 0.f, 0.f};

    // FC1: 4 phases of BK=64 (K slices 2p, 2p+1)
    for (int p = 0; p < 4; ++p) {
      __syncthreads();                                // phase-p W landed; buf^1 free
      if (p < 3) stageW1(c, 2 * (p + 1), buf ^ 1);
      else       stageW2(c, 0, buf ^ 1);
      const short8 af0 = *(const short8*)&Al[(2 * p) * 2048 + (w * 16 + cl) * 32 + qsw];
      const short8 af1 = *(const short8*)&Al[(2 * p + 1) * 2048 + (w * 16 + cl) * 32 + qsw];
#pragma unroll
      for (int ni = 0; ni < 8; ++ni) {
        const short8 bq0 = *(const short8*)(Wl + buf * 8192 + (ni * 16 + cl) * 32 + qsw);
        acc1[ni] = __builtin_amdgcn_mfma_f32_16x16x32_bf16(af0, bq0, acc1[ni], 0, 0, 0);
      }
#pragma unroll
      for (int ni = 0; ni < 8; ++ni) {
        const short8 bq1 = *(const short8*)(Wl + buf * 8192 + 4096 + (ni * 16 + cl) * 32 + qsw);
        acc1[ni] = __builtin_amdgcn_mfma_f32_16x16x32_bf16(af1, bq1, acc1[ni], 0, 0, 0);
      }
      buf ^= 1;
    }

    // bias + GELU -> H tile (A-fragment swizzled layout; wave-private rows)
#pragma unroll
    for (int ni = 0; ni < 8; ++ni) {
      const int hc = ni * 16 + cl;
      const float bv = in_elem(b1, (size_t)b1off + c * 128 + hc, md);
      const int hbase = (hc >> 5) * 2048;
      const int hq = (hc >> 3) & 3, he = hc & 7;
#pragma unroll
      for (int r = 0; r < 4; ++r) {
        const int hr = w * 16 + rq * 4 + r;
        Hl[hbase + hr * 32 + ((hq ^ ((hr >> 1) & 3)) * 8) + he] =
            f2b(gelu_cheap(acc1[ni][r] + bv));
      }
    }

    // FC2: 4 phases of 32-hk; accumulate into acc2
    for (int q = 0; q < 4; ++q) {
      __syncthreads();                                // W2 slice q landed; H visible
      if (q < 3)      stageW2(c, q + 1, buf ^ 1);
      else if (c < 7) stageW1(c + 1, 0, buf ^ 1);
      const short8 hf = *(const short8*)((const bf16*)&Hl[q * 2048 + (w * 16 + cl) * 32 + qsw]);
#pragma unroll
      for (int ni = 0; ni < 16; ++ni) {
        const short8 bq = *(const short8*)(Wl + buf * 8192 + (ni * 16 + cl) * 32 + qsw);
        acc2[ni] = __builtin_amdgcn_mfma_f32_16x16x32_bf16(hf, bq, acc2[ni], 0, 0, 0);
      }
      buf ^= 1;
    }
  }

  // ---- epilogue (fullN-style): wave-private LDS transpose -> coalesced streams ----
  __syncthreads();
  float* EPw = (float*)smem + w * 1088;               // overlays Al (dead)
  const int c4 = l * 4;

  float bias4[4], g4[4], b4[4];
#pragma unroll
  for (int i = 0; i < 4; ++i) bias4[i] = in_elem(b2, (size_t)b2off + c4 + i, md);
  if (MODE == 1) {
#pragma unroll
    for (int i = 0; i < 4; ++i) {
      g4[i] = in_elem(lng, (size_t)lnoff + c4 + i, md);
      b4[i] = in_elem(lnb, (size_t)lnoff + c4 + i, md);
    }
  }

  for (int r = 0; r < 4; ++r) {
#pragma unroll
    for (int ni = 0; ni < 16; ++ni)
      EPw[rq * 272 + ni * 16 + cl] = acc2[ni][r];

#pragma unroll
    for (int g = 0; g < 4; ++g) {
      const int lrow_g = row0 + w * 16 + g * 4 + r;   // token row
      const float4 av = *(const float4*)&EPw[g * 272 + c4];
      const float4 xv = *(const float4*)(xf + (size_t)lrow_g * 256 + c4);
      float t0 = av.x + bias4[0] + xv.x;
      float t1 = av.y + bias4[1] + xv.y;
      float t2 = av.z + bias4[2] + xv.z;
      float t3 = av.w + bias4[3] + xv.w;

      if (MODE == 2) {
        *(float4*)((float*)outp + (size_t)lrow_g * 256 + c4) = make_float4(t0, t1, t2, t3);
        continue;
      }

      // token row -> windowed(shift=4) destination row
      const int bb = lrow_g >> 12, th = (lrow_g >> 6) & 63, tw = lrow_g & 63;
      const int gh = (th + 60) & 63, gw = (tw + 60) & 63;
      const int wi2 = ((gh >> 3) << 3) + (gw >> 3);
      const int tt = ((gh & 7) << 3) + (gw & 7);
      const int dstrow = (bb << 12) + (wi2 << 6) + tt;

      float s = t0 + t1 + t2 + t3;
#pragma unroll
      for (int off = 32; off > 0; off >>= 1) s += __shfl_xor(s, off, 64);
      const float mu = s * 0.00390625f;
      const float d0 = t0 - mu, d1 = t1 - mu, d2 = t2 - mu, d3 = t3 - mu;
      float q = d0 * d0 + d1 * d1 + d2 * d2 + d3 * d3;
#pragma unroll
      for (int off = 32; off > 0; off >>= 1) q += __shfl_xor(q, off, 64);
      const float rs = rsqrtf(q * 0.00390625f + 1e-5f);

      *(float4*)(xf + (size_t)lrow_g * 256 + c4) = make_float4(t0, t1, t2, t3);
      const u32 p0 = (u32)f2b(d0 * rs * g4[0] + b4[0]) | ((u32)f2b(d1 * rs * g4[1] + b4[1]) << 16);
      const u32 p1 = (u32)f2b(d2 * rs * g4[2] + b4[2]) | ((u32)f2b(d3 * rs * g4[3] + b4[3]) << 16);
      *(uint2*)((u16*)outp + (size_t)dstrow * 256 + c4) = make_uint2(p0, p1);
    }
  }
}

// ---------------- windowed attention (MFMA; wave = window x head, 2 heads/wave) ----------------
__global__ __launch_bounds__(256, 2) void k_attn(
    const bf16* __restrict__ qkv, const void* __restrict__ rpb,
    bf16* __restrict__ outp, const int* __restrict__ mode, int eoff, int shifted)
{
  __shared__ __align__(16) u16 Pl[4][64][72];   // 36864 B
  __shared__ __align__(16) u16 Vt[4][32][72];   // 18432 B
  __shared__ float rpbs[4][228];                //  3648 B
  const int md = *mode;
  const int l = threadIdx.x & 63, w = threadIdx.x >> 6;
  const int cl = l & 15, qd = l >> 4;
  const int ko = qd * 8;
  const int win = blockIdx.x;
  const int wi = win & 63;
  const int whb = (wi >> 3) << 3, wwb = (wi & 7) << 3;
  const size_t rowbase = (size_t)win * 64 * 768;

  for (int hh = 0; hh < 2; ++hh) {
    const int h = w + hh * 4;
    for (int i = l; i < 225; i += 64)
      rpbs[w][i] = in_elem(rpb, (size_t)eoff + (size_t)i * 8 + h, md);
    {
      const u16* vrow = (const u16*)(qkv + rowbase + (size_t)l * 768 + 512 + h * 32);
#pragma unroll
      for (int n = 0; n < 32; ++n) Vt[w][n][l] = vrow[n];
    }
    short8 qf[4], kf[4];
#pragma unroll
    for (int t = 0; t < 4; ++t) {
      qf[t] = *(const short8*)(qkv + rowbase + (size_t)(t * 16 + cl) * 768 + h * 32 + ko);
      kf[t] = *(const short8*)(qkv + rowbase + (size_t)(t * 16 + cl) * 768 + 256 + h * 32 + ko);
    }
    __syncthreads();

    floatx4 S[4][4];
#pragma unroll
    for (int mi = 0; mi < 4; ++mi)
#pragma unroll
      for (int ni = 0; ni < 4; ++ni)
        S[mi][ni] = __builtin_amdgcn_mfma_f32_16x16x32_bf16(qf[mi], kf[ni], (floatx4){0.f, 0.f, 0.f, 0.f}, 0, 0, 0);

    int cty[4], ctx[4], clab[4];
#pragma unroll
    for (int ni = 0; ni < 4; ++ni) {
      const int ct = ni * 16 + cl;
      cty[ni] = ct >> 3; ctx[ni] = ct & 7;
      clab[ni] = shifted ? (swlab(whb + cty[ni]) * 3 + swlab(wwb + ctx[ni])) : 0;
    }

    float invs[4][4];
#pragma unroll
    for (int mi = 0; mi < 4; ++mi) {
#pragma unroll
      for (int r = 0; r < 4; ++r) {
        const int rt = mi * 16 + qd * 4 + r;
        const int rty = rt >> 3, rtx = rt & 7;
        const int rlab = shifted ? (swlab(whb + rty) * 3 + swlab(wwb + rtx)) : 0;
        float sv[4];
#pragma unroll
        for (int ni = 0; ni < 4; ++ni) {
          float x = S[mi][ni][r] * 0.17677669529663687f;
          x += rpbs[w][(rty - cty[ni] + 7) * 15 + (rtx - ctx[ni] + 7)];
          if (shifted && (rlab != clab[ni])) x -= 100.f;
          sv[ni] = x;
        }
        float mx = fmaxf(fmaxf(sv[0], sv[1]), fmaxf(sv[2], sv[3]));
        mx = fmaxf(mx, __shfl_xor(mx, 1, 64));
        mx = fmaxf(mx, __shfl_xor(mx, 2, 64));
        mx = fmaxf(mx, __shfl_xor(mx, 4, 64));
        mx = fmaxf(mx, __shfl_xor(mx, 8, 64));
        float sum = 0.f;
#pragma unroll
        for (int ni = 0; ni < 4; ++ni) { sv[ni] = __expf(sv[ni] - mx); sum += sv[ni]; }
        sum += __shfl_xor(sum, 1, 64);
        sum += __shfl_xor(sum, 2, 64);
        sum += __shfl_xor(sum, 4, 64);
        sum += __shfl_xor(sum, 8, 64);
        invs[mi][r] = __builtin_amdgcn_rcpf(sum);
#pragma unroll
        for (int ni = 0; ni < 4; ++ni) Pl[w][rt][ni * 16 + cl] = f2b(sv[ni]);
      }
    }
    __syncthreads();

    floatx4 O[4][2];
#pragma unroll
    for (int mi = 0; mi < 4; ++mi)
#pragma unroll
      for (int nv = 0; nv < 2; ++nv)
        O[mi][nv] = (floatx4){0.f, 0.f, 0.f, 0.f};
    short8 vf[2][2];
#pragma unroll
    for (int nv = 0; nv < 2; ++nv)
#pragma unroll
      for (int kk = 0; kk < 2; ++kk)
        vf[nv][kk] = *(const short8*)&Vt[w][nv * 16 + cl][kk * 32 + ko];
#pragma unroll
    for (int mi = 0; mi < 4; ++mi) {
      const short8 pf0 = *(const short8*)&Pl[w][mi * 16 + cl][ko];
      const short8 pf1 = *(const short8*)&Pl[w][mi * 16 + cl][32 + ko];
#pragma unroll
      for (int nv = 0; nv < 2; ++nv) {
        O[mi][nv] = __builtin_amdgcn_mfma_f32_16x16x32_bf16(pf0, vf[nv][0], O[mi][nv], 0, 0, 0);
        O[mi][nv] = __builtin_amdgcn_mfma_f32_16x16x32_bf16(pf1, vf[nv][1], O[mi][nv], 0, 0, 0);
      }
    }

#pragma unroll
    for (int mi = 0; mi < 4; ++mi)
#pragma unroll
      for (int nv = 0; nv < 2; ++nv)
#pragma unroll
        for (int r = 0; r < 4; ++r) {
          const int row = mi * 16 + qd * 4 + r;
          ((u16*)outp)[((size_t)win * 64 + row) * 256 + h * 32 + nv * 16 + cl] =
              f2b(O[mi][nv][r] * invs[mi][r]);
        }
    __syncthreads();
  }
}

// ---------------- host launcher ----------------
extern "C" void kernel_launch(void* const* d_in, const int* in_sizes, int n_in,
                              void* d_out, int out_size, void* d_ws, size_t ws_size,
                              hipStream_t stream) {
  (void)in_sizes; (void)n_in; (void)out_size; (void)ws_size;
  const void* x_in   = d_in[0];
  const void* qkv_w  = d_in[1];
  const void* qkv_b  = d_in[2];
  const void* proj_w = d_in[3];
  const void* proj_b = d_in[4];
  const void* ln1_g  = d_in[5];
  const void* ln1_b  = d_in[6];
  const void* ln2_g  = d_in[7];
  const void* ln2_b  = d_in[8];
  const void* fc1_w  = d_in[9];
  const void* fc1_b  = d_in[10];
  const void* fc2_w  = d_in[11];
  const void* fc2_b  = d_in[12];
  const void* rpb    = d_in[13];

  char* ws = (char*)d_ws;
  float* xf  = (float*)ws;                   // 32 MiB
  bf16* bufQ = (bf16*)(ws + 100663296);      // 48 MiB qkv / LN2 out
  bf16* bufB = (bf16*)(ws + 150994944);      // 16 MiB LN out / attn out
  bf16* wT   = (bf16*)(ws + 167772160);      // 3 MiB
  int* mode  = (int*)(ws + 170917888);       // 4 B

  k_detect<<<1, 1, 0, stream>>>((const u32*)ln1_g, mode);
  // ingest + LN1(depth0): x -> xf, LN -> bufB (windowed, shift=0)
  k_ingest_ln<<<8192, 256, 0, stream>>>(x_in, xf, ln1_g, ln1_b, bufB, mode);

  // transposed weights per depth:
  // qkvT[768][256] @0, projT[256][256] @196608, fc1T[1024][256] @262144, fc2T[256][1024] @524288
  k_transpose<<<dim3(24, 8), 256, 0, stream>>>(qkv_w,  wT,          mode, 196608, 786432, 256, 768);
  k_transpose<<<dim3(8, 8), 256, 0, stream>>>(proj_w, wT + 196608, mode, 65536, 786432, 256, 256);
  k_transpose<<<dim3(32, 8), 256, 0, stream>>>(fc1_w, wT + 262144, mode, 262144, 786432, 256, 1024);
  k_transpose<<<dim3(8, 32), 256, 0, stream>>>(fc2_w, wT + 524288, mode, 262144, 786432, 1024, 256);

  for (int i = 0; i < 2; ++i) {
    const int shift = i ? 4 : 0;
    bf16* base  = wT + (size_t)i * 786432;
    bf16* qkvT  = base;
    bf16* projT = base + 196608;
    bf16* fc1T  = base + 262144;
    bf16* fc2T  = base + 524288;

    // QKV: bufQ[32768,768] = bufB @ qkv_w + b
    k_gemm<0><<<dim3(6, 256), 256, 0, stream>>>(bufB, qkvT, qkv_b, bufQ, mode, i * 768, 256, 768);
    // windowed attention: bufQ -> bufB (attnout, window order)
    k_attn<<<512, 256, 0, stream>>>(bufQ, rpb, bufB, mode, i * 1800, i);
    // proj + window-reverse(+unshift) + residual into xf + LN2 -> bufQ (token order)
    k_fullN<0><<<512, 256, 0, stream>>>(bufB, projT, proj_b, ln2_g, ln2_b, bufQ, xf, mode,
                                        i * 256, i * 256, 256, shift);
    // fused MLP: FC2(GELU(FC1(bufQ))) + residual; d0 fuses LN1(d1, shift=4) -> bufB;
    // d1 writes final fp32 output
    if (i == 0)
      k_mlp<1><<<512, 256, 0, stream>>>(bufQ, fc1T, fc2T, fc1_b, fc2_b, ln1_g, ln1_b,
                                        bufB, xf, mode, 0, 0, 256);
    else
      k_mlp<2><<<512, 256, 0, stream>>>(bufQ, fc1T, fc2T, fc1_b, fc2_b, nullptr, nullptr,
                                        d_out, xf, mode, 1024, 256, 0);
  }
}

// Round 10
// 398.998 us; speedup vs baseline: 1.2376x; 1.0557x over previous
//
#include <hip/hip_runtime.h>
#include <hip/hip_bf16.h>

// SwinTransformerEncoder on gfx950.
// H=W=64, C=256, HEADS=8 (d=32), WS=8, N=64 tok/window, NW=64, B=8, DEPTH=2, HIDDEN=1024.
// Inputs fp32 (runtime probe also supports bf16-cast). OUTPUT fp32. Residual fp32 in ws.
// R18: k_mlp was LDS-read-pipe-bound (18 reads/16 MFMA FC1, 17/16 FC2 from 4x B-fragment
//     redundancy at wave tile M=16; ~2480 cyc/phase ~= LDS arithmetic). Re-tiled waves:
//     FC1 wave = 64 rows x 32 hid (12 reads/16 MFMA), FC2 wave = 64 rows x 64 out-cols
//     (8 reads/16 MFMA) -> 1.75x fewer LDS reads. Same staging lambdas, same barrier
//     schedule, bitwise-identical K-accumulation order. Epilogue: acc2 -> full 64x272
//     fp32 LDS buffer (overlays dead staging, +1 barrier) -> per-wave full-row
//     coalesced LN streaming (proven fullN pattern).
//
// Workspace (~100 MiB of 256 MiB):
//   xf   fp32 [8*4096*256]   @ 0          (32 MiB)  residual stream
//   bufQ bf16 [32768*768]    @ 100663296  (48 MiB)  qkv / LN2 out
//   bufB bf16 [32768*256]    @ 150994944  (16 MiB)  LN out / attn out
//   wT   bf16 [2*786432]     @ 167772160  (3 MiB)   transposed weights
//   mode int                 @ 170917888  (4 B)     input-dtype flag (1=bf16, 0=fp32)

typedef __hip_bfloat16 bf16;
typedef unsigned short u16;
typedef unsigned int u32;
typedef short short8 __attribute__((ext_vector_type(8)));
typedef float floatx4 __attribute__((ext_vector_type(4)));

#define DEVI static __device__ __forceinline__
#define WAITCNT_VM(n) asm volatile("s_waitcnt vmcnt(" #n ")" ::: "memory")

DEVI float lo16(u32 u) { union { u32 i; float f; } x; x.i = u << 16; return x.f; }
DEVI float hi16(u32 u) { union { u32 i; float f; } x; x.i = u & 0xffff0000u; return x.f; }
DEVI float b2f(u16 u) { union { u32 i; float f; } x; x.i = ((u32)u) << 16; return x.f; }
DEVI u16 f2b(float f) {  // round-to-nearest-even
  union { float f; u32 i; } x; x.f = f;
  u32 r = x.i + 0x7fffu + ((x.i >> 16) & 1u);
  return (u16)(r >> 16);
}
DEVI float in_elem(const void* p, size_t i, int m) {
  return m ? b2f(((const u16*)p)[i]) : ((const float*)p)[i];
}
DEVI int swlab(int g) { return (g < 56) ? 0 : (g < 60 ? 1 : 2); }

// GELU via tanh form, 7 VALU ops (max abs err vs exact-erf GELU ~3e-4, << bf16 quant).
DEVI float gelu_cheap(float v) {
  const float u = v * v;
  const float t = v * __builtin_fmaf(0.1029436f, u, 2.3022090f);
  const float e = __builtin_amdgcn_exp2f(t);
  const float r = __builtin_amdgcn_rcpf(e + 1.0f);
  return __builtin_fmaf(-v, r, v);
}

DEVI void async16(const bf16* g, bf16* l) {
  __builtin_amdgcn_global_load_lds((const __attribute__((address_space(1))) u32*)g,
                                   (__attribute__((address_space(3))) u32*)l, 16, 0, 0);
}

// ---------------- dtype probe (ln1_g is all-ones) ----------------
__global__ void k_detect(const u32* __restrict__ ln1g, int* __restrict__ mode) {
  if (threadIdx.x == 0 && blockIdx.x == 0)
    *mode = (ln1g[0] == 0x3F803F80u) ? 1 : 0;
}

// ---------------- ingest + LN1(depth0): x -> xf copy, LN -> bufB windowed ----------------
__global__ __launch_bounds__(256) void k_ingest_ln(const void* __restrict__ xin,
    float* __restrict__ xf, const void* __restrict__ gamw, const void* __restrict__ betw,
    bf16* __restrict__ outp, const int* __restrict__ mode)
{
  const int m = *mode;
  const int l = threadIdx.x & 63, w = threadIdx.x >> 6;
  const int row = blockIdx.x * 4 + w;     // window-order output row
  const int t = row & 63, win = row >> 6;
  const int bb = win >> 6, wi = win & 63;
  const int gh = ((wi >> 3) << 3) + (t >> 3);
  const int gw = ((wi & 7) << 3) + (t & 7);
  const int srow = (bb << 12) + (gh << 6) + gw;   // token row (shift=0)
  const int cb = l << 2;
  float4 v;
  if (m) {
    const uint2 u = *(const uint2*)((const u16*)xin + (size_t)srow * 256 + cb);
    v = make_float4(lo16(u.x), hi16(u.x), lo16(u.y), hi16(u.y));
  } else {
    v = ((const float4*)((const float*)xin + (size_t)srow * 256))[l];
  }
  ((float4*)(xf + (size_t)srow * 256))[l] = v;    // residual copy
  float s = v.x + v.y + v.z + v.w;
#pragma unroll
  for (int off = 32; off > 0; off >>= 1) s += __shfl_xor(s, off, 64);
  const float mu = s * 0.00390625f;
  const float a = v.x - mu, b = v.y - mu, c = v.z - mu, d = v.w - mu;
  float q = a * a + b * b + c * c + d * d;
#pragma unroll
  for (int off = 32; off > 0; off >>= 1) q += __shfl_xor(q, off, 64);
  const float rs = rsqrtf(q * 0.00390625f + 1e-5f);
  const float o0 = a * rs * in_elem(gamw, cb + 0, m) + in_elem(betw, cb + 0, m);
  const float o1 = b * rs * in_elem(gamw, cb + 1, m) + in_elem(betw, cb + 1, m);
  const float o2 = c * rs * in_elem(gamw, cb + 2, m) + in_elem(betw, cb + 2, m);
  const float o3 = d * rs * in_elem(gamw, cb + 3, m) + in_elem(betw, cb + 3, m);
  const u32 p0 = (u32)f2b(o0) | ((u32)f2b(o1) << 16);
  const u32 p1 = (u32)f2b(o2) | ((u32)f2b(o3) << 16);
  *(uint2*)((u16*)outp + (size_t)row * 256 + cb) = make_uint2(p0, p1);
}

// ---------------- coalesced weight transpose: dst[c][r] = src[r][c], both depths ----------
__global__ __launch_bounds__(256) void k_transpose(
    const void* __restrict__ src, bf16* __restrict__ dst,
    const int* __restrict__ mode, int estride, int dstride, int R, int Cn) {
  __shared__ float T[32][33];
  const int m = *mode;
  const int tx = threadIdx.x & 31, ty = threadIdx.x >> 5;  // ty in 0..7
  const int bc = blockIdx.x << 5, br = blockIdx.y << 5;
  for (int d = 0; d < 2; ++d) {
    __syncthreads();
#pragma unroll
    for (int dy = 0; dy < 4; ++dy) {
      const int r = br + ty + dy * 8;
      T[ty + dy * 8][tx] = in_elem(src, (size_t)d * estride + (size_t)r * Cn + bc + tx, m);
    }
    __syncthreads();
#pragma unroll
    for (int dy = 0; dy < 4; ++dy) {
      const int c = bc + ty + dy * 8;
      ((u16*)dst)[(size_t)d * dstride + (size_t)c * R + br + tx] = f2b(T[tx][ty + dy * 8]);
    }
  }
}

// ---------------- bf16 MFMA GEMM: C[M,N] = A[M,K] @ Bt[N,K]^T + bias ----------------
// Tile 128 x 128, 4 waves (2x2), 16x16x32 MFMA; depth-2 prefetch (3 buffers, counted
// vmcnt(4), vmcnt(0) on last iter); XOR-swizzled LDS; XCD-chunked block swizzle.
// Epilogue: wave-private [4][72] LDS transpose -> uint2 coalesced stores.
template <int EPI>
__global__ __launch_bounds__(256, 3) void k_gemm(
    const bf16* __restrict__ A, const bf16* __restrict__ Bt,
    const void* __restrict__ bias, bf16* __restrict__ outb,
    const int* __restrict__ mode, int boff, int K, int N)
{
  __shared__ __align__(16) bf16 As[3][128 * 32];
  __shared__ __align__(16) bf16 Bs[3][128 * 32];
  __shared__ __align__(16) float EPs[4][4][72];   // wave-private transpose scratch
  const int md = *mode;
  const int tid = threadIdx.x;
  const int l = tid & 63, wid = tid >> 6;
  const int wr = wid >> 1, wc = wid & 1;

  const int gx = gridDim.x;
  const int nwg = gx * gridDim.y;
  int fid = blockIdx.y * gx + blockIdx.x;
  if (!(nwg & 7)) fid = (fid & 7) * (nwg >> 3) + (fid >> 3);
  const int row0 = (fid / gx) * 128;
  const int col0 = (fid % gx) * 128;

  const int lrow = l >> 2;
  const int lkof = (((l & 3) ^ ((l >> 3) & 3)) * 8);    // swizzled staged k-chunk
  const int qsw  = (((l >> 4) ^ ((l >> 1) & 3)) * 8);   // swizzled read slot

  floatx4 acc[4][4];
#pragma unroll
  for (int mi = 0; mi < 4; ++mi)
#pragma unroll
    for (int ni = 0; ni < 4; ++ni)
      acc[mi][ni] = (floatx4){0.f, 0.f, 0.f, 0.f};

  auto stage = [&](int b, int kbase) {   // 4 global_load_lds per thread
    const int kk = kbase + lkof;
#pragma unroll
    for (int c = 0; c < 2; ++c) {
      const int seg = c * 4 + wid;
      async16(A + (size_t)(row0 + seg * 16 + lrow) * K + kk, &As[b][seg * 512]);
      async16(Bt + (size_t)(col0 + seg * 16 + lrow) * K + kk, &Bs[b][seg * 512]);
    }
  };

  const int nsl = K >> 5;
  stage(0, 0);
  stage(1, 32);

  for (int s = 0; s < nsl; ++s) {
    const int cur = s % 3;
    if (s < nsl - 1) { WAITCNT_VM(4); }  // slice-s landed; slice s+1's 4 may fly
    else            { WAITCNT_VM(0); }   // tail: only slice-s loads outstanding
    __builtin_amdgcn_s_barrier();        // slice s resident, slice s-1 reads done
    if (s + 2 < nsl) stage((s + 2) % 3, (s + 2) * 32);  // overwrites slice s-1's buffer

    short8 af[4], bq[4];
#pragma unroll
    for (int mi = 0; mi < 4; ++mi)
      af[mi] = *(const short8*)&As[cur][(wr * 64 + mi * 16 + (l & 15)) * 32 + qsw];
#pragma unroll
    for (int ni = 0; ni < 4; ++ni)
      bq[ni] = *(const short8*)&Bs[cur][(wc * 64 + ni * 16 + (l & 15)) * 32 + qsw];
#pragma unroll
    for (int mi = 0; mi < 4; ++mi)
#pragma unroll
      for (int ni = 0; ni < 4; ++ni)
        acc[mi][ni] = __builtin_amdgcn_mfma_f32_16x16x32_bf16(af[mi], bq[ni], acc[mi][ni], 0, 0, 0);
  }

  // ---- epilogue: wave-private LDS transpose -> coalesced uint2 stores ----
  float* EPw = &EPs[wid][0][0];
  const int cl = l & 15, rq = l >> 4;   // fragment: col=lane&15, row=(lane>>4)*4+reg
  const int colb = wc * 64 + cl * 4;    // read-phase col base within 128-tile
  float bias4[4];
#pragma unroll
  for (int i = 0; i < 4; ++i) bias4[i] = in_elem(bias, (size_t)boff + col0 + colb + i, md);

#pragma unroll
  for (int mi = 0; mi < 4; ++mi) {
#pragma unroll
    for (int r = 0; r < 4; ++r) {
#pragma unroll
      for (int ni = 0; ni < 4; ++ni)
        EPw[rq * 72 + ni * 16 + cl] = acc[mi][ni][r];
      const float4 av = *(const float4*)&EPw[rq * 72 + cl * 4];
      float v0 = av.x + bias4[0], v1 = av.y + bias4[1];
      float v2 = av.z + bias4[2], v3 = av.w + bias4[3];
      if (EPI == 1) {
        v0 = gelu_cheap(v0); v1 = gelu_cheap(v1);
        v2 = gelu_cheap(v2); v3 = gelu_cheap(v3);
      }
      const int row = row0 + wr * 64 + mi * 16 + rq * 4 + r;
      const u32 p0 = (u32)f2b(v0) | ((u32)f2b(v1) << 16);
      const u32 p1 = (u32)f2b(v2) | ((u32)f2b(v3) << 16);
      *(uint2*)((u16*)outb + (size_t)row * N + col0 + colb) = make_uint2(p0, p1);
    }
  }
}

// ---------------- full-N GEMM (N=256) + fused residual/LN epilogue (proj only now) ----
// MODE 0 = proj: t = xf[winrev(row)]+v+bias; xf=t; outp[tokenrow] = LN2(t)
template <int MODE>
__global__ __launch_bounds__(256, 2) void k_fullN(
    const bf16* __restrict__ A, const bf16* __restrict__ Bt,
    const void* __restrict__ bias, const void* __restrict__ lng,
    const void* __restrict__ lnb, void* __restrict__ outp,
    float* __restrict__ xf, const int* __restrict__ mode,
    int boff, int lnoff, int K, int shift)
{
  __shared__ __align__(16) char smem[61440];
  bf16* As = (bf16*)smem;                 // [3][64*32]
  bf16* Bs = (bf16*)(smem + 12288);       // [3][256*32]
  const int md = *mode;
  const int tid = threadIdx.x;
  const int l = tid & 63, w = tid >> 6;

  int fid = blockIdx.x;
  const int nwg = gridDim.x;
  if (!(nwg & 7)) fid = (fid & 7) * (nwg >> 3) + (fid >> 3);
  const int row0 = fid * 64;

  const int lrow = l >> 2;
  const int lkof = (((l & 3) ^ ((l >> 3) & 3)) * 8);
  const int qsw  = (((l >> 4) ^ ((l >> 1) & 3)) * 8);

  floatx4 acc[16];
#pragma unroll
  for (int ni = 0; ni < 16; ++ni) acc[ni] = (floatx4){0.f, 0.f, 0.f, 0.f};

  auto stage = [&](int b, int kbase) {   // 5 global_load_lds per thread
    const int kk = kbase + lkof;
    async16(A + (size_t)(row0 + w * 16 + lrow) * K + kk, As + b * 2048 + w * 512);
#pragma unroll
    for (int c = 0; c < 4; ++c) {
      const int seg = c * 4 + w;
      async16(Bt + (size_t)(seg * 16 + lrow) * K + kk, Bs + b * 8192 + seg * 512);
    }
  };

  const int nsl = K >> 5;
  stage(0, 0);
  stage(1, 32);

  for (int s = 0; s < nsl; ++s) {
    const int cur = s % 3;
    if (s < nsl - 1) { WAITCNT_VM(5); }
    else            { WAITCNT_VM(0); }   // tail: only slice-s loads outstanding
    __builtin_amdgcn_s_barrier();
    if (s + 2 < nsl) stage((s + 2) % 3, (s + 2) * 32);

    const short8 af = *(const short8*)&As[cur * 2048 + (w * 16 + (l & 15)) * 32 + qsw];
#pragma unroll
    for (int ni = 0; ni < 16; ++ni) {
      const short8 bq = *(const short8*)&Bs[cur * 8192 + (ni * 16 + (l & 15)) * 32 + qsw];
      acc[ni] = __builtin_amdgcn_mfma_f32_16x16x32_bf16(af, bq, acc[ni], 0, 0, 0);
    }
  }

  // ---- epilogue: wave-private LDS transpose -> coalesced row streaming ----
  __syncthreads();

  float* EPw = (float*)smem + w * 1088;   // [4 rows][272 floats]
  const int cl = l & 15, rq = l >> 4;
  const int c4 = l * 4;

  float bias4[4], g4[4], b4[4];
#pragma unroll
  for (int i = 0; i < 4; ++i) bias4[i] = in_elem(bias, (size_t)boff + c4 + i, md);
#pragma unroll
  for (int i = 0; i < 4; ++i) {
    g4[i] = in_elem(lng, (size_t)lnoff + c4 + i, md);
    b4[i] = in_elem(lnb, (size_t)lnoff + c4 + i, md);
  }

  for (int r = 0; r < 4; ++r) {
#pragma unroll
    for (int ni = 0; ni < 16; ++ni)
      EPw[rq * 272 + ni * 16 + cl] = acc[ni][r];

#pragma unroll
    for (int g = 0; g < 4; ++g) {
      const int lrow_g = row0 + w * 16 + g * 4 + r;
      const float4 av = *(const float4*)&EPw[g * 272 + c4];

      const int t_ = lrow_g & 63, win = lrow_g >> 6;
      const int bb = win >> 6, wi2 = win & 63;
      int gh = ((wi2 >> 3) << 3) + (t_ >> 3);
      int gw = ((wi2 & 7) << 3) + (t_ & 7);
      gh = (gh + shift) & 63; gw = (gw + shift) & 63;
      const int resrow = (bb << 12) + (gh << 6) + gw;
      const int dstrow = resrow;

      const float4 xv = *(const float4*)(xf + (size_t)resrow * 256 + c4);
      float t0 = av.x + bias4[0] + xv.x;
      float t1 = av.y + bias4[1] + xv.y;
      float t2 = av.z + bias4[2] + xv.z;
      float t3 = av.w + bias4[3] + xv.w;

      float s = t0 + t1 + t2 + t3;
#pragma unroll
      for (int off = 32; off > 0; off >>= 1) s += __shfl_xor(s, off, 64);
      const float mu = s * 0.00390625f;
      const float d0 = t0 - mu, d1 = t1 - mu, d2 = t2 - mu, d3 = t3 - mu;
      float q = d0 * d0 + d1 * d1 + d2 * d2 + d3 * d3;
#pragma unroll
      for (int off = 32; off > 0; off >>= 1) q += __shfl_xor(q, off, 64);
      const float rs = rsqrtf(q * 0.00390625f + 1e-5f);

      *(float4*)(xf + (size_t)resrow * 256 + c4) = make_float4(t0, t1, t2, t3);
      const u32 p0 = (u32)f2b(d0 * rs * g4[0] + b4[0]) | ((u32)f2b(d1 * rs * g4[1] + b4[1]) << 16);
      const u32 p1 = (u32)f2b(d2 * rs * g4[2] + b4[2]) | ((u32)f2b(d3 * rs * g4[3] + b4[3]) << 16);
      *(uint2*)((u16*)outp + (size_t)dstrow * 256 + c4) = make_uint2(p0, p1);
    }
  }
}

// ---------------- fused MLP: out = FC2(GELU(FC1(A))) + residual (+LN1d1) ----------------
// Block = 64 token rows, 4 waves. A panel staged once (32KB, 8 swizzled slices).
// 8 hidden-chunks of 128. Wave tiles re-squared vs R16 (LDS-read-pipe fix):
//   FC1: wave = 64 rows x 32 hid  -> per BK=64 phase: 8 A + 4 B reads, 16 MFMA
//   FC2: wave = 64 rows x 64 outc -> per 32-hk step:  4 H + 4 B reads, 16 MFMA
// W1/W2 16KB slices double-buffered (2-phase __syncthreads pipeline; L2-resident).
// Epilogue: acc2 -> [64][272] fp32 LDS (overlays staging) -> per-wave full-row
// coalesced LN streaming. Accumulation order identical to R16 (bitwise-same result).
// MODE 1 = fc2(d0): t = xf[row]+v+b2; xf=t; outp[winshift4(row)] = LN1d1(t) (bf16)
// MODE 2 = fc2(d1): outp fp32 = xf[row] + v + b2  (final)
template <int MODE>
__global__ __launch_bounds__(256) void k_mlp(
    const bf16* __restrict__ A, const bf16* __restrict__ W1t, const bf16* __restrict__ W2t,
    const void* __restrict__ b1, const void* __restrict__ b2,
    const void* __restrict__ lng, const void* __restrict__ lnb,
    void* __restrict__ outp, float* __restrict__ xf, const int* __restrict__ mode,
    int b1off, int b2off, int lnoff)
{
  __shared__ __align__(16) char smem[81920];          // 80 KB -> 2 blocks/CU
  bf16* Al = (bf16*)smem;                             // [8][64*32]  32 KB (A slices)
  bf16* Wl = (bf16*)(smem + 32768);                   // [2][8192]   32 KB (W dbuf)
  u16*  Hl = (u16*)(smem + 65536);                    // [4][64*32]  16 KB (hidden chunk)
  const int md = *mode;
  const int tid = threadIdx.x;
  const int l = tid & 63, w = tid >> 6;
  int fid = blockIdx.x;
  const int nwg = gridDim.x;
  if (!(nwg & 7)) fid = (fid & 7) * (nwg >> 3) + (fid >> 3);
  const int row0 = fid * 64;

  const int lr4 = l >> 2;                             // staging row within 16-row seg
  const int lkof = (((l & 3) ^ ((l >> 3) & 3)) * 8);  // pre-swizzled global k-chunk
  const int qsw  = (((l >> 4) ^ ((l >> 1) & 3)) * 8); // swizzled LDS read slot
  const int cl = l & 15, rq = l >> 4;

  floatx4 acc2[4][4];
#pragma unroll
  for (int mi = 0; mi < 4; ++mi)
#pragma unroll
    for (int ni = 0; ni < 4; ++ni)
      acc2[mi][ni] = (floatx4){0.f, 0.f, 0.f, 0.f};

  // W1 pair-stage: slices s, s+1 of chunk c (each 128 Hrows x 32 k) -> buf halves
  auto stageW1 = [&](int c, int s, int b) {           // 4 loads/thread
#pragma unroll
    for (int cc = 0; cc < 2; ++cc) {
      const int seg = w * 2 + cc;
      const size_t gr = (size_t)(c * 128 + seg * 16 + lr4) * 256;
      async16(W1t + gr + s * 32 + lkof,       Wl + b * 8192 + seg * 512);
      async16(W1t + gr + (s + 1) * 32 + lkof, Wl + b * 8192 + 4096 + seg * 512);
    }
  };
  // W2 stage: slice q of chunk c (256 out-rows x 32 hk) -> full buf
  auto stageW2 = [&](int c, int q, int b) {           // 4 loads/thread
#pragma unroll
    for (int cc = 0; cc < 4; ++cc) {
      const int seg = w * 4 + cc;
      async16(W2t + (size_t)(seg * 16 + lr4) * 1024 + c * 128 + q * 32 + lkof,
              Wl + b * 8192 + seg * 512);
    }
  };

  // prologue: A panel (8 slices) + W1 chunk0 slices 0,1 -> buf 0
#pragma unroll
  for (int s = 0; s < 8; ++s)
    async16(A + (size_t)(row0 + w * 16 + lr4) * 256 + s * 32 + lkof, Al + s * 2048 + w * 512);
  stageW1(0, 0, 0);

  int buf = 0;
  for (int c = 0; c < 8; ++c) {
    floatx4 acc1[4][2];
#pragma unroll
    for (int mi = 0; mi < 4; ++mi)
#pragma unroll
      for (int bni = 0; bni < 2; ++bni)
        acc1[mi][bni] = (floatx4){0.f, 0.f, 0.f, 0.f};

    // FC1: 4 phases of BK=64 (K slices 2p, 2p+1); wave = 64 rows x 32 hid
    for (int p = 0; p < 4; ++p) {
      __syncthreads();                                // phase-p W landed; buf^1 free
      if (p < 3) stageW1(c, 2 * (p + 1), buf ^ 1);
      else       stageW2(c, 0, buf ^ 1);
#pragma unroll
      for (int h2 = 0; h2 < 2; ++h2) {                // k slices 2p (h2=0), 2p+1 (h2=1)
        const int ks = 2 * p + h2;
        short8 af[4];
#pragma unroll
        for (int mi = 0; mi < 4; ++mi)
          af[mi] = *(const short8*)&Al[ks * 2048 + (mi * 16 + cl) * 32 + qsw];
#pragma unroll
        for (int bni = 0; bni < 2; ++bni) {
          const short8 bq = *(const short8*)(Wl + buf * 8192 + h2 * 4096 +
                                             (w * 32 + bni * 16 + cl) * 32 + qsw);
#pragma unroll
          for (int mi = 0; mi < 4; ++mi)
            acc1[mi][bni] = __builtin_amdgcn_mfma_f32_16x16x32_bf16(af[mi], bq, acc1[mi][bni], 0, 0, 0);
        }
      }
      buf ^= 1;
    }

    // bias + GELU -> H tile (wave-private 32-col quarter w; A-fragment swizzle)
#pragma unroll
    for (int bni = 0; bni < 2; ++bni) {
      const int hcl = w * 32 + bni * 16 + cl;         // hid col within chunk (0..127)
      const float bv = in_elem(b1, (size_t)b1off + c * 128 + hcl, md);
      const int hq = (hcl >> 3) & 3, he = hcl & 7;    // slot-group within 32-col quarter
#pragma unroll
      for (int mi = 0; mi < 4; ++mi)
#pragma unroll
        for (int r = 0; r < 4; ++r) {
          const int hr = mi * 16 + rq * 4 + r;
          Hl[w * 2048 + hr * 32 + ((hq ^ ((hr >> 1) & 3)) * 8) + he] =
              f2b(gelu_cheap(acc1[mi][bni][r] + bv));
        }
    }

    // FC2: 4 phases of 32-hk; wave = 64 rows x 64 out-cols; accumulate into acc2
    for (int q = 0; q < 4; ++q) {
      __syncthreads();                                // W2 slice q landed; H visible
      if (q < 3)      stageW2(c, q + 1, buf ^ 1);
      else if (c < 7) stageW1(c + 1, 0, buf ^ 1);
      short8 hf[4];
#pragma unroll
      for (int mi = 0; mi < 4; ++mi)
        hf[mi] = *(const short8*)((const bf16*)&Hl[q * 2048 + (mi * 16 + cl) * 32 + qsw]);
#pragma unroll
      for (int ni = 0; ni < 4; ++ni) {
        const short8 bq = *(const short8*)(Wl + buf * 8192 +
                                           (w * 64 + ni * 16 + cl) * 32 + qsw);
#pragma unroll
        for (int mi = 0; mi < 4; ++mi)
          acc2[mi][ni] = __builtin_amdgcn_mfma_f32_16x16x32_bf16(hf[mi], bq, acc2[mi][ni], 0, 0, 0);
      }
      buf ^= 1;
    }
  }

  // ---- epilogue: acc2 -> [64][272] fp32 LDS (overlays dead staging) -> streaming ----
  __syncthreads();                                    // all waves done with Wl/Hl
  float* EPf = (float*)smem;                          // [64][272] = 69632 B
#pragma unroll
  for (int mi = 0; mi < 4; ++mi)
#pragma unroll
    for (int ni = 0; ni < 4; ++ni)
#pragma unroll
      for (int r = 0; r < 4; ++r)
        EPf[(mi * 16 + rq * 4 + r) * 272 + w * 64 + ni * 16 + cl] = acc2[mi][ni][r];
  __syncthreads();                                    // EPf complete

  const int c4 = l * 4;
  float bias4[4], g4[4], b4[4];
#pragma unroll
  for (int i = 0; i < 4; ++i) bias4[i] = in_elem(b2, (size_t)b2off + c4 + i, md);
  if (MODE == 1) {
#pragma unroll
    for (int i = 0; i < 4; ++i) {
      g4[i] = in_elem(lng, (size_t)lnoff + c4 + i, md);
      b4[i] = in_elem(lnb, (size_t)lnoff + c4 + i, md);
    }
  }

  for (int rr = 0; rr < 16; ++rr) {
    const int lrow_g = row0 + w * 16 + rr;            // token row (lane-uniform)
    const float4 av = *(const float4*)&EPf[(w * 16 + rr) * 272 + c4];
    const float4 xv = *(const float4*)(xf + (size_t)lrow_g * 256 + c4);
    float t0 = av.x + bias4[0] + xv.x;
    float t1 = av.y + bias4[1] + xv.y;
    float t2 = av.z + bias4[2] + xv.z;
    float t3 = av.w + bias4[3] + xv.w;

    if (MODE == 2) {
      *(float4*)((float*)outp + (size_t)lrow_g * 256 + c4) = make_float4(t0, t1, t2, t3);
      continue;
    }

    // token row -> windowed(shift=4) destination row
    const int bb = lrow_g >> 12, th = (lrow_g >> 6) & 63, tw = lrow_g & 63;
    const int gh = (th + 60) & 63, gw = (tw + 60) & 63;
    const int wi2 = ((gh >> 3) << 3) + (gw >> 3);
    const int tt = ((gh & 7) << 3) + (gw & 7);
    const int dstrow = (bb << 12) + (wi2 << 6) + tt;

    float s = t0 + t1 + t2 + t3;
#pragma unroll
    for (int off = 32; off > 0; off >>= 1) s += __shfl_xor(s, off, 64);
    const float mu = s * 0.00390625f;
    const float d0 = t0 - mu, d1 = t1 - mu, d2 = t2 - mu, d3 = t3 - mu;
    float q = d0 * d0 + d1 * d1 + d2 * d2 + d3 * d3;
#pragma unroll
    for (int off = 32; off > 0; off >>= 1) q += __shfl_xor(q, off, 64);
    const float rs = rsqrtf(q * 0.00390625f + 1e-5f);

    *(float4*)(xf + (size_t)lrow_g * 256 + c4) = make_float4(t0, t1, t2, t3);
    const u32 p0 = (u32)f2b(d0 * rs * g4[0] + b4[0]) | ((u32)f2b(d1 * rs * g4[1] + b4[1]) << 16);
    const u32 p1 = (u32)f2b(d2 * rs * g4[2] + b4[2]) | ((u32)f2b(d3 * rs * g4[3] + b4[3]) << 16);
    *(uint2*)((u16*)outp + (size_t)dstrow * 256 + c4) = make_uint2(p0, p1);
  }
}

// ---------------- windowed attention (MFMA; wave = window x head, 2 heads/wave) ----------------
__global__ __launch_bounds__(256, 2) void k_attn(
    const bf16* __restrict__ qkv, const void* __restrict__ rpb,
    bf16* __restrict__ outp, const int* __restrict__ mode, int eoff, int shifted)
{
  __shared__ __align__(16) u16 Pl[4][64][72];   // 36864 B
  __shared__ __align__(16) u16 Vt[4][32][72];   // 18432 B
  __shared__ float rpbs[4][228];                //  3648 B
  const int md = *mode;
  const int l = threadIdx.x & 63, w = threadIdx.x >> 6;
  const int cl = l & 15, qd = l >> 4;
  const int ko = qd * 8;
  const int win = blockIdx.x;
  const int wi = win & 63;
  const int whb = (wi >> 3) << 3, wwb = (wi & 7) << 3;
  const size_t rowbase = (size_t)win * 64 * 768;

  for (int hh = 0; hh < 2; ++hh) {
    const int h = w + hh * 4;
    for (int i = l; i < 225; i += 64)
      rpbs[w][i] = in_elem(rpb, (size_t)eoff + (size_t)i * 8 + h, md);
    {
      const u16* vrow = (const u16*)(qkv + rowbase + (size_t)l * 768 + 512 + h * 32);
#pragma unroll
      for (int n = 0; n < 32; ++n) Vt[w][n][l] = vrow[n];
    }
    short8 qf[4], kf[4];
#pragma unroll
    for (int t = 0; t < 4; ++t) {
      qf[t] = *(const short8*)(qkv + rowbase + (size_t)(t * 16 + cl) * 768 + h * 32 + ko);
      kf[t] = *(const short8*)(qkv + rowbase + (size_t)(t * 16 + cl) * 768 + 256 + h * 32 + ko);
    }
    __syncthreads();

    floatx4 S[4][4];
#pragma unroll
    for (int mi = 0; mi < 4; ++mi)
#pragma unroll
      for (int ni = 0; ni < 4; ++ni)
        S[mi][ni] = __builtin_amdgcn_mfma_f32_16x16x32_bf16(qf[mi], kf[ni], (floatx4){0.f, 0.f, 0.f, 0.f}, 0, 0, 0);

    int cty[4], ctx[4], clab[4];
#pragma unroll
    for (int ni = 0; ni < 4; ++ni) {
      const int ct = ni * 16 + cl;
      cty[ni] = ct >> 3; ctx[ni] = ct & 7;
      clab[ni] = shifted ? (swlab(whb + cty[ni]) * 3 + swlab(wwb + ctx[ni])) : 0;
    }

    float invs[4][4];
#pragma unroll
    for (int mi = 0; mi < 4; ++mi) {
#pragma unroll
      for (int r = 0; r < 4; ++r) {
        const int rt = mi * 16 + qd * 4 + r;
        const int rty = rt >> 3, rtx = rt & 7;
        const int rlab = shifted ? (swlab(whb + rty) * 3 + swlab(wwb + rtx)) : 0;
        float sv[4];
#pragma unroll
        for (int ni = 0; ni < 4; ++ni) {
          float x = S[mi][ni][r] * 0.17677669529663687f;
          x += rpbs[w][(rty - cty[ni] + 7) * 15 + (rtx - ctx[ni] + 7)];
          if (shifted && (rlab != clab[ni])) x -= 100.f;
          sv[ni] = x;
        }
        float mx = fmaxf(fmaxf(sv[0], sv[1]), fmaxf(sv[2], sv[3]));
        mx = fmaxf(mx, __shfl_xor(mx, 1, 64));
        mx = fmaxf(mx, __shfl_xor(mx, 2, 64));
        mx = fmaxf(mx, __shfl_xor(mx, 4, 64));
        mx = fmaxf(mx, __shfl_xor(mx, 8, 64));
        float sum = 0.f;
#pragma unroll
        for (int ni = 0; ni < 4; ++ni) { sv[ni] = __expf(sv[ni] - mx); sum += sv[ni]; }
        sum += __shfl_xor(sum, 1, 64);
        sum += __shfl_xor(sum, 2, 64);
        sum += __shfl_xor(sum, 4, 64);
        sum += __shfl_xor(sum, 8, 64);
        invs[mi][r] = __builtin_amdgcn_rcpf(sum);
#pragma unroll
        for (int ni = 0; ni < 4; ++ni) Pl[w][rt][ni * 16 + cl] = f2b(sv[ni]);
      }
    }
    __syncthreads();

    floatx4 O[4][2];
#pragma unroll
    for (int mi = 0; mi < 4; ++mi)
#pragma unroll
      for (int nv = 0; nv < 2; ++nv)
        O[mi][nv] = (floatx4){0.f, 0.f, 0.f, 0.f};
    short8 vf[2][2];
#pragma unroll
    for (int nv = 0; nv < 2; ++nv)
#pragma unroll
      for (int kk = 0; kk < 2; ++kk)
        vf[nv][kk] = *(const short8*)&Vt[w][nv * 16 + cl][kk * 32 + ko];
#pragma unroll
    for (int mi = 0; mi < 4; ++mi) {
      const short8 pf0 = *(const short8*)&Pl[w][mi * 16 + cl][ko];
      const short8 pf1 = *(const short8*)&Pl[w][mi * 16 + cl][32 + ko];
#pragma unroll
      for (int nv = 0; nv < 2; ++nv) {
        O[mi][nv] = __builtin_amdgcn_mfma_f32_16x16x32_bf16(pf0, vf[nv][0], O[mi][nv], 0, 0, 0);
        O[mi][nv] = __builtin_amdgcn_mfma_f32_16x16x32_bf16(pf1, vf[nv][1], O[mi][nv], 0, 0, 0);
      }
    }

#pragma unroll
    for (int mi = 0; mi < 4; ++mi)
#pragma unroll
      for (int nv = 0; nv < 2; ++nv)
#pragma unroll
        for (int r = 0; r < 4; ++r) {
          const int row = mi * 16 + qd * 4 + r;
          ((u16*)outp)[((size_t)win * 64 + row) * 256 + h * 32 + nv * 16 + cl] =
              f2b(O[mi][nv][r] * invs[mi][r]);
        }
    __syncthreads();
  }
}

// ---------------- host launcher ----------------
extern "C" void kernel_launch(void* const* d_in, const int* in_sizes, int n_in,
                              void* d_out, int out_size, void* d_ws, size_t ws_size,
                              hipStream_t stream) {
  (void)in_sizes; (void)n_in; (void)out_size; (void)ws_size;
  const void* x_in   = d_in[0];
  const void* qkv_w  = d_in[1];
  const void* qkv_b  = d_in[2];
  const void* proj_w = d_in[3];
  const void* proj_b = d_in[4];
  const void* ln1_g  = d_in[5];
  const void* ln1_b  = d_in[6];
  const void* ln2_g  = d_in[7];
  const void* ln2_b  = d_in[8];
  const void* fc1_w  = d_in[9];
  const void* fc1_b  = d_in[10];
  const void* fc2_w  = d_in[11];
  const void* fc2_b  = d_in[12];
  const void* rpb    = d_in[13];

  char* ws = (char*)d_ws;
  float* xf  = (float*)ws;                   // 32 MiB
  bf16* bufQ = (bf16*)(ws + 100663296);      // 48 MiB qkv / LN2 out
  bf16* bufB = (bf16*)(ws + 150994944);      // 16 MiB LN out / attn out
  bf16* wT   = (bf16*)(ws + 167772160);      // 3 MiB
  int* mode  = (int*)(ws + 170917888);       // 4 B

  k_detect<<<1, 1, 0, stream>>>((const u32*)ln1_g, mode);
  // ingest + LN1(depth0): x -> xf, LN -> bufB (windowed, shift=0)
  k_ingest_ln<<<8192, 256, 0, stream>>>(x_in, xf, ln1_g, ln1_b, bufB, mode);

  // transposed weights per depth:
  // qkvT[768][256] @0, projT[256][256] @196608, fc1T[1024][256] @262144, fc2T[256][1024] @524288
  k_transpose<<<dim3(24, 8), 256, 0, stream>>>(qkv_w,  wT,          mode, 196608, 786432, 256, 768);
  k_transpose<<<dim3(8, 8), 256, 0, stream>>>(proj_w, wT + 196608, mode, 65536, 786432, 256, 256);
  k_transpose<<<dim3(32, 8), 256, 0, stream>>>(fc1_w, wT + 262144, mode, 262144, 786432, 256, 1024);
  k_transpose<<<dim3(8, 32), 256, 0, stream>>>(fc2_w, wT + 524288, mode, 262144, 786432, 1024, 256);

  for (int i = 0; i < 2; ++i) {
    const int shift = i ? 4 : 0;
    bf16* base  = wT + (size_t)i * 786432;
    bf16* qkvT  = base;
    bf16* projT = base + 196608;
    bf16* fc1T  = base + 262144;
    bf16* fc2T  = base + 524288;

    // QKV: bufQ[32768,768] = bufB @ qkv_w + b
    k_gemm<0><<<dim3(6, 256), 256, 0, stream>>>(bufB, qkvT, qkv_b, bufQ, mode, i * 768, 256, 768);
    // windowed attention: bufQ -> bufB (attnout, window order)
    k_attn<<<512, 256, 0, stream>>>(bufQ, rpb, bufB, mode, i * 1800, i);
    // proj + window-reverse(+unshift) + residual into xf + LN2 -> bufQ (token order)
    k_fullN<0><<<512, 256, 0, stream>>>(bufB, projT, proj_b, ln2_g, ln2_b, bufQ, xf, mode,
                                        i * 256, i * 256, 256, shift);
    // fused MLP: FC2(GELU(FC1(bufQ))) + residual; d0 fuses LN1(d1, shift=4) -> bufB;
    // d1 writes final fp32 output
    if (i == 0)
      k_mlp<1><<<512, 256, 0, stream>>>(bufQ, fc1T, fc2T, fc1_b, fc2_b, ln1_g, ln1_b,
                                        bufB, xf, mode, 0, 0, 256);
    else
      k_mlp<2><<<512, 256, 0, stream>>>(bufQ, fc1T, fc2T, fc1_b, fc2_b, nullptr, nullptr,
                                        d_out, xf, mode, 1024, 256, 0);
  }
}

// Round 11
// 391.384 us; speedup vs baseline: 1.2617x; 1.0195x over previous
//
#include <hip/hip_runtime.h>
#include <hip/hip_bf16.h>

// SwinTransformerEncoder on gfx950.
// H=W=64, C=256, HEADS=8 (d=32), WS=8, N=64 tok/window, NW=64, B=8, DEPTH=2, HIDDEN=1024.
// Inputs fp32 (runtime probe also supports bf16-cast). OUTPUT fp32. Residual fp32 in ws.
// R19: k_mlp K-loop was W-staging-bound (2.7k cyc/phase vs ~150 cyc MFMA; depth-1
//     __syncthreads pipeline + 2 blocks/CU broadcasting 1MB/phase from each XCD L2).
//     Restructured: 128 rows/block, 8 waves, grid 256 (exactly 1 block/CU, no tail);
//     per-wave tiles unchanged (FC1 64rx32h, FC2 64rx64c). W now 3x16KB buffers with
//     depth-2 counted-vmcnt prefetch (k_gemm pattern + R14 tail fix); explicit
//     lgkmcnt(0) before the FC2-entry barrier for H-tile ds_write visibility.
//     LDS 144KB (A 64 + W 48 + H 32); epilogue EPf[128][272] overlays. Accumulation
//     order bitwise-identical to R18. Everything else unchanged.
//
// Workspace (~100 MiB of 256 MiB):
//   xf   fp32 [8*4096*256]   @ 0          (32 MiB)  residual stream
//   bufQ bf16 [32768*768]    @ 100663296  (48 MiB)  qkv / LN2 out
//   bufB bf16 [32768*256]    @ 150994944  (16 MiB)  LN out / attn out
//   wT   bf16 [2*786432]     @ 167772160  (3 MiB)   transposed weights
//   mode int                 @ 170917888  (4 B)     input-dtype flag (1=bf16, 0=fp32)

typedef __hip_bfloat16 bf16;
typedef unsigned short u16;
typedef unsigned int u32;
typedef short short8 __attribute__((ext_vector_type(8)));
typedef float floatx4 __attribute__((ext_vector_type(4)));

#define DEVI static __device__ __forceinline__
#define WAITCNT_VM(n) asm volatile("s_waitcnt vmcnt(" #n ")" ::: "memory")

DEVI float lo16(u32 u) { union { u32 i; float f; } x; x.i = u << 16; return x.f; }
DEVI float hi16(u32 u) { union { u32 i; float f; } x; x.i = u & 0xffff0000u; return x.f; }
DEVI float b2f(u16 u) { union { u32 i; float f; } x; x.i = ((u32)u) << 16; return x.f; }
DEVI u16 f2b(float f) {  // round-to-nearest-even
  union { float f; u32 i; } x; x.f = f;
  u32 r = x.i + 0x7fffu + ((x.i >> 16) & 1u);
  return (u16)(r >> 16);
}
DEVI float in_elem(const void* p, size_t i, int m) {
  return m ? b2f(((const u16*)p)[i]) : ((const float*)p)[i];
}
DEVI int swlab(int g) { return (g < 56) ? 0 : (g < 60 ? 1 : 2); }

// GELU via tanh form, 7 VALU ops (max abs err vs exact-erf GELU ~3e-4, << bf16 quant).
DEVI float gelu_cheap(float v) {
  const float u = v * v;
  const float t = v * __builtin_fmaf(0.1029436f, u, 2.3022090f);
  const float e = __builtin_amdgcn_exp2f(t);
  const float r = __builtin_amdgcn_rcpf(e + 1.0f);
  return __builtin_fmaf(-v, r, v);
}

DEVI void async16(const bf16* g, bf16* l) {
  __builtin_amdgcn_global_load_lds((const __attribute__((address_space(1))) u32*)g,
                                   (__attribute__((address_space(3))) u32*)l, 16, 0, 0);
}

// ---------------- dtype probe (ln1_g is all-ones) ----------------
__global__ void k_detect(const u32* __restrict__ ln1g, int* __restrict__ mode) {
  if (threadIdx.x == 0 && blockIdx.x == 0)
    *mode = (ln1g[0] == 0x3F803F80u) ? 1 : 0;
}

// ---------------- ingest + LN1(depth0): x -> xf copy, LN -> bufB windowed ----------------
__global__ __launch_bounds__(256) void k_ingest_ln(const void* __restrict__ xin,
    float* __restrict__ xf, const void* __restrict__ gamw, const void* __restrict__ betw,
    bf16* __restrict__ outp, const int* __restrict__ mode)
{
  const int m = *mode;
  const int l = threadIdx.x & 63, w = threadIdx.x >> 6;
  const int row = blockIdx.x * 4 + w;     // window-order output row
  const int t = row & 63, win = row >> 6;
  const int bb = win >> 6, wi = win & 63;
  const int gh = ((wi >> 3) << 3) + (t >> 3);
  const int gw = ((wi & 7) << 3) + (t & 7);
  const int srow = (bb << 12) + (gh << 6) + gw;   // token row (shift=0)
  const int cb = l << 2;
  float4 v;
  if (m) {
    const uint2 u = *(const uint2*)((const u16*)xin + (size_t)srow * 256 + cb);
    v = make_float4(lo16(u.x), hi16(u.x), lo16(u.y), hi16(u.y));
  } else {
    v = ((const float4*)((const float*)xin + (size_t)srow * 256))[l];
  }
  ((float4*)(xf + (size_t)srow * 256))[l] = v;    // residual copy
  float s = v.x + v.y + v.z + v.w;
#pragma unroll
  for (int off = 32; off > 0; off >>= 1) s += __shfl_xor(s, off, 64);
  const float mu = s * 0.00390625f;
  const float a = v.x - mu, b = v.y - mu, c = v.z - mu, d = v.w - mu;
  float q = a * a + b * b + c * c + d * d;
#pragma unroll
  for (int off = 32; off > 0; off >>= 1) q += __shfl_xor(q, off, 64);
  const float rs = rsqrtf(q * 0.00390625f + 1e-5f);
  const float o0 = a * rs * in_elem(gamw, cb + 0, m) + in_elem(betw, cb + 0, m);
  const float o1 = b * rs * in_elem(gamw, cb + 1, m) + in_elem(betw, cb + 1, m);
  const float o2 = c * rs * in_elem(gamw, cb + 2, m) + in_elem(betw, cb + 2, m);
  const float o3 = d * rs * in_elem(gamw, cb + 3, m) + in_elem(betw, cb + 3, m);
  const u32 p0 = (u32)f2b(o0) | ((u32)f2b(o1) << 16);
  const u32 p1 = (u32)f2b(o2) | ((u32)f2b(o3) << 16);
  *(uint2*)((u16*)outp + (size_t)row * 256 + cb) = make_uint2(p0, p1);
}

// ---------------- coalesced weight transpose: dst[c][r] = src[r][c], both depths ----------
__global__ __launch_bounds__(256) void k_transpose(
    const void* __restrict__ src, bf16* __restrict__ dst,
    const int* __restrict__ mode, int estride, int dstride, int R, int Cn) {
  __shared__ float T[32][33];
  const int m = *mode;
  const int tx = threadIdx.x & 31, ty = threadIdx.x >> 5;  // ty in 0..7
  const int bc = blockIdx.x << 5, br = blockIdx.y << 5;
  for (int d = 0; d < 2; ++d) {
    __syncthreads();
#pragma unroll
    for (int dy = 0; dy < 4; ++dy) {
      const int r = br + ty + dy * 8;
      T[ty + dy * 8][tx] = in_elem(src, (size_t)d * estride + (size_t)r * Cn + bc + tx, m);
    }
    __syncthreads();
#pragma unroll
    for (int dy = 0; dy < 4; ++dy) {
      const int c = bc + ty + dy * 8;
      ((u16*)dst)[(size_t)d * dstride + (size_t)c * R + br + tx] = f2b(T[tx][ty + dy * 8]);
    }
  }
}

// ---------------- bf16 MFMA GEMM: C[M,N] = A[M,K] @ Bt[N,K]^T + bias ----------------
// Tile 128 x 128, 4 waves (2x2), 16x16x32 MFMA; depth-2 prefetch (3 buffers, counted
// vmcnt(4), vmcnt(0) on last iter); XOR-swizzled LDS; XCD-chunked block swizzle.
// Epilogue: wave-private [4][72] LDS transpose -> uint2 coalesced stores.
template <int EPI>
__global__ __launch_bounds__(256, 3) void k_gemm(
    const bf16* __restrict__ A, const bf16* __restrict__ Bt,
    const void* __restrict__ bias, bf16* __restrict__ outb,
    const int* __restrict__ mode, int boff, int K, int N)
{
  __shared__ __align__(16) bf16 As[3][128 * 32];
  __shared__ __align__(16) bf16 Bs[3][128 * 32];
  __shared__ __align__(16) float EPs[4][4][72];   // wave-private transpose scratch
  const int md = *mode;
  const int tid = threadIdx.x;
  const int l = tid & 63, wid = tid >> 6;
  const int wr = wid >> 1, wc = wid & 1;

  const int gx = gridDim.x;
  const int nwg = gx * gridDim.y;
  int fid = blockIdx.y * gx + blockIdx.x;
  if (!(nwg & 7)) fid = (fid & 7) * (nwg >> 3) + (fid >> 3);
  const int row0 = (fid / gx) * 128;
  const int col0 = (fid % gx) * 128;

  const int lrow = l >> 2;
  const int lkof = (((l & 3) ^ ((l >> 3) & 3)) * 8);    // swizzled staged k-chunk
  const int qsw  = (((l >> 4) ^ ((l >> 1) & 3)) * 8);   // swizzled read slot

  floatx4 acc[4][4];
#pragma unroll
  for (int mi = 0; mi < 4; ++mi)
#pragma unroll
    for (int ni = 0; ni < 4; ++ni)
      acc[mi][ni] = (floatx4){0.f, 0.f, 0.f, 0.f};

  auto stage = [&](int b, int kbase) {   // 4 global_load_lds per thread
    const int kk = kbase + lkof;
#pragma unroll
    for (int c = 0; c < 2; ++c) {
      const int seg = c * 4 + wid;
      async16(A + (size_t)(row0 + seg * 16 + lrow) * K + kk, &As[b][seg * 512]);
      async16(Bt + (size_t)(col0 + seg * 16 + lrow) * K + kk, &Bs[b][seg * 512]);
    }
  };

  const int nsl = K >> 5;
  stage(0, 0);
  stage(1, 32);

  for (int s = 0; s < nsl; ++s) {
    const int cur = s % 3;
    if (s < nsl - 1) { WAITCNT_VM(4); }  // slice-s landed; slice s+1's 4 may fly
    else            { WAITCNT_VM(0); }   // tail: only slice-s loads outstanding
    __builtin_amdgcn_s_barrier();        // slice s resident, slice s-1 reads done
    if (s + 2 < nsl) stage((s + 2) % 3, (s + 2) * 32);  // overwrites slice s-1's buffer

    short8 af[4], bq[4];
#pragma unroll
    for (int mi = 0; mi < 4; ++mi)
      af[mi] = *(const short8*)&As[cur][(wr * 64 + mi * 16 + (l & 15)) * 32 + qsw];
#pragma unroll
    for (int ni = 0; ni < 4; ++ni)
      bq[ni] = *(const short8*)&Bs[cur][(wc * 64 + ni * 16 + (l & 15)) * 32 + qsw];
#pragma unroll
    for (int mi = 0; mi < 4; ++mi)
#pragma unroll
      for (int ni = 0; ni < 4; ++ni)
        acc[mi][ni] = __builtin_amdgcn_mfma_f32_16x16x32_bf16(af[mi], bq[ni], acc[mi][ni], 0, 0, 0);
  }

  // ---- epilogue: wave-private LDS transpose -> coalesced uint2 stores ----
  float* EPw = &EPs[wid][0][0];
  const int cl = l & 15, rq = l >> 4;   // fragment: col=lane&15, row=(lane>>4)*4+reg
  const int colb = wc * 64 + cl * 4;    // read-phase col base within 128-tile
  float bias4[4];
#pragma unroll
  for (int i = 0; i < 4; ++i) bias4[i] = in_elem(bias, (size_t)boff + col0 + colb + i, md);

#pragma unroll
  for (int mi = 0; mi < 4; ++mi) {
#pragma unroll
    for (int r = 0; r < 4; ++r) {
#pragma unroll
      for (int ni = 0; ni < 4; ++ni)
        EPw[rq * 72 + ni * 16 + cl] = acc[mi][ni][r];
      const float4 av = *(const float4*)&EPw[rq * 72 + cl * 4];
      float v0 = av.x + bias4[0], v1 = av.y + bias4[1];
      float v2 = av.z + bias4[2], v3 = av.w + bias4[3];
      if (EPI == 1) {
        v0 = gelu_cheap(v0); v1 = gelu_cheap(v1);
        v2 = gelu_cheap(v2); v3 = gelu_cheap(v3);
      }
      const int row = row0 + wr * 64 + mi * 16 + rq * 4 + r;
      const u32 p0 = (u32)f2b(v0) | ((u32)f2b(v1) << 16);
      const u32 p1 = (u32)f2b(v2) | ((u32)f2b(v3) << 16);
      *(uint2*)((u16*)outb + (size_t)row * N + col0 + colb) = make_uint2(p0, p1);
    }
  }
}

// ---------------- full-N GEMM (N=256) + fused residual/LN epilogue (proj only now) ----
// MODE 0 = proj: t = xf[winrev(row)]+v+bias; xf=t; outp[tokenrow] = LN2(t)
template <int MODE>
__global__ __launch_bounds__(256, 2) void k_fullN(
    const bf16* __restrict__ A, const bf16* __restrict__ Bt,
    const void* __restrict__ bias, const void* __restrict__ lng,
    const void* __restrict__ lnb, void* __restrict__ outp,
    float* __restrict__ xf, const int* __restrict__ mode,
    int boff, int lnoff, int K, int shift)
{
  __shared__ __align__(16) char smem[61440];
  bf16* As = (bf16*)smem;                 // [3][64*32]
  bf16* Bs = (bf16*)(smem + 12288);       // [3][256*32]
  const int md = *mode;
  const int tid = threadIdx.x;
  const int l = tid & 63, w = tid >> 6;

  int fid = blockIdx.x;
  const int nwg = gridDim.x;
  if (!(nwg & 7)) fid = (fid & 7) * (nwg >> 3) + (fid >> 3);
  const int row0 = fid * 64;

  const int lrow = l >> 2;
  const int lkof = (((l & 3) ^ ((l >> 3) & 3)) * 8);
  const int qsw  = (((l >> 4) ^ ((l >> 1) & 3)) * 8);

  floatx4 acc[16];
#pragma unroll
  for (int ni = 0; ni < 16; ++ni) acc[ni] = (floatx4){0.f, 0.f, 0.f, 0.f};

  auto stage = [&](int b, int kbase) {   // 5 global_load_lds per thread
    const int kk = kbase + lkof;
    async16(A + (size_t)(row0 + w * 16 + lrow) * K + kk, As + b * 2048 + w * 512);
#pragma unroll
    for (int c = 0; c < 4; ++c) {
      const int seg = c * 4 + w;
      async16(Bt + (size_t)(seg * 16 + lrow) * K + kk, Bs + b * 8192 + seg * 512);
    }
  };

  const int nsl = K >> 5;
  stage(0, 0);
  stage(1, 32);

  for (int s = 0; s < nsl; ++s) {
    const int cur = s % 3;
    if (s < nsl - 1) { WAITCNT_VM(5); }
    else            { WAITCNT_VM(0); }   // tail: only slice-s loads outstanding
    __builtin_amdgcn_s_barrier();
    if (s + 2 < nsl) stage((s + 2) % 3, (s + 2) * 32);

    const short8 af = *(const short8*)&As[cur * 2048 + (w * 16 + (l & 15)) * 32 + qsw];
#pragma unroll
    for (int ni = 0; ni < 16; ++ni) {
      const short8 bq = *(const short8*)&Bs[cur * 8192 + (ni * 16 + (l & 15)) * 32 + qsw];
      acc[ni] = __builtin_amdgcn_mfma_f32_16x16x32_bf16(af, bq, acc[ni], 0, 0, 0);
    }
  }

  // ---- epilogue: wave-private LDS transpose -> coalesced row streaming ----
  __syncthreads();

  float* EPw = (float*)smem + w * 1088;   // [4 rows][272 floats]
  const int cl = l & 15, rq = l >> 4;
  const int c4 = l * 4;

  float bias4[4], g4[4], b4[4];
#pragma unroll
  for (int i = 0; i < 4; ++i) bias4[i] = in_elem(bias, (size_t)boff + c4 + i, md);
#pragma unroll
  for (int i = 0; i < 4; ++i) {
    g4[i] = in_elem(lng, (size_t)lnoff + c4 + i, md);
    b4[i] = in_elem(lnb, (size_t)lnoff + c4 + i, md);
  }

  for (int r = 0; r < 4; ++r) {
#pragma unroll
    for (int ni = 0; ni < 16; ++ni)
      EPw[rq * 272 + ni * 16 + cl] = acc[ni][r];

#pragma unroll
    for (int g = 0; g < 4; ++g) {
      const int lrow_g = row0 + w * 16 + g * 4 + r;
      const float4 av = *(const float4*)&EPw[g * 272 + c4];

      const int t_ = lrow_g & 63, win = lrow_g >> 6;
      const int bb = win >> 6, wi2 = win & 63;
      int gh = ((wi2 >> 3) << 3) + (t_ >> 3);
      int gw = ((wi2 & 7) << 3) + (t_ & 7);
      gh = (gh + shift) & 63; gw = (gw + shift) & 63;
      const int resrow = (bb << 12) + (gh << 6) + gw;
      const int dstrow = resrow;

      const float4 xv = *(const float4*)(xf + (size_t)resrow * 256 + c4);
      float t0 = av.x + bias4[0] + xv.x;
      float t1 = av.y + bias4[1] + xv.y;
      float t2 = av.z + bias4[2] + xv.z;
      float t3 = av.w + bias4[3] + xv.w;

      float s = t0 + t1 + t2 + t3;
#pragma unroll
      for (int off = 32; off > 0; off >>= 1) s += __shfl_xor(s, off, 64);
      const float mu = s * 0.00390625f;
      const float d0 = t0 - mu, d1 = t1 - mu, d2 = t2 - mu, d3 = t3 - mu;
      float q = d0 * d0 + d1 * d1 + d2 * d2 + d3 * d3;
#pragma unroll
      for (int off = 32; off > 0; off >>= 1) q += __shfl_xor(q, off, 64);
      const float rs = rsqrtf(q * 0.00390625f + 1e-5f);

      *(float4*)(xf + (size_t)resrow * 256 + c4) = make_float4(t0, t1, t2, t3);
      const u32 p0 = (u32)f2b(d0 * rs * g4[0] + b4[0]) | ((u32)f2b(d1 * rs * g4[1] + b4[1]) << 16);
      const u32 p1 = (u32)f2b(d2 * rs * g4[2] + b4[2]) | ((u32)f2b(d3 * rs * g4[3] + b4[3]) << 16);
      *(uint2*)((u16*)outp + (size_t)dstrow * 256 + c4) = make_uint2(p0, p1);
    }
  }
}

// ---------------- fused MLP: out = FC2(GELU(FC1(A))) + residual (+LN1d1) ----------------
// Block = 128 token rows, 8 waves (512 thr), grid 256 = exactly 1 block/CU, no tail.
// Wave tiles: FC1 = (rowhalf rh, hidquarter hq4): 64 rows x 32 hid; FC2 = (rh, colq):
// 64 rows x 64 out-cols. A panel (128x256) staged once (64KB, 8 swizzled slices).
// 64 global phases (8 chunks x [4 FC1 + 4 FC2]); W staged 16KB/phase into 3 buffers
// with depth-2 counted-vmcnt prefetch (vmcnt(2); vmcnt(0) tail). H chunk tile 32KB.
// Explicit lgkmcnt(0) after H ds_writes, before the FC2-entry barrier (raw s_barrier
// does not drain). LDS 144KB. Epilogue: acc2 -> EPf[128][272] fp32 (overlays) ->
// per-wave 16-row coalesced LN streaming. Accumulation order identical to R18.
// MODE 1 = fc2(d0): t = xf[row]+v+b2; xf=t; outp[winshift4(row)] = LN1d1(t) (bf16)
// MODE 2 = fc2(d1): outp fp32 = xf[row] + v + b2  (final)
template <int MODE>
__global__ __launch_bounds__(512, 2) void k_mlp(
    const bf16* __restrict__ A, const bf16* __restrict__ W1t, const bf16* __restrict__ W2t,
    const void* __restrict__ b1, const void* __restrict__ b2,
    const void* __restrict__ lng, const void* __restrict__ lnb,
    void* __restrict__ outp, float* __restrict__ xf, const int* __restrict__ mode,
    int b1off, int b2off, int lnoff)
{
  __shared__ __align__(16) char smem[147456];         // 144 KB -> 1 block/CU
  bf16* Al = (bf16*)smem;                             // [8][128*32]  64 KB (A slices)
  bf16* Wl = (bf16*)(smem + 65536);                   // [3][8192]    48 KB (W 3-buf)
  u16*  Hl = (u16*)(smem + 114688);                   // [4][128*32]  32 KB (hidden chunk)
  const int md = *mode;
  const int tid = threadIdx.x;
  const int l = tid & 63, w = tid >> 6;               // 8 waves
  const int rh = w >> 2, wq = w & 3;                  // rowhalf / quarter
  int fid = blockIdx.x;
  const int nwg = gridDim.x;
  if (!(nwg & 7)) fid = (fid & 7) * (nwg >> 3) + (fid >> 3);
  const int row0 = fid * 128;

  const int lr4 = l >> 2;                             // staging row within 16-row seg
  const int lkof = (((l & 3) ^ ((l >> 3) & 3)) * 8);  // pre-swizzled global k-chunk
  const int qsw  = (((l >> 4) ^ ((l >> 1) & 3)) * 8); // swizzled LDS read slot
  const int cl = l & 15, rq = l >> 4;

  floatx4 acc2[4][4];
#pragma unroll
  for (int mi = 0; mi < 4; ++mi)
#pragma unroll
    for (int ni = 0; ni < 4; ++ni)
      acc2[mi][ni] = (floatx4){0.f, 0.f, 0.f, 0.f};

  // W1 pair-stage: k-slices s,s+1 of chunk c (128 hid rows x 32k each) -> buf halves
  auto stageW1 = [&](int c, int s, int b) {           // 2 loads/thread
    const size_t gr = (size_t)(c * 128 + w * 16 + lr4) * 256;
    async16(W1t + gr + s * 32 + lkof,       Wl + b * 8192 + w * 512);
    async16(W1t + gr + (s + 1) * 32 + lkof, Wl + b * 8192 + 4096 + w * 512);
  };
  // W2 stage: hk-slice q of chunk c (256 out-rows x 32 hk) -> full buf
  auto stageW2 = [&](int c, int q, int b) {           // 2 loads/thread
#pragma unroll
    for (int cc = 0; cc < 2; ++cc) {
      const int seg = w * 2 + cc;
      async16(W2t + (size_t)(seg * 16 + lr4) * 1024 + c * 128 + q * 32 + lkof,
              Wl + b * 8192 + seg * 512);
    }
  };
  // global phase g (0..63) -> what to stage into buf g%3
  auto stage_g = [&](int g) {
    const int c = g >> 3, sub = g & 7, b = g % 3;
    if (sub < 4) stageW1(c, 2 * sub, b);
    else         stageW2(c, sub - 4, b);
  };

  // prologue: A panel (8 slices, 64KB) + phases 0,1
#pragma unroll
  for (int s = 0; s < 8; ++s)
    async16(A + (size_t)(row0 + w * 16 + lr4) * 256 + s * 32 + lkof, Al + s * 4096 + w * 512);
  stage_g(0);
  stage_g(1);

  int ph = 0;
  for (int c = 0; c < 8; ++c) {
    floatx4 acc1[4][2];
#pragma unroll
    for (int mi = 0; mi < 4; ++mi)
#pragma unroll
      for (int bni = 0; bni < 2; ++bni)
        acc1[mi][bni] = (floatx4){0.f, 0.f, 0.f, 0.f};

    // FC1: 4 phases of BK=64; wave = 64 rows x 32 hid
    for (int p = 0; p < 4; ++p, ++ph) {
      if (ph < 63) { WAITCNT_VM(2); }   // phase-ph W landed; ph+1's 2 loads may fly
      else         { WAITCNT_VM(0); }
      __builtin_amdgcn_s_barrier();
      if (ph + 2 < 64) stage_g(ph + 2);
      const int buf = ph % 3;
#pragma unroll
      for (int h2 = 0; h2 < 2; ++h2) {
        const int ks = 2 * p + h2;
        short8 af[4];
#pragma unroll
        for (int mi = 0; mi < 4; ++mi)
          af[mi] = *(const short8*)&Al[ks * 4096 + (rh * 64 + mi * 16 + cl) * 32 + qsw];
#pragma unroll
        for (int bni = 0; bni < 2; ++bni) {
          const short8 bq = *(const short8*)(Wl + buf * 8192 + h2 * 4096 +
                                             (wq * 32 + bni * 16 + cl) * 32 + qsw);
#pragma unroll
          for (int mi = 0; mi < 4; ++mi)
            acc1[mi][bni] = __builtin_amdgcn_mfma_f32_16x16x32_bf16(af[mi], bq, acc1[mi][bni], 0, 0, 0);
        }
      }
    }

    // bias + GELU -> H tile (wave-private (rh, hq4) region; A-fragment swizzle)
#pragma unroll
    for (int bni = 0; bni < 2; ++bni) {
      const int h32 = bni * 16 + cl;                  // col within the wave's 32-group
      const float bv = in_elem(b1, (size_t)b1off + c * 128 + wq * 32 + h32, md);
      const int hq = h32 >> 3, he = h32 & 7;
#pragma unroll
      for (int mi = 0; mi < 4; ++mi)
#pragma unroll
        for (int r = 0; r < 4; ++r) {
          const int hr = rh * 64 + mi * 16 + rq * 4 + r;
          Hl[wq * 4096 + hr * 32 + ((hq ^ ((hr >> 1) & 3)) * 8) + he] =
              f2b(gelu_cheap(acc1[mi][bni][r] + bv));
        }
    }
    asm volatile("s_waitcnt lgkmcnt(0)" ::: "memory");  // H writes drained pre-barrier

    // FC2: 4 phases of 32-hk; wave = 64 rows x 64 out-cols; accumulate into acc2
    for (int q = 0; q < 4; ++q, ++ph) {
      if (ph < 63) { WAITCNT_VM(2); }
      else         { WAITCNT_VM(0); }
      __builtin_amdgcn_s_barrier();                   // W landed; all H writes visible
      if (ph + 2 < 64) stage_g(ph + 2);
      const int buf = ph % 3;
      short8 hf[4];
#pragma unroll
      for (int mi = 0; mi < 4; ++mi)
        hf[mi] = *(const short8*)((const bf16*)&Hl[q * 4096 + (rh * 64 + mi * 16 + cl) * 32 + qsw]);
#pragma unroll
      for (int ni = 0; ni < 4; ++ni) {
        const short8 bq = *(const short8*)(Wl + buf * 8192 +
                                           (wq * 64 + ni * 16 + cl) * 32 + qsw);
#pragma unroll
        for (int mi = 0; mi < 4; ++mi)
          acc2[mi][ni] = __builtin_amdgcn_mfma_f32_16x16x32_bf16(hf[mi], bq, acc2[mi][ni], 0, 0, 0);
      }
    }
  }

  // ---- epilogue: acc2 -> EPf[128][272] fp32 (overlays all staging) -> streaming ----
  __syncthreads();                                    // all phases done, LDS dead
  float* EPf = (float*)smem;                          // 128*272*4 = 139264 B
#pragma unroll
  for (int mi = 0; mi < 4; ++mi)
#pragma unroll
    for (int ni = 0; ni < 4; ++ni)
#pragma unroll
      for (int r = 0; r < 4; ++r)
        EPf[(rh * 64 + mi * 16 + rq * 4 + r) * 272 + wq * 64 + ni * 16 + cl] = acc2[mi][ni][r];
  __syncthreads();                                    // EPf complete

  const int c4 = l * 4;
  float bias4[4], g4[4], b4[4];
#pragma unroll
  for (int i = 0; i < 4; ++i) bias4[i] = in_elem(b2, (size_t)b2off + c4 + i, md);
  if (MODE == 1) {
#pragma unroll
    for (int i = 0; i < 4; ++i) {
      g4[i] = in_elem(lng, (size_t)lnoff + c4 + i, md);
      b4[i] = in_elem(lnb, (size_t)lnoff + c4 + i, md);
    }
  }

  for (int rr = 0; rr < 16; ++rr) {
    const int lrow_g = row0 + w * 16 + rr;            // token row (lane-uniform)
    const float4 av = *(const float4*)&EPf[(w * 16 + rr) * 272 + c4];
    const float4 xv = *(const float4*)(xf + (size_t)lrow_g * 256 + c4);
    float t0 = av.x + bias4[0] + xv.x;
    float t1 = av.y + bias4[1] + xv.y;
    float t2 = av.z + bias4[2] + xv.z;
    float t3 = av.w + bias4[3] + xv.w;

    if (MODE == 2) {
      *(float4*)((float*)outp + (size_t)lrow_g * 256 + c4) = make_float4(t0, t1, t2, t3);
      continue;
    }

    // token row -> windowed(shift=4) destination row
    const int bb = lrow_g >> 12, th = (lrow_g >> 6) & 63, tw = lrow_g & 63;
    const int gh = (th + 60) & 63, gw = (tw + 60) & 63;
    const int wi2 = ((gh >> 3) << 3) + (gw >> 3);
    const int tt = ((gh & 7) << 3) + (gw & 7);
    const int dstrow = (bb << 12) + (wi2 << 6) + tt;

    float s = t0 + t1 + t2 + t3;
#pragma unroll
    for (int off = 32; off > 0; off >>= 1) s += __shfl_xor(s, off, 64);
    const float mu = s * 0.00390625f;
    const float d0 = t0 - mu, d1 = t1 - mu, d2 = t2 - mu, d3 = t3 - mu;
    float q = d0 * d0 + d1 * d1 + d2 * d2 + d3 * d3;
#pragma unroll
    for (int off = 32; off > 0; off >>= 1) q += __shfl_xor(q, off, 64);
    const float rs = rsqrtf(q * 0.00390625f + 1e-5f);

    *(float4*)(xf + (size_t)lrow_g * 256 + c4) = make_float4(t0, t1, t2, t3);
    const u32 p0 = (u32)f2b(d0 * rs * g4[0] + b4[0]) | ((u32)f2b(d1 * rs * g4[1] + b4[1]) << 16);
    const u32 p1 = (u32)f2b(d2 * rs * g4[2] + b4[2]) | ((u32)f2b(d3 * rs * g4[3] + b4[3]) << 16);
    *(uint2*)((u16*)outp + (size_t)dstrow * 256 + c4) = make_uint2(p0, p1);
  }
}

// ---------------- windowed attention (MFMA; wave = window x head, 2 heads/wave) ----------------
__global__ __launch_bounds__(256, 2) void k_attn(
    const bf16* __restrict__ qkv, const void* __restrict__ rpb,
    bf16* __restrict__ outp, const int* __restrict__ mode, int eoff, int shifted)
{
  __shared__ __align__(16) u16 Pl[4][64][72];   // 36864 B
  __shared__ __align__(16) u16 Vt[4][32][72];   // 18432 B
  __shared__ float rpbs[4][228];                //  3648 B
  const int md = *mode;
  const int l = threadIdx.x & 63, w = threadIdx.x >> 6;
  const int cl = l & 15, qd = l >> 4;
  const int ko = qd * 8;
  const int win = blockIdx.x;
  const int wi = win & 63;
  const int whb = (wi >> 3) << 3, wwb = (wi & 7) << 3;
  const size_t rowbase = (size_t)win * 64 * 768;

  for (int hh = 0; hh < 2; ++hh) {
    const int h = w + hh * 4;
    for (int i = l; i < 225; i += 64)
      rpbs[w][i] = in_elem(rpb, (size_t)eoff + (size_t)i * 8 + h, md);
    {
      const u16* vrow = (const u16*)(qkv + rowbase + (size_t)l * 768 + 512 + h * 32);
#pragma unroll
      for (int n = 0; n < 32; ++n) Vt[w][n][l] = vrow[n];
    }
    short8 qf[4], kf[4];
#pragma unroll
    for (int t = 0; t < 4; ++t) {
      qf[t] = *(const short8*)(qkv + rowbase + (size_t)(t * 16 + cl) * 768 + h * 32 + ko);
      kf[t] = *(const short8*)(qkv + rowbase + (size_t)(t * 16 + cl) * 768 + 256 + h * 32 + ko);
    }
    __syncthreads();

    floatx4 S[4][4];
#pragma unroll
    for (int mi = 0; mi < 4; ++mi)
#pragma unroll
      for (int ni = 0; ni < 4; ++ni)
        S[mi][ni] = __builtin_amdgcn_mfma_f32_16x16x32_bf16(qf[mi], kf[ni], (floatx4){0.f, 0.f, 0.f, 0.f}, 0, 0, 0);

    int cty[4], ctx[4], clab[4];
#pragma unroll
    for (int ni = 0; ni < 4; ++ni) {
      const int ct = ni * 16 + cl;
      cty[ni] = ct >> 3; ctx[ni] = ct & 7;
      clab[ni] = shifted ? (swlab(whb + cty[ni]) * 3 + swlab(wwb + ctx[ni])) : 0;
    }

    float invs[4][4];
#pragma unroll
    for (int mi = 0; mi < 4; ++mi) {
#pragma unroll
      for (int r = 0; r < 4; ++r) {
        const int rt = mi * 16 + qd * 4 + r;
        const int rty = rt >> 3, rtx = rt & 7;
        const int rlab = shifted ? (swlab(whb + rty) * 3 + swlab(wwb + rtx)) : 0;
        float sv[4];
#pragma unroll
        for (int ni = 0; ni < 4; ++ni) {
          float x = S[mi][ni][r] * 0.17677669529663687f;
          x += rpbs[w][(rty - cty[ni] + 7) * 15 + (rtx - ctx[ni] + 7)];
          if (shifted && (rlab != clab[ni])) x -= 100.f;
          sv[ni] = x;
        }
        float mx = fmaxf(fmaxf(sv[0], sv[1]), fmaxf(sv[2], sv[3]));
        mx = fmaxf(mx, __shfl_xor(mx, 1, 64));
        mx = fmaxf(mx, __shfl_xor(mx, 2, 64));
        mx = fmaxf(mx, __shfl_xor(mx, 4, 64));
        mx = fmaxf(mx, __shfl_xor(mx, 8, 64));
        float sum = 0.f;
#pragma unroll
        for (int ni = 0; ni < 4; ++ni) { sv[ni] = __expf(sv[ni] - mx); sum += sv[ni]; }
        sum += __shfl_xor(sum, 1, 64);
        sum += __shfl_xor(sum, 2, 64);
        sum += __shfl_xor(sum, 4, 64);
        sum += __shfl_xor(sum, 8, 64);
        invs[mi][r] = __builtin_amdgcn_rcpf(sum);
#pragma unroll
        for (int ni = 0; ni < 4; ++ni) Pl[w][rt][ni * 16 + cl] = f2b(sv[ni]);
      }
    }
    __syncthreads();

    floatx4 O[4][2];
#pragma unroll
    for (int mi = 0; mi < 4; ++mi)
#pragma unroll
      for (int nv = 0; nv < 2; ++nv)
        O[mi][nv] = (floatx4){0.f, 0.f, 0.f, 0.f};
    short8 vf[2][2];
#pragma unroll
    for (int nv = 0; nv < 2; ++nv)
#pragma unroll
      for (int kk = 0; kk < 2; ++kk)
        vf[nv][kk] = *(const short8*)&Vt[w][nv * 16 + cl][kk * 32 + ko];
#pragma unroll
    for (int mi = 0; mi < 4; ++mi) {
      const short8 pf0 = *(const short8*)&Pl[w][mi * 16 + cl][ko];
      const short8 pf1 = *(const short8*)&Pl[w][mi * 16 + cl][32 + ko];
#pragma unroll
      for (int nv = 0; nv < 2; ++nv) {
        O[mi][nv] = __builtin_amdgcn_mfma_f32_16x16x32_bf16(pf0, vf[nv][0], O[mi][nv], 0, 0, 0);
        O[mi][nv] = __builtin_amdgcn_mfma_f32_16x16x32_bf16(pf1, vf[nv][1], O[mi][nv], 0, 0, 0);
      }
    }

#pragma unroll
    for (int mi = 0; mi < 4; ++mi)
#pragma unroll
      for (int nv = 0; nv < 2; ++nv)
#pragma unroll
        for (int r = 0; r < 4; ++r) {
          const int row = mi * 16 + qd * 4 + r;
          ((u16*)outp)[((size_t)win * 64 + row) * 256 + h * 32 + nv * 16 + cl] =
              f2b(O[mi][nv][r] * invs[mi][r]);
        }
    __syncthreads();
  }
}

// ---------------- host launcher ----------------
extern "C" void kernel_launch(void* const* d_in, const int* in_sizes, int n_in,
                              void* d_out, int out_size, void* d_ws, size_t ws_size,
                              hipStream_t stream) {
  (void)in_sizes; (void)n_in; (void)out_size; (void)ws_size;
  const void* x_in   = d_in[0];
  const void* qkv_w  = d_in[1];
  const void* qkv_b  = d_in[2];
  const void* proj_w = d_in[3];
  const void* proj_b = d_in[4];
  const void* ln1_g  = d_in[5];
  const void* ln1_b  = d_in[6];
  const void* ln2_g  = d_in[7];
  const void* ln2_b  = d_in[8];
  const void* fc1_w  = d_in[9];
  const void* fc1_b  = d_in[10];
  const void* fc2_w  = d_in[11];
  const void* fc2_b  = d_in[12];
  const void* rpb    = d_in[13];

  char* ws = (char*)d_ws;
  float* xf  = (float*)ws;                   // 32 MiB
  bf16* bufQ = (bf16*)(ws + 100663296);      // 48 MiB qkv / LN2 out
  bf16* bufB = (bf16*)(ws + 150994944);      // 16 MiB LN out / attn out
  bf16* wT   = (bf16*)(ws + 167772160);      // 3 MiB
  int* mode  = (int*)(ws + 170917888);       // 4 B

  k_detect<<<1, 1, 0, stream>>>((const u32*)ln1_g, mode);
  // ingest + LN1(depth0): x -> xf, LN -> bufB (windowed, shift=0)
  k_ingest_ln<<<8192, 256, 0, stream>>>(x_in, xf, ln1_g, ln1_b, bufB, mode);

  // transposed weights per depth:
  // qkvT[768][256] @0, projT[256][256] @196608, fc1T[1024][256] @262144, fc2T[256][1024] @524288
  k_transpose<<<dim3(24, 8), 256, 0, stream>>>(qkv_w,  wT,          mode, 196608, 786432, 256, 768);
  k_transpose<<<dim3(8, 8), 256, 0, stream>>>(proj_w, wT + 196608, mode, 65536, 786432, 256, 256);
  k_transpose<<<dim3(32, 8), 256, 0, stream>>>(fc1_w, wT + 262144, mode, 262144, 786432, 256, 1024);
  k_transpose<<<dim3(8, 32), 256, 0, stream>>>(fc2_w, wT + 524288, mode, 262144, 786432, 1024, 256);

  for (int i = 0; i < 2; ++i) {
    const int shift = i ? 4 : 0;
    bf16* base  = wT + (size_t)i * 786432;
    bf16* qkvT  = base;
    bf16* projT = base + 196608;
    bf16* fc1T  = base + 262144;
    bf16* fc2T  = base + 524288;

    // QKV: bufQ[32768,768] = bufB @ qkv_w + b
    k_gemm<0><<<dim3(6, 256), 256, 0, stream>>>(bufB, qkvT, qkv_b, bufQ, mode, i * 768, 256, 768);
    // windowed attention: bufQ -> bufB (attnout, window order)
    k_attn<<<512, 256, 0, stream>>>(bufQ, rpb, bufB, mode, i * 1800, i);
    // proj + window-reverse(+unshift) + residual into xf + LN2 -> bufQ (token order)
    k_fullN<0><<<512, 256, 0, stream>>>(bufB, projT, proj_b, ln2_g, ln2_b, bufQ, xf, mode,
                                        i * 256, i * 256, 256, shift);
    // fused MLP: FC2(GELU(FC1(bufQ))) + residual; d0 fuses LN1(d1, shift=4) -> bufB;
    // d1 writes final fp32 output
    if (i == 0)
      k_mlp<1><<<256, 512, 0, stream>>>(bufQ, fc1T, fc2T, fc1_b, fc2_b, ln1_g, ln1_b,
                                        bufB, xf, mode, 0, 0, 256);
    else
      k_mlp<2><<<256, 512, 0, stream>>>(bufQ, fc1T, fc2T, fc1_b, fc2_b, nullptr, nullptr,
                                        d_out, xf, mode, 1024, 256, 0);
  }
}

// Round 12
// 388.848 us; speedup vs baseline: 1.2699x; 1.0065x over previous
//
#include <hip/hip_runtime.h>
#include <hip/hip_bf16.h>

// SwinTransformerEncoder on gfx950.
// H=W=64, C=256, HEADS=8 (d=32), WS=8, N=64 tok/window, NW=64, B=8, DEPTH=2, HIDDEN=1024.
// Inputs fp32 (runtime probe also supports bf16-cast). OUTPUT fp32. Residual fp32 in ws.
// R20: k_mlp phase-fattening. R19 counters: MfmaUtil 20.3% == arithmetic floor ratio
//     (13.8us MFMA / 64.6us); per-phase cost ~2400 cyc vs ~600-900 issue -> ~1800 cyc
//     FIXED sync dead time per barrier-phase (1 block/CU: every barrier empties the CU).
//     Fix: halve phase count 64->32 via 32KB W slices (FC1: 2 phases of BK=128; FC2:
//     2 phases of 64 hk per chunk). LDS = full 160KB (A 64 + W 2x32 + H 32; AITER
//     precedent). Depth-1 prefetch w/ vmcnt(0)+raw barrier (fat phase covers L2).
//     Inner slice order unchanged -> bitwise-identical accumulation. Only k_mlp touched.
//
// Workspace (~100 MiB of 256 MiB):
//   xf   fp32 [8*4096*256]   @ 0          (32 MiB)  residual stream
//   bufQ bf16 [32768*768]    @ 100663296  (48 MiB)  qkv / LN2 out
//   bufB bf16 [32768*256]    @ 150994944  (16 MiB)  LN out / attn out
//   wT   bf16 [2*786432]     @ 167772160  (3 MiB)   transposed weights
//   mode int                 @ 170917888  (4 B)     input-dtype flag (1=bf16, 0=fp32)

typedef __hip_bfloat16 bf16;
typedef unsigned short u16;
typedef unsigned int u32;
typedef short short8 __attribute__((ext_vector_type(8)));
typedef float floatx4 __attribute__((ext_vector_type(4)));

#define DEVI static __device__ __forceinline__
#define WAITCNT_VM(n) asm volatile("s_waitcnt vmcnt(" #n ")" ::: "memory")

DEVI float lo16(u32 u) { union { u32 i; float f; } x; x.i = u << 16; return x.f; }
DEVI float hi16(u32 u) { union { u32 i; float f; } x; x.i = u & 0xffff0000u; return x.f; }
DEVI float b2f(u16 u) { union { u32 i; float f; } x; x.i = ((u32)u) << 16; return x.f; }
DEVI u16 f2b(float f) {  // round-to-nearest-even
  union { float f; u32 i; } x; x.f = f;
  u32 r = x.i + 0x7fffu + ((x.i >> 16) & 1u);
  return (u16)(r >> 16);
}
DEVI float in_elem(const void* p, size_t i, int m) {
  return m ? b2f(((const u16*)p)[i]) : ((const float*)p)[i];
}
DEVI int swlab(int g) { return (g < 56) ? 0 : (g < 60 ? 1 : 2); }

// GELU via tanh form, 7 VALU ops (max abs err vs exact-erf GELU ~3e-4, << bf16 quant).
DEVI float gelu_cheap(float v) {
  const float u = v * v;
  const float t = v * __builtin_fmaf(0.1029436f, u, 2.3022090f);
  const float e = __builtin_amdgcn_exp2f(t);
  const float r = __builtin_amdgcn_rcpf(e + 1.0f);
  return __builtin_fmaf(-v, r, v);
}

DEVI void async16(const bf16* g, bf16* l) {
  __builtin_amdgcn_global_load_lds((const __attribute__((address_space(1))) u32*)g,
                                   (__attribute__((address_space(3))) u32*)l, 16, 0, 0);
}

// ---------------- dtype probe (ln1_g is all-ones) ----------------
__global__ void k_detect(const u32* __restrict__ ln1g, int* __restrict__ mode) {
  if (threadIdx.x == 0 && blockIdx.x == 0)
    *mode = (ln1g[0] == 0x3F803F80u) ? 1 : 0;
}

// ---------------- ingest + LN1(depth0): x -> xf copy, LN -> bufB windowed ----------------
__global__ __launch_bounds__(256) void k_ingest_ln(const void* __restrict__ xin,
    float* __restrict__ xf, const void* __restrict__ gamw, const void* __restrict__ betw,
    bf16* __restrict__ outp, const int* __restrict__ mode)
{
  const int m = *mode;
  const int l = threadIdx.x & 63, w = threadIdx.x >> 6;
  const int row = blockIdx.x * 4 + w;     // window-order output row
  const int t = row & 63, win = row >> 6;
  const int bb = win >> 6, wi = win & 63;
  const int gh = ((wi >> 3) << 3) + (t >> 3);
  const int gw = ((wi & 7) << 3) + (t & 7);
  const int srow = (bb << 12) + (gh << 6) + gw;   // token row (shift=0)
  const int cb = l << 2;
  float4 v;
  if (m) {
    const uint2 u = *(const uint2*)((const u16*)xin + (size_t)srow * 256 + cb);
    v = make_float4(lo16(u.x), hi16(u.x), lo16(u.y), hi16(u.y));
  } else {
    v = ((const float4*)((const float*)xin + (size_t)srow * 256))[l];
  }
  ((float4*)(xf + (size_t)srow * 256))[l] = v;    // residual copy
  float s = v.x + v.y + v.z + v.w;
#pragma unroll
  for (int off = 32; off > 0; off >>= 1) s += __shfl_xor(s, off, 64);
  const float mu = s * 0.00390625f;
  const float a = v.x - mu, b = v.y - mu, c = v.z - mu, d = v.w - mu;
  float q = a * a + b * b + c * c + d * d;
#pragma unroll
  for (int off = 32; off > 0; off >>= 1) q += __shfl_xor(q, off, 64);
  const float rs = rsqrtf(q * 0.00390625f + 1e-5f);
  const float o0 = a * rs * in_elem(gamw, cb + 0, m) + in_elem(betw, cb + 0, m);
  const float o1 = b * rs * in_elem(gamw, cb + 1, m) + in_elem(betw, cb + 1, m);
  const float o2 = c * rs * in_elem(gamw, cb + 2, m) + in_elem(betw, cb + 2, m);
  const float o3 = d * rs * in_elem(gamw, cb + 3, m) + in_elem(betw, cb + 3, m);
  const u32 p0 = (u32)f2b(o0) | ((u32)f2b(o1) << 16);
  const u32 p1 = (u32)f2b(o2) | ((u32)f2b(o3) << 16);
  *(uint2*)((u16*)outp + (size_t)row * 256 + cb) = make_uint2(p0, p1);
}

// ---------------- coalesced weight transpose: dst[c][r] = src[r][c], both depths ----------
__global__ __launch_bounds__(256) void k_transpose(
    const void* __restrict__ src, bf16* __restrict__ dst,
    const int* __restrict__ mode, int estride, int dstride, int R, int Cn) {
  __shared__ float T[32][33];
  const int m = *mode;
  const int tx = threadIdx.x & 31, ty = threadIdx.x >> 5;  // ty in 0..7
  const int bc = blockIdx.x << 5, br = blockIdx.y << 5;
  for (int d = 0; d < 2; ++d) {
    __syncthreads();
#pragma unroll
    for (int dy = 0; dy < 4; ++dy) {
      const int r = br + ty + dy * 8;
      T[ty + dy * 8][tx] = in_elem(src, (size_t)d * estride + (size_t)r * Cn + bc + tx, m);
    }
    __syncthreads();
#pragma unroll
    for (int dy = 0; dy < 4; ++dy) {
      const int c = bc + ty + dy * 8;
      ((u16*)dst)[(size_t)d * dstride + (size_t)c * R + br + tx] = f2b(T[tx][ty + dy * 8]);
    }
  }
}

// ---------------- bf16 MFMA GEMM: C[M,N] = A[M,K] @ Bt[N,K]^T + bias ----------------
// Tile 128 x 128, 4 waves (2x2), 16x16x32 MFMA; depth-2 prefetch (3 buffers, counted
// vmcnt(4), vmcnt(0) on last iter); XOR-swizzled LDS; XCD-chunked block swizzle.
// Epilogue: wave-private [4][72] LDS transpose -> uint2 coalesced stores.
template <int EPI>
__global__ __launch_bounds__(256, 3) void k_gemm(
    const bf16* __restrict__ A, const bf16* __restrict__ Bt,
    const void* __restrict__ bias, bf16* __restrict__ outb,
    const int* __restrict__ mode, int boff, int K, int N)
{
  __shared__ __align__(16) bf16 As[3][128 * 32];
  __shared__ __align__(16) bf16 Bs[3][128 * 32];
  __shared__ __align__(16) float EPs[4][4][72];   // wave-private transpose scratch
  const int md = *mode;
  const int tid = threadIdx.x;
  const int l = tid & 63, wid = tid >> 6;
  const int wr = wid >> 1, wc = wid & 1;

  const int gx = gridDim.x;
  const int nwg = gx * gridDim.y;
  int fid = blockIdx.y * gx + blockIdx.x;
  if (!(nwg & 7)) fid = (fid & 7) * (nwg >> 3) + (fid >> 3);
  const int row0 = (fid / gx) * 128;
  const int col0 = (fid % gx) * 128;

  const int lrow = l >> 2;
  const int lkof = (((l & 3) ^ ((l >> 3) & 3)) * 8);    // swizzled staged k-chunk
  const int qsw  = (((l >> 4) ^ ((l >> 1) & 3)) * 8);   // swizzled read slot

  floatx4 acc[4][4];
#pragma unroll
  for (int mi = 0; mi < 4; ++mi)
#pragma unroll
    for (int ni = 0; ni < 4; ++ni)
      acc[mi][ni] = (floatx4){0.f, 0.f, 0.f, 0.f};

  auto stage = [&](int b, int kbase) {   // 4 global_load_lds per thread
    const int kk = kbase + lkof;
#pragma unroll
    for (int c = 0; c < 2; ++c) {
      const int seg = c * 4 + wid;
      async16(A + (size_t)(row0 + seg * 16 + lrow) * K + kk, &As[b][seg * 512]);
      async16(Bt + (size_t)(col0 + seg * 16 + lrow) * K + kk, &Bs[b][seg * 512]);
    }
  };

  const int nsl = K >> 5;
  stage(0, 0);
  stage(1, 32);

  for (int s = 0; s < nsl; ++s) {
    const int cur = s % 3;
    if (s < nsl - 1) { WAITCNT_VM(4); }  // slice-s landed; slice s+1's 4 may fly
    else            { WAITCNT_VM(0); }   // tail: only slice-s loads outstanding
    __builtin_amdgcn_s_barrier();        // slice s resident, slice s-1 reads done
    if (s + 2 < nsl) stage((s + 2) % 3, (s + 2) * 32);  // overwrites slice s-1's buffer

    short8 af[4], bq[4];
#pragma unroll
    for (int mi = 0; mi < 4; ++mi)
      af[mi] = *(const short8*)&As[cur][(wr * 64 + mi * 16 + (l & 15)) * 32 + qsw];
#pragma unroll
    for (int ni = 0; ni < 4; ++ni)
      bq[ni] = *(const short8*)&Bs[cur][(wc * 64 + ni * 16 + (l & 15)) * 32 + qsw];
#pragma unroll
    for (int mi = 0; mi < 4; ++mi)
#pragma unroll
      for (int ni = 0; ni < 4; ++ni)
        acc[mi][ni] = __builtin_amdgcn_mfma_f32_16x16x32_bf16(af[mi], bq[ni], acc[mi][ni], 0, 0, 0);
  }

  // ---- epilogue: wave-private LDS transpose -> coalesced uint2 stores ----
  float* EPw = &EPs[wid][0][0];
  const int cl = l & 15, rq = l >> 4;   // fragment: col=lane&15, row=(lane>>4)*4+reg
  const int colb = wc * 64 + cl * 4;    // read-phase col base within 128-tile
  float bias4[4];
#pragma unroll
  for (int i = 0; i < 4; ++i) bias4[i] = in_elem(bias, (size_t)boff + col0 + colb + i, md);

#pragma unroll
  for (int mi = 0; mi < 4; ++mi) {
#pragma unroll
    for (int r = 0; r < 4; ++r) {
#pragma unroll
      for (int ni = 0; ni < 4; ++ni)
        EPw[rq * 72 + ni * 16 + cl] = acc[mi][ni][r];
      const float4 av = *(const float4*)&EPw[rq * 72 + cl * 4];
      float v0 = av.x + bias4[0], v1 = av.y + bias4[1];
      float v2 = av.z + bias4[2], v3 = av.w + bias4[3];
      if (EPI == 1) {
        v0 = gelu_cheap(v0); v1 = gelu_cheap(v1);
        v2 = gelu_cheap(v2); v3 = gelu_cheap(v3);
      }
      const int row = row0 + wr * 64 + mi * 16 + rq * 4 + r;
      const u32 p0 = (u32)f2b(v0) | ((u32)f2b(v1) << 16);
      const u32 p1 = (u32)f2b(v2) | ((u32)f2b(v3) << 16);
      *(uint2*)((u16*)outb + (size_t)row * N + col0 + colb) = make_uint2(p0, p1);
    }
  }
}

// ---------------- full-N GEMM (N=256) + fused residual/LN epilogue (proj only now) ----
// MODE 0 = proj: t = xf[winrev(row)]+v+bias; xf=t; outp[tokenrow] = LN2(t)
template <int MODE>
__global__ __launch_bounds__(256, 2) void k_fullN(
    const bf16* __restrict__ A, const bf16* __restrict__ Bt,
    const void* __restrict__ bias, const void* __restrict__ lng,
    const void* __restrict__ lnb, void* __restrict__ outp,
    float* __restrict__ xf, const int* __restrict__ mode,
    int boff, int lnoff, int K, int shift)
{
  __shared__ __align__(16) char smem[61440];
  bf16* As = (bf16*)smem;                 // [3][64*32]
  bf16* Bs = (bf16*)(smem + 12288);       // [3][256*32]
  const int md = *mode;
  const int tid = threadIdx.x;
  const int l = tid & 63, w = tid >> 6;

  int fid = blockIdx.x;
  const int nwg = gridDim.x;
  if (!(nwg & 7)) fid = (fid & 7) * (nwg >> 3) + (fid >> 3);
  const int row0 = fid * 64;

  const int lrow = l >> 2;
  const int lkof = (((l & 3) ^ ((l >> 3) & 3)) * 8);
  const int qsw  = (((l >> 4) ^ ((l >> 1) & 3)) * 8);

  floatx4 acc[16];
#pragma unroll
  for (int ni = 0; ni < 16; ++ni) acc[ni] = (floatx4){0.f, 0.f, 0.f, 0.f};

  auto stage = [&](int b, int kbase) {   // 5 global_load_lds per thread
    const int kk = kbase + lkof;
    async16(A + (size_t)(row0 + w * 16 + lrow) * K + kk, As + b * 2048 + w * 512);
#pragma unroll
    for (int c = 0; c < 4; ++c) {
      const int seg = c * 4 + w;
      async16(Bt + (size_t)(seg * 16 + lrow) * K + kk, Bs + b * 8192 + seg * 512);
    }
  };

  const int nsl = K >> 5;
  stage(0, 0);
  stage(1, 32);

  for (int s = 0; s < nsl; ++s) {
    const int cur = s % 3;
    if (s < nsl - 1) { WAITCNT_VM(5); }
    else            { WAITCNT_VM(0); }   // tail: only slice-s loads outstanding
    __builtin_amdgcn_s_barrier();
    if (s + 2 < nsl) stage((s + 2) % 3, (s + 2) * 32);

    const short8 af = *(const short8*)&As[cur * 2048 + (w * 16 + (l & 15)) * 32 + qsw];
#pragma unroll
    for (int ni = 0; ni < 16; ++ni) {
      const short8 bq = *(const short8*)&Bs[cur * 8192 + (ni * 16 + (l & 15)) * 32 + qsw];
      acc[ni] = __builtin_amdgcn_mfma_f32_16x16x32_bf16(af, bq, acc[ni], 0, 0, 0);
    }
  }

  // ---- epilogue: wave-private LDS transpose -> coalesced row streaming ----
  __syncthreads();

  float* EPw = (float*)smem + w * 1088;   // [4 rows][272 floats]
  const int cl = l & 15, rq = l >> 4;
  const int c4 = l * 4;

  float bias4[4], g4[4], b4[4];
#pragma unroll
  for (int i = 0; i < 4; ++i) bias4[i] = in_elem(bias, (size_t)boff + c4 + i, md);
#pragma unroll
  for (int i = 0; i < 4; ++i) {
    g4[i] = in_elem(lng, (size_t)lnoff + c4 + i, md);
    b4[i] = in_elem(lnb, (size_t)lnoff + c4 + i, md);
  }

  for (int r = 0; r < 4; ++r) {
#pragma unroll
    for (int ni = 0; ni < 16; ++ni)
      EPw[rq * 272 + ni * 16 + cl] = acc[ni][r];

#pragma unroll
    for (int g = 0; g < 4; ++g) {
      const int lrow_g = row0 + w * 16 + g * 4 + r;
      const float4 av = *(const float4*)&EPw[g * 272 + c4];

      const int t_ = lrow_g & 63, win = lrow_g >> 6;
      const int bb = win >> 6, wi2 = win & 63;
      int gh = ((wi2 >> 3) << 3) + (t_ >> 3);
      int gw = ((wi2 & 7) << 3) + (t_ & 7);
      gh = (gh + shift) & 63; gw = (gw + shift) & 63;
      const int resrow = (bb << 12) + (gh << 6) + gw;
      const int dstrow = resrow;

      const float4 xv = *(const float4*)(xf + (size_t)resrow * 256 + c4);
      float t0 = av.x + bias4[0] + xv.x;
      float t1 = av.y + bias4[1] + xv.y;
      float t2 = av.z + bias4[2] + xv.z;
      float t3 = av.w + bias4[3] + xv.w;

      float s = t0 + t1 + t2 + t3;
#pragma unroll
      for (int off = 32; off > 0; off >>= 1) s += __shfl_xor(s, off, 64);
      const float mu = s * 0.00390625f;
      const float d0 = t0 - mu, d1 = t1 - mu, d2 = t2 - mu, d3 = t3 - mu;
      float q = d0 * d0 + d1 * d1 + d2 * d2 + d3 * d3;
#pragma unroll
      for (int off = 32; off > 0; off >>= 1) q += __shfl_xor(q, off, 64);
      const float rs = rsqrtf(q * 0.00390625f + 1e-5f);

      *(float4*)(xf + (size_t)resrow * 256 + c4) = make_float4(t0, t1, t2, t3);
      const u32 p0 = (u32)f2b(d0 * rs * g4[0] + b4[0]) | ((u32)f2b(d1 * rs * g4[1] + b4[1]) << 16);
      const u32 p1 = (u32)f2b(d2 * rs * g4[2] + b4[2]) | ((u32)f2b(d3 * rs * g4[3] + b4[3]) << 16);
      *(uint2*)((u16*)outp + (size_t)dstrow * 256 + c4) = make_uint2(p0, p1);
    }
  }
}

// ---------------- fused MLP: out = FC2(GELU(FC1(A))) + residual (+LN1d1) ----------------
// Block = 128 token rows, 8 waves (512 thr), grid 256 = exactly 1 block/CU, no tail.
// 32 fat phases (8 chunks x [2 FC1 BK=128 + 2 FC2 64-hk]); W staged 32KB/phase into
// 2 buffers, depth-1 vmcnt(0)+raw-barrier (fat phase covers L2 latency+BW). LDS =
// full 160KB: A 64KB (8 swizzled slices) + W 2x32KB + H 32KB. Explicit lgkmcnt(0)
// after H ds_writes, before the FC2-entry barrier. Epilogue: acc2 -> EPf[128][272]
// fp32 (overlays) -> per-wave 16-row coalesced LN streaming. Slice order identical
// to R19 -> bitwise-same accumulation.
// MODE 1 = fc2(d0): t = xf[row]+v+b2; xf=t; outp[winshift4(row)] = LN1d1(t) (bf16)
// MODE 2 = fc2(d1): outp fp32 = xf[row] + v + b2  (final)
template <int MODE>
__global__ __launch_bounds__(512, 2) void k_mlp(
    const bf16* __restrict__ A, const bf16* __restrict__ W1t, const bf16* __restrict__ W2t,
    const void* __restrict__ b1, const void* __restrict__ b2,
    const void* __restrict__ lng, const void* __restrict__ lnb,
    void* __restrict__ outp, float* __restrict__ xf, const int* __restrict__ mode,
    int b1off, int b2off, int lnoff)
{
  __shared__ __align__(16) char smem[163840];         // 160 KB -> 1 block/CU (AITER precedent)
  bf16* Al = (bf16*)smem;                             // [8][128*32]  64 KB (A slices)
  bf16* Wl = (bf16*)(smem + 65536);                   // [2][16384]   64 KB (W dbuf, 32KB each)
  u16*  Hl = (u16*)(smem + 131072);                   // [4][128*32]  32 KB (hidden chunk)
  const int md = *mode;
  const int tid = threadIdx.x;
  const int l = tid & 63, w = tid >> 6;               // 8 waves
  const int rh = w >> 2, wq = w & 3;                  // rowhalf / quarter
  int fid = blockIdx.x;
  const int nwg = gridDim.x;
  if (!(nwg & 7)) fid = (fid & 7) * (nwg >> 3) + (fid >> 3);
  const int row0 = fid * 128;

  const int lr4 = l >> 2;                             // staging row within 16-row seg
  const int lkof = (((l & 3) ^ ((l >> 3) & 3)) * 8);  // pre-swizzled global k-chunk
  const int qsw  = (((l >> 4) ^ ((l >> 1) & 3)) * 8); // swizzled LDS read slot
  const int cl = l & 15, rq = l >> 4;

  floatx4 acc2[4][4];
#pragma unroll
  for (int mi = 0; mi < 4; ++mi)
#pragma unroll
    for (int ni = 0; ni < 4; ++ni)
      acc2[mi][ni] = (floatx4){0.f, 0.f, 0.f, 0.f};

  // W1 quad-stage: k-slices s..s+3 of chunk c (128 hid rows x 32k each, 8KB) -> 4 slots
  auto stageW1 = [&](int c, int s, int b) {           // 4 loads/thread
    const size_t gr = (size_t)(c * 128 + w * 16 + lr4) * 256;
#pragma unroll
    for (int ss = 0; ss < 4; ++ss)
      async16(W1t + gr + (s + ss) * 32 + lkof, Wl + b * 16384 + ss * 4096 + w * 512);
  };
  // W2 dual-stage: hk-slices q,q+1 of chunk c (256 out-rows x 32 hk each, 16KB) -> 2 slots
  auto stageW2 = [&](int c, int q, int b) {           // 4 loads/thread
#pragma unroll
    for (int qq = 0; qq < 2; ++qq)
#pragma unroll
      for (int cc = 0; cc < 2; ++cc) {
        const int seg = w * 2 + cc;
        async16(W2t + (size_t)(seg * 16 + lr4) * 1024 + c * 128 + (q + qq) * 32 + lkof,
                Wl + b * 16384 + qq * 8192 + seg * 512);
      }
  };
  // global phase g (0..31) -> what to stage into buf g&1
  auto stage_g = [&](int g) {
    const int c = g >> 2, sub = g & 3, b = g & 1;
    if (sub < 2) stageW1(c, 4 * sub, b);
    else         stageW2(c, 2 * (sub - 2), b);
  };

  // prologue: A panel (8 slices, 64KB) + phase 0
#pragma unroll
  for (int s = 0; s < 8; ++s)
    async16(A + (size_t)(row0 + w * 16 + lr4) * 256 + s * 32 + lkof, Al + s * 4096 + w * 512);
  stage_g(0);

  int ph = 0;
  for (int c = 0; c < 8; ++c) {
    floatx4 acc1[4][2];
#pragma unroll
    for (int mi = 0; mi < 4; ++mi)
#pragma unroll
      for (int bni = 0; bni < 2; ++bni)
        acc1[mi][bni] = (floatx4){0.f, 0.f, 0.f, 0.f};

    // FC1: 2 fat phases of BK=128; wave = 64 rows x 32 hid
    for (int p = 0; p < 2; ++p, ++ph) {
      WAITCNT_VM(0);                    // phase-ph W (+A at ph=0) landed
      __builtin_amdgcn_s_barrier();     // all waves: W resident, buf(ph^1) reads done
      if (ph + 1 < 32) stage_g(ph + 1); // into buf (ph+1)&1
      const int buf = ph & 1;
#pragma unroll
      for (int h2 = 0; h2 < 4; ++h2) {
        const int ks = 4 * p + h2;      // k-slice 0..7, in order (bitwise-same acc)
        short8 af[4];
#pragma unroll
        for (int mi = 0; mi < 4; ++mi)
          af[mi] = *(const short8*)&Al[ks * 4096 + (rh * 64 + mi * 16 + cl) * 32 + qsw];
#pragma unroll
        for (int bni = 0; bni < 2; ++bni) {
          const short8 bq = *(const short8*)(Wl + buf * 16384 + h2 * 4096 +
                                             (wq * 32 + bni * 16 + cl) * 32 + qsw);
#pragma unroll
          for (int mi = 0; mi < 4; ++mi)
            acc1[mi][bni] = __builtin_amdgcn_mfma_f32_16x16x32_bf16(af[mi], bq, acc1[mi][bni], 0, 0, 0);
        }
      }
    }

    // bias + GELU -> H tile (wave-private (rh, wq) region; A-fragment swizzle)
#pragma unroll
    for (int bni = 0; bni < 2; ++bni) {
      const int h32 = bni * 16 + cl;                  // col within the wave's 32-group
      const float bv = in_elem(b1, (size_t)b1off + c * 128 + wq * 32 + h32, md);
      const int hq = h32 >> 3, he = h32 & 7;
#pragma unroll
      for (int mi = 0; mi < 4; ++mi)
#pragma unroll
        for (int r = 0; r < 4; ++r) {
          const int hr = rh * 64 + mi * 16 + rq * 4 + r;
          Hl[wq * 4096 + hr * 32 + ((hq ^ ((hr >> 1) & 3)) * 8) + he] =
              f2b(gelu_cheap(acc1[mi][bni][r] + bv));
        }
    }
    asm volatile("s_waitcnt lgkmcnt(0)" ::: "memory");  // H writes drained pre-barrier

    // FC2: 2 fat phases of 64-hk; wave = 64 rows x 64 out-cols; accumulate into acc2
    for (int p = 0; p < 2; ++p, ++ph) {
      WAITCNT_VM(0);
      __builtin_amdgcn_s_barrier();                   // W landed; all H writes visible
      if (ph + 1 < 32) stage_g(ph + 1);
      const int buf = ph & 1;
#pragma unroll
      for (int qq = 0; qq < 2; ++qq) {
        const int q2 = 2 * p + qq;                    // hk-slice 0..3, in order
        short8 hf[4];
#pragma unroll
        for (int mi = 0; mi < 4; ++mi)
          hf[mi] = *(const short8*)((const bf16*)&Hl[q2 * 4096 + (rh * 64 + mi * 16 + cl) * 32 + qsw]);
#pragma unroll
        for (int ni = 0; ni < 4; ++ni) {
          const short8 bq = *(const short8*)(Wl + buf * 16384 + qq * 8192 +
                                             (wq * 64 + ni * 16 + cl) * 32 + qsw);
#pragma unroll
          for (int mi = 0; mi < 4; ++mi)
            acc2[mi][ni] = __builtin_amdgcn_mfma_f32_16x16x32_bf16(hf[mi], bq, acc2[mi][ni], 0, 0, 0);
        }
      }
    }
  }

  // ---- epilogue: acc2 -> EPf[128][272] fp32 (overlays all staging) -> streaming ----
  __syncthreads();                                    // all phases done, LDS dead
  float* EPf = (float*)smem;                          // 128*272*4 = 139264 B
#pragma unroll
  for (int mi = 0; mi < 4; ++mi)
#pragma unroll
    for (int ni = 0; ni < 4; ++ni)
#pragma unroll
      for (int r = 0; r < 4; ++r)
        EPf[(rh * 64 + mi * 16 + rq * 4 + r) * 272 + wq * 64 + ni * 16 + cl] = acc2[mi][ni][r];
  __syncthreads();                                    // EPf complete

  const int c4 = l * 4;
  float bias4[4], g4[4], b4[4];
#pragma unroll
  for (int i = 0; i < 4; ++i) bias4[i] = in_elem(b2, (size_t)b2off + c4 + i, md);
  if (MODE == 1) {
#pragma unroll
    for (int i = 0; i < 4; ++i) {
      g4[i] = in_elem(lng, (size_t)lnoff + c4 + i, md);
      b4[i] = in_elem(lnb, (size_t)lnoff + c4 + i, md);
    }
  }

  for (int rr = 0; rr < 16; ++rr) {
    const int lrow_g = row0 + w * 16 + rr;            // token row (lane-uniform)
    const float4 av = *(const float4*)&EPf[(w * 16 + rr) * 272 + c4];
    const float4 xv = *(const float4*)(xf + (size_t)lrow_g * 256 + c4);
    float t0 = av.x + bias4[0] + xv.x;
    float t1 = av.y + bias4[1] + xv.y;
    float t2 = av.z + bias4[2] + xv.z;
    float t3 = av.w + bias4[3] + xv.w;

    if (MODE == 2) {
      *(float4*)((float*)outp + (size_t)lrow_g * 256 + c4) = make_float4(t0, t1, t2, t3);
      continue;
    }

    // token row -> windowed(shift=4) destination row
    const int bb = lrow_g >> 12, th = (lrow_g >> 6) & 63, tw = lrow_g & 63;
    const int gh = (th + 60) & 63, gw = (tw + 60) & 63;
    const int wi2 = ((gh >> 3) << 3) + (gw >> 3);
    const int tt = ((gh & 7) << 3) + (gw & 7);
    const int dstrow = (bb << 12) + (wi2 << 6) + tt;

    float s = t0 + t1 + t2 + t3;
#pragma unroll
    for (int off = 32; off > 0; off >>= 1) s += __shfl_xor(s, off, 64);
    const float mu = s * 0.00390625f;
    const float d0 = t0 - mu, d1 = t1 - mu, d2 = t2 - mu, d3 = t3 - mu;
    float q = d0 * d0 + d1 * d1 + d2 * d2 + d3 * d3;
#pragma unroll
    for (int off = 32; off > 0; off >>= 1) q += __shfl_xor(q, off, 64);
    const float rs = rsqrtf(q * 0.00390625f + 1e-5f);

    *(float4*)(xf + (size_t)lrow_g * 256 + c4) = make_float4(t0, t1, t2, t3);
    const u32 p0 = (u32)f2b(d0 * rs * g4[0] + b4[0]) | ((u32)f2b(d1 * rs * g4[1] + b4[1]) << 16);
    const u32 p1 = (u32)f2b(d2 * rs * g4[2] + b4[2]) | ((u32)f2b(d3 * rs * g4[3] + b4[3]) << 16);
    *(uint2*)((u16*)outp + (size_t)dstrow * 256 + c4) = make_uint2(p0, p1);
  }
}

// ---------------- windowed attention (MFMA; wave = window x head, 2 heads/wave) ----------------
__global__ __launch_bounds__(256, 2) void k_attn(
    const bf16* __restrict__ qkv, const void* __restrict__ rpb,
    bf16* __restrict__ outp, const int* __restrict__ mode, int eoff, int shifted)
{
  __shared__ __align__(16) u16 Pl[4][64][72];   // 36864 B
  __shared__ __align__(16) u16 Vt[4][32][72];   // 18432 B
  __shared__ float rpbs[4][228];                //  3648 B
  const int md = *mode;
  const int l = threadIdx.x & 63, w = threadIdx.x >> 6;
  const int cl = l & 15, qd = l >> 4;
  const int ko = qd * 8;
  const int win = blockIdx.x;
  const int wi = win & 63;
  const int whb = (wi >> 3) << 3, wwb = (wi & 7) << 3;
  const size_t rowbase = (size_t)win * 64 * 768;

  for (int hh = 0; hh < 2; ++hh) {
    const int h = w + hh * 4;
    for (int i = l; i < 225; i += 64)
      rpbs[w][i] = in_elem(rpb, (size_t)eoff + (size_t)i * 8 + h, md);
    {
      const u16* vrow = (const u16*)(qkv + rowbase + (size_t)l * 768 + 512 + h * 32);
#pragma unroll
      for (int n = 0; n < 32; ++n) Vt[w][n][l] = vrow[n];
    }
    short8 qf[4], kf[4];
#pragma unroll
    for (int t = 0; t < 4; ++t) {
      qf[t] = *(const short8*)(qkv + rowbase + (size_t)(t * 16 + cl) * 768 + h * 32 + ko);
      kf[t] = *(const short8*)(qkv + rowbase + (size_t)(t * 16 + cl) * 768 + 256 + h * 32 + ko);
    }
    __syncthreads();

    floatx4 S[4][4];
#pragma unroll
    for (int mi = 0; mi < 4; ++mi)
#pragma unroll
      for (int ni = 0; ni < 4; ++ni)
        S[mi][ni] = __builtin_amdgcn_mfma_f32_16x16x32_bf16(qf[mi], kf[ni], (floatx4){0.f, 0.f, 0.f, 0.f}, 0, 0, 0);

    int cty[4], ctx[4], clab[4];
#pragma unroll
    for (int ni = 0; ni < 4; ++ni) {
      const int ct = ni * 16 + cl;
      cty[ni] = ct >> 3; ctx[ni] = ct & 7;
      clab[ni] = shifted ? (swlab(whb + cty[ni]) * 3 + swlab(wwb + ctx[ni])) : 0;
    }

    float invs[4][4];
#pragma unroll
    for (int mi = 0; mi < 4; ++mi) {
#pragma unroll
      for (int r = 0; r < 4; ++r) {
        const int rt = mi * 16 + qd * 4 + r;
        const int rty = rt >> 3, rtx = rt & 7;
        const int rlab = shifted ? (swlab(whb + rty) * 3 + swlab(wwb + rtx)) : 0;
        float sv[4];
#pragma unroll
        for (int ni = 0; ni < 4; ++ni) {
          float x = S[mi][ni][r] * 0.17677669529663687f;
          x += rpbs[w][(rty - cty[ni] + 7) * 15 + (rtx - ctx[ni] + 7)];
          if (shifted && (rlab != clab[ni])) x -= 100.f;
          sv[ni] = x;
        }
        float mx = fmaxf(fmaxf(sv[0], sv[1]), fmaxf(sv[2], sv[3]));
        mx = fmaxf(mx, __shfl_xor(mx, 1, 64));
        mx = fmaxf(mx, __shfl_xor(mx, 2, 64));
        mx = fmaxf(mx, __shfl_xor(mx, 4, 64));
        mx = fmaxf(mx, __shfl_xor(mx, 8, 64));
        float sum = 0.f;
#pragma unroll
        for (int ni = 0; ni < 4; ++ni) { sv[ni] = __expf(sv[ni] - mx); sum += sv[ni]; }
        sum += __shfl_xor(sum, 1, 64);
        sum += __shfl_xor(sum, 2, 64);
        sum += __shfl_xor(sum, 4, 64);
        sum += __shfl_xor(sum, 8, 64);
        invs[mi][r] = __builtin_amdgcn_rcpf(sum);
#pragma unroll
        for (int ni = 0; ni < 4; ++ni) Pl[w][rt][ni * 16 + cl] = f2b(sv[ni]);
      }
    }
    __syncthreads();

    floatx4 O[4][2];
#pragma unroll
    for (int mi = 0; mi < 4; ++mi)
#pragma unroll
      for (int nv = 0; nv < 2; ++nv)
        O[mi][nv] = (floatx4){0.f, 0.f, 0.f, 0.f};
    short8 vf[2][2];
#pragma unroll
    for (int nv = 0; nv < 2; ++nv)
#pragma unroll
      for (int kk = 0; kk < 2; ++kk)
        vf[nv][kk] = *(const short8*)&Vt[w][nv * 16 + cl][kk * 32 + ko];
#pragma unroll
    for (int mi = 0; mi < 4; ++mi) {
      const short8 pf0 = *(const short8*)&Pl[w][mi * 16 + cl][ko];
      const short8 pf1 = *(const short8*)&Pl[w][mi * 16 + cl][32 + ko];
#pragma unroll
      for (int nv = 0; nv < 2; ++nv) {
        O[mi][nv] = __builtin_amdgcn_mfma_f32_16x16x32_bf16(pf0, vf[nv][0], O[mi][nv], 0, 0, 0);
        O[mi][nv] = __builtin_amdgcn_mfma_f32_16x16x32_bf16(pf1, vf[nv][1], O[mi][nv], 0, 0, 0);
      }
    }

#pragma unroll
    for (int mi = 0; mi < 4; ++mi)
#pragma unroll
      for (int nv = 0; nv < 2; ++nv)
#pragma unroll
        for (int r = 0; r < 4; ++r) {
          const int row = mi * 16 + qd * 4 + r;
          ((u16*)outp)[((size_t)win * 64 + row) * 256 + h * 32 + nv * 16 + cl] =
              f2b(O[mi][nv][r] * invs[mi][r]);
        }
    __syncthreads();
  }
}

// ---------------- host launcher ----------------
extern "C" void kernel_launch(void* const* d_in, const int* in_sizes, int n_in,
                              void* d_out, int out_size, void* d_ws, size_t ws_size,
                              hipStream_t stream) {
  (void)in_sizes; (void)n_in; (void)out_size; (void)ws_size;
  const void* x_in   = d_in[0];
  const void* qkv_w  = d_in[1];
  const void* qkv_b  = d_in[2];
  const void* proj_w = d_in[3];
  const void* proj_b = d_in[4];
  const void* ln1_g  = d_in[5];
  const void* ln1_b  = d_in[6];
  const void* ln2_g  = d_in[7];
  const void* ln2_b  = d_in[8];
  const void* fc1_w  = d_in[9];
  const void* fc1_b  = d_in[10];
  const void* fc2_w  = d_in[11];
  const void* fc2_b  = d_in[12];
  const void* rpb    = d_in[13];

  char* ws = (char*)d_ws;
  float* xf  = (float*)ws;                   // 32 MiB
  bf16* bufQ = (bf16*)(ws + 100663296);      // 48 MiB qkv / LN2 out
  bf16* bufB = (bf16*)(ws + 150994944);      // 16 MiB LN out / attn out
  bf16* wT   = (bf16*)(ws + 167772160);      // 3 MiB
  int* mode  = (int*)(ws + 170917888);       // 4 B

  k_detect<<<1, 1, 0, stream>>>((const u32*)ln1_g, mode);
  // ingest + LN1(depth0): x -> xf, LN -> bufB (windowed, shift=0)
  k_ingest_ln<<<8192, 256, 0, stream>>>(x_in, xf, ln1_g, ln1_b, bufB, mode);

  // transposed weights per depth:
  // qkvT[768][256] @0, projT[256][256] @196608, fc1T[1024][256] @262144, fc2T[256][1024] @524288
  k_transpose<<<dim3(24, 8), 256, 0, stream>>>(qkv_w,  wT,          mode, 196608, 786432, 256, 768);
  k_transpose<<<dim3(8, 8), 256, 0, stream>>>(proj_w, wT + 196608, mode, 65536, 786432, 256, 256);
  k_transpose<<<dim3(32, 8), 256, 0, stream>>>(fc1_w, wT + 262144, mode, 262144, 786432, 256, 1024);
  k_transpose<<<dim3(8, 32), 256, 0, stream>>>(fc2_w, wT + 524288, mode, 262144, 786432, 1024, 256);

  for (int i = 0; i < 2; ++i) {
    const int shift = i ? 4 : 0;
    bf16* base  = wT + (size_t)i * 786432;
    bf16* qkvT  = base;
    bf16* projT = base + 196608;
    bf16* fc1T  = base + 262144;
    bf16* fc2T  = base + 524288;

    // QKV: bufQ[32768,768] = bufB @ qkv_w + b
    k_gemm<0><<<dim3(6, 256), 256, 0, stream>>>(bufB, qkvT, qkv_b, bufQ, mode, i * 768, 256, 768);
    // windowed attention: bufQ -> bufB (attnout, window order)
    k_attn<<<512, 256, 0, stream>>>(bufQ, rpb, bufB, mode, i * 1800, i);
    // proj + window-reverse(+unshift) + residual into xf + LN2 -> bufQ (token order)
    k_fullN<0><<<512, 256, 0, stream>>>(bufB, projT, proj_b, ln2_g, ln2_b, bufQ, xf, mode,
                                        i * 256, i * 256, 256, shift);
    // fused MLP: FC2(GELU(FC1(bufQ))) + residual; d0 fuses LN1(d1, shift=4) -> bufB;
    // d1 writes final fp32 output
    if (i == 0)
      k_mlp<1><<<256, 512, 0, stream>>>(bufQ, fc1T, fc2T, fc1_b, fc2_b, ln1_g, ln1_b,
                                        bufB, xf, mode, 0, 0, 256);
    else
      k_mlp<2><<<256, 512, 0, stream>>>(bufQ, fc1T, fc2T, fc1_b, fc2_b, nullptr, nullptr,
                                        d_out, xf, mode, 1024, 256, 0);
  }
}